// Round 10
// baseline (13979.678 us; speedup 1.0000x reference)
//
#include <hip/hip_runtime.h>
#include <math.h>

#define T 512
#define B 128
#define E 256
#define H 256
#define G 1024   // 4H
#define DA 25
#define HEADS 5
#define NEGINF (-1e30f)

// ---------------- workspace layout (bytes) ----------------
static constexpr size_t WBT_OFF  = 0;           // [2][128 k2][256 j][8] ushort (bf16 W_hh^T) 1,048,576
static constexpr size_t WS1T_OFF = 2097152;     // [512][25] f32                  51,200
static constexpr size_t PX_OFF   = 2148352;     // [2][64][128][1024] f32     67,108,864
static constexpr size_t HC_OFF   = 69257216;    // [128][512][512] f32       134,217,728
static constexpr size_t HBUF_OFF = 203474944;   // [2][64 bt][256 j] float2      262,144
static constexpr size_t CST_OFF  = 203737088;   // [2][128][256] f32 c-state     262,144
static constexpr size_t A_OFF    = 203999232;   // [128][5][512] f32           1,310,720
static constexpr size_t PART_OFF = 205309952;   // [128] f32                         512

__device__ __forceinline__ float sigmoidf_(float x) { return 1.f / (1.f + expf(-x)); }
__device__ __forceinline__ float blo_(unsigned u) { return __uint_as_float(u << 16); }
__device__ __forceinline__ float bhi_(unsigned u) { return __uint_as_float(u & 0xffff0000u); }

__device__ __forceinline__ unsigned short f2bf_(float f) {   // RNE bf16
    unsigned u = __float_as_uint(f);
    unsigned r = (u + 0x7fffu + ((u >> 16) & 1u)) >> 16;
    return (unsigned short)r;
}

// 16 FMAs for one k-pair: 4 gates x 2 samples x 2 k
__device__ __forceinline__ void fma8_(uint4 wv, float4 hv,
                                      float& a00, float& a01, float& a10, float& a11,
                                      float& a20, float& a21, float& a30, float& a31) {
    float w0e = blo_(wv.x), w1e = bhi_(wv.x);
    float w2e = blo_(wv.y), w3e = bhi_(wv.y);
    float w0o = blo_(wv.z), w1o = bhi_(wv.z);
    float w2o = blo_(wv.w), w3o = bhi_(wv.w);
    a00 = fmaf(w0e, hv.x, a00); a01 = fmaf(w0e, hv.y, a01);
    a10 = fmaf(w1e, hv.x, a10); a11 = fmaf(w1e, hv.y, a11);
    a20 = fmaf(w2e, hv.x, a20); a21 = fmaf(w2e, hv.y, a21);
    a30 = fmaf(w3e, hv.x, a30); a31 = fmaf(w3e, hv.y, a31);
    a00 = fmaf(w0o, hv.z, a00); a01 = fmaf(w0o, hv.w, a01);
    a10 = fmaf(w1o, hv.z, a10); a11 = fmaf(w1o, hv.w, a11);
    a20 = fmaf(w2o, hv.z, a20); a21 = fmaf(w2o, hv.w, a21);
    a30 = fmaf(w3o, hv.z, a30); a31 = fmaf(w3o, hv.w, a31);
}

// ---------------- prep: pack W_hh (bf16, k-pair/gate interleaved) + W_s1^T --
// wbt layout: [(d*128 + k2)*256 + j]*8 + ke*4 + gate  (ushort)
__global__ __launch_bounds__(256) void prep_kernel(const float* __restrict__ Whf,
                                                   const float* __restrict__ Whb,
                                                   const float* __restrict__ Ws1,
                                                   unsigned short* __restrict__ wbt,
                                                   float* __restrict__ ws1t) {
    int idx = blockIdx.x * 256 + threadIdx.x;
    if (idx < 2 * G * H) {
        int d = idx >> 18;
        int rem = idx & 262143;
        int r = rem >> 8;                        // gate row 0..1023
        int k = rem & 255;                       // h index
        const float* W = d ? Whb : Whf;
        int gate = r >> 8, j = r & 255;
        int k2 = k >> 1, ke = k & 1;
        wbt[(((size_t)d * 128 + k2) * 256 + j) * 8 + ke * 4 + gate] = f2bf_(W[(size_t)r * H + k]);
    }
    if (idx < DA * 512) {
        int r = idx / 512, k = idx % 512;
        ws1t[k * DA + r] = Ws1[idx];
    }
}

// ---------------- input projection for one 64-step chunk ----------------
// grid (16 gtiles, 128 b, 2 dir), block 256
__global__ __launch_bounds__(256) void proj_kernel(const int* __restrict__ word_ids,
                                                   const int* __restrict__ lengths,
                                                   const float* __restrict__ emb,
                                                   const float* __restrict__ Wf,
                                                   const float* __restrict__ Wb,
                                                   const float* __restrict__ bf,
                                                   const float* __restrict__ bb,
                                                   float* __restrict__ pxc, int chunk) {
    int g0 = blockIdx.x * 64;
    int b  = blockIdx.y;
    int d  = blockIdx.z;
    int len = lengths[b];
    int t0 = chunk * 64;
    if (t0 >= len) return;
    const float* Wih  = d ? Wb : Wf;
    const float* bias = d ? bb : bf;

    __shared__ int   wid[64];
    __shared__ float As[64][17];   // [m][kk], k-minor, padded
    __shared__ float Bs[64][17];

    int tid = threadIdx.x;
    if (tid < 64) {
        int t = t0 + tid;
        int src;
        if (d == 0) src = t;
        else { src = len - 1 - t; if (src < 0) src = 0; }
        wid[tid] = word_ids[b * T + src];
    }
    __syncthreads();

    int tx = tid & 15, ty = tid >> 4;   // compute mapping
    int kk = tid & 15, r0 = tid >> 4;   // load mapping
    float acc[4][4];
    #pragma unroll
    for (int i = 0; i < 4; i++)
        #pragma unroll
        for (int j = 0; j < 4; j++) acc[i][j] = 0.f;

    for (int k0 = 0; k0 < E; k0 += 16) {
        #pragma unroll
        for (int i = 0; i < 4; i++) {
            int m = r0 + 16 * i;
            As[m][kk] = emb[(size_t)wid[m] * E + k0 + kk];
            Bs[m][kk] = Wih[(size_t)(g0 + m) * E + k0 + kk];
        }
        __syncthreads();
        #pragma unroll
        for (int kq = 0; kq < 16; kq++) {
            float a[4], bv[4];
            #pragma unroll
            for (int i = 0; i < 4; i++) a[i] = As[ty * 4 + i][kq];
            #pragma unroll
            for (int j = 0; j < 4; j++) bv[j] = Bs[tx * 4 + j][kq];
            #pragma unroll
            for (int i = 0; i < 4; i++)
                #pragma unroll
                for (int j = 0; j < 4; j++) acc[i][j] += a[i] * bv[j];
        }
        __syncthreads();
    }
    #pragma unroll
    for (int i = 0; i < 4; i++) {
        int m = ty * 4 + i;
        #pragma unroll
        for (int j = 0; j < 4; j++) {
            int n = tx * 4 + j;
            pxc[((size_t)(d * 64 + m) * B + b) * G + g0 + n] = acc[i][j] + bias[g0 + n];
        }
    }
}

// ---------------- LSTM recurrence, wave-parallel K-split + resident W ------
// grid (64 btiles, 2 dir); block 1024 = 16 waves.
// amdgpu_waves_per_eu(4,4): min=MAX=4 waves/EU. Round 9 showed launch_bounds'
// 2nd arg only sets the MIN of the range [4,8] and the register allocator
// targets the max (8 w/EU = 64 VGPR cap) -> spilled the resident W (2.3 GB
// scratch FETCH). Pinning max=4 gives the 128-VGPR budget this kernel needs.
// Thread (j = tid&255, kq = tid>>8): k-slice [kq*64, kq*64+64) = 32 k-pairs.
//   k-pairs 0..11  : W in 12 NAMED uint4 registers (48 VGPR), loaded once.
//   k-pairs 12..31 : W streamed from L2 (320 KB/step/CU, down from 512).
__global__ __attribute__((amdgpu_waves_per_eu(4, 4)))
__launch_bounds__(1024) void lstm4_kernel(const int* __restrict__ lengths,
                                          const unsigned short* __restrict__ wbt,
                                          const float* __restrict__ pxc,
                                          float* __restrict__ hc_out,
                                          float* __restrict__ hbuf,
                                          float* __restrict__ cstate,
                                          int chunk) {
    int bt = blockIdx.x;
    int d  = blockIdx.y;
    int b0 = bt * 2;
    int tid = threadIdx.x;
    int j  = tid & 255;
    int kq = tid >> 8;                 // 0..3 (wave-uniform)

    int len0 = lengths[b0], len1 = lengths[b0 + 1];
    int maxlen = max(len0, len1);
    int t0 = chunk * 64;
    if (t0 >= maxlen) return;
    int tend = min(t0 + 64, maxlen);

    __shared__ float2 hping[2][256];       // [buf][k] = h[k] for {b0, b0+1}
    __shared__ float4 part[3][2][257];     // kq=1..3 partials, padded

    float2* hbufg = (float2*)hbuf + ((size_t)d * 64 + bt) * 256;

    float c0 = 0.f, c1 = 0.f;
    int cur = 0;
    if (chunk == 0) {
        if (tid < 256) hping[0][tid] = make_float2(0.f, 0.f);
    } else if (kq == 0) {
        c0 = cstate[((size_t)d * B + b0) * H + j];
        c1 = cstate[((size_t)d * B + b0 + 1) * H + j];
        hping[0][j] = hbufg[j];
    }
    __syncthreads();

    // thread's W rows: k2 in [kq*32, kq*32+32), column j
    const uint4* wp  = (const uint4*)wbt + (size_t)d * 128 * 256 + (size_t)(kq * 32) * 256 + j;
    const float* pxd = pxc + (size_t)d * 64 * B * G;

    // resident W: k-pairs 0..11 in named registers (48 VGPR, no arrays)
    uint4 wr0  = wp[0 * 256],  wr1  = wp[1 * 256],  wr2  = wp[2 * 256];
    uint4 wr3  = wp[3 * 256],  wr4  = wp[4 * 256],  wr5  = wp[5 * 256];
    uint4 wr6  = wp[6 * 256],  wr7  = wp[7 * 256],  wr8  = wp[8 * 256];
    uint4 wr9  = wp[9 * 256],  wr10 = wp[10 * 256], wr11 = wp[11 * 256];

    for (int t = t0; t < tend; t++) {
        int s = t - t0;
        // px loads (kq0 waves only), consumed at combine — pipelined
        float p0, p1, p2, p3, p4, p5, p6, p7;
        if (kq == 0) {
            const float* pxs = pxd + ((size_t)s * B + b0) * G;
            p0 = pxs[j];       p1 = pxs[G + j];
            p2 = pxs[256 + j]; p3 = pxs[G + 256 + j];
            p4 = pxs[512 + j]; p5 = pxs[G + 512 + j];
            p6 = pxs[768 + j]; p7 = pxs[G + 768 + j];
        }
        float a00 = 0.f, a01 = 0.f, a10 = 0.f, a11 = 0.f;
        float a20 = 0.f, a21 = 0.f, a30 = 0.f, a31 = 0.f;

        const float4* hcur = (const float4*)hping[cur] + kq * 32;

        // streamed part first: loads issue early, resident FMAs fill the waits
        #pragma unroll 4
        for (int r = 12; r < 32; r++) {
            uint4 wv = wp[(size_t)r * 256];
            float4 hv = hcur[r];           // wave-uniform -> LDS broadcast
            fma8_(wv, hv, a00, a01, a10, a11, a20, a21, a30, a31);
        }
        // resident part: pure compute
        fma8_(wr0,  hcur[0],  a00, a01, a10, a11, a20, a21, a30, a31);
        fma8_(wr1,  hcur[1],  a00, a01, a10, a11, a20, a21, a30, a31);
        fma8_(wr2,  hcur[2],  a00, a01, a10, a11, a20, a21, a30, a31);
        fma8_(wr3,  hcur[3],  a00, a01, a10, a11, a20, a21, a30, a31);
        fma8_(wr4,  hcur[4],  a00, a01, a10, a11, a20, a21, a30, a31);
        fma8_(wr5,  hcur[5],  a00, a01, a10, a11, a20, a21, a30, a31);
        fma8_(wr6,  hcur[6],  a00, a01, a10, a11, a20, a21, a30, a31);
        fma8_(wr7,  hcur[7],  a00, a01, a10, a11, a20, a21, a30, a31);
        fma8_(wr8,  hcur[8],  a00, a01, a10, a11, a20, a21, a30, a31);
        fma8_(wr9,  hcur[9],  a00, a01, a10, a11, a20, a21, a30, a31);
        fma8_(wr10, hcur[10], a00, a01, a10, a11, a20, a21, a30, a31);
        fma8_(wr11, hcur[11], a00, a01, a10, a11, a20, a21, a30, a31);

        if (kq > 0) {
            part[kq - 1][0][j] = make_float4(a00, a01, a10, a11);
            part[kq - 1][1][j] = make_float4(a20, a21, a30, a31);
        }
        __syncthreads();

        if (kq == 0) {
            #pragma unroll
            for (int q = 0; q < 3; q++) {
                float4 q0 = part[q][0][j];
                float4 q1 = part[q][1][j];
                a00 += q0.x; a01 += q0.y; a10 += q0.z; a11 += q0.w;
                a20 += q1.x; a21 += q1.y; a30 += q1.z; a31 += q1.w;
            }
            a00 += p0; a01 += p1; a10 += p2; a11 += p3;
            a20 += p4; a21 += p5; a30 += p6; a31 += p7;

            float i0 = sigmoidf_(a00), f0 = sigmoidf_(a10), o0 = sigmoidf_(a30);
            c0 = f0 * c0 + i0 * tanhf(a20);
            float h0 = o0 * tanhf(c0);
            float i1 = sigmoidf_(a01), f1 = sigmoidf_(a11), o1 = sigmoidf_(a31);
            c1 = f1 * c1 + i1 * tanhf(a21);
            float h1 = o1 * tanhf(c1);

            hping[cur ^ 1][j] = make_float2(h0, h1);
            if (t < len0) {
                int pos = d ? (len0 - 1 - t) : t;
                hc_out[((size_t)b0 * T + pos) * (2 * H) + d * H + j] = h0;
            }
            if (t < len1) {
                int pos = d ? (len1 - 1 - t) : t;
                hc_out[((size_t)(b0 + 1) * T + pos) * (2 * H) + d * H + j] = h1;
            }
        }
        __syncthreads();
        cur ^= 1;
    }

    if (kq == 0) {
        cstate[((size_t)d * B + b0) * H + j]     = c0;
        cstate[((size_t)d * B + b0 + 1) * H + j] = c1;
        hbufg[j] = hping[cur][j];
    }
}

// ---------------- attention logits (masked) ----------------
__global__ __launch_bounds__(256) void logits_kernel(const int* __restrict__ lengths,
                                                     const float* __restrict__ hc,
                                                     const float* __restrict__ ws1t,
                                                     const float* __restrict__ Ws2,
                                                     float* __restrict__ S) {
    __shared__ float s_w1[512 * DA];
    __shared__ float s_w2[HEADS * DA];
    int b = blockIdx.y, tt = blockIdx.x;
    int tid = threadIdx.x;
    for (int i = tid; i < 512 * DA; i += 256) s_w1[i] = ws1t[i];
    for (int i = tid; i < HEADS * DA; i += 256) s_w2[i] = Ws2[i];
    __syncthreads();

    int len = lengths[b];
    int lane = tid & 63, wave = tid >> 6;
    for (int ti = 0; ti < 16; ti++) {
        int t = tt * 64 + wave * 16 + ti;
        if (t < len) {
            float y[DA];
            #pragma unroll
            for (int r = 0; r < DA; r++) y[r] = 0.f;
            const float* hcp = hc + ((size_t)b * T + t) * (2 * H);
            #pragma unroll
            for (int kk = 0; kk < 8; kk++) {
                int k = lane + kk * 64;
                float v = hcp[k];
                const float* w = s_w1 + k * DA;
                #pragma unroll
                for (int r = 0; r < DA; r++) y[r] += v * w[r];
            }
            #pragma unroll
            for (int r = 0; r < DA; r++) {
                float v = y[r];
                for (int off = 32; off; off >>= 1) v += __shfl_xor(v, off, 64);
                y[r] = tanhf(v);
            }
            if (lane < HEADS) {
                float s = 0.f;
                #pragma unroll
                for (int r = 0; r < DA; r++) s += y[r] * s_w2[lane * DA + r];
                S[((size_t)b * HEADS + lane) * T + t] = s;
            }
        } else {
            if (lane < HEADS) S[((size_t)b * HEADS + lane) * T + t] = NEGINF;
        }
    }
}

// ---------------- masked softmax over T, in place ----------------
__global__ __launch_bounds__(256) void softmax_kernel(float* __restrict__ S) {
    int row = blockIdx.x;
    float* p = S + (size_t)row * T;
    int tid = threadIdx.x;
    int lane = tid & 63, wave = tid >> 6;
    __shared__ float rr[4], ss[4];

    float mx = NEGINF;
    #pragma unroll
    for (int i = 0; i < 2; i++) mx = fmaxf(mx, p[tid + i * 256]);
    for (int off = 32; off; off >>= 1) mx = fmaxf(mx, __shfl_xor(mx, off, 64));
    if (lane == 0) rr[wave] = mx;
    __syncthreads();
    mx = fmaxf(fmaxf(rr[0], rr[1]), fmaxf(rr[2], rr[3]));

    float e[2], sum = 0.f;
    #pragma unroll
    for (int i = 0; i < 2; i++) { e[i] = expf(p[tid + i * 256] - mx); sum += e[i]; }
    for (int off = 32; off; off >>= 1) sum += __shfl_xor(sum, off, 64);
    if (lane == 0) ss[wave] = sum;
    __syncthreads();
    sum = ss[0] + ss[1] + ss[2] + ss[3];
    float inv = 1.f / sum;
    #pragma unroll
    for (int i = 0; i < 2; i++) p[tid + i * 256] = e[i] * inv;
}

// ---------------- M = A @ Hc -> sentence embeddings (d_out) ----------------
__global__ __launch_bounds__(256) void attnM_kernel(const int* __restrict__ lengths,
                                                    const float* __restrict__ A,
                                                    const float* __restrict__ hc,
                                                    float* __restrict__ out) {
    int b = blockIdx.x, tid = threadIdx.x;
    int len = lengths[b];
    const float* Ab  = A + (size_t)b * HEADS * T;
    const float* hcb = hc + (size_t)b * T * (2 * H);
    float acc[HEADS][2];
    #pragma unroll
    for (int h = 0; h < HEADS; h++) { acc[h][0] = 0.f; acc[h][1] = 0.f; }
    for (int t = 0; t < len; t++) {
        float v0 = hcb[(size_t)t * (2 * H) + tid];
        float v1 = hcb[(size_t)t * (2 * H) + H + tid];
        #pragma unroll
        for (int h = 0; h < HEADS; h++) {
            float a = Ab[h * T + t];
            acc[h][0] += a * v0;
            acc[h][1] += a * v1;
        }
    }
    #pragma unroll
    for (int h = 0; h < HEADS; h++) {
        out[(size_t)b * (HEADS * 2 * H) + h * (2 * H) + tid]     = acc[h][0];
        out[(size_t)b * (HEADS * 2 * H) + h * (2 * H) + H + tid] = acc[h][1];
    }
}

// ---------------- penalization ----------------
__global__ __launch_bounds__(256) void penal_kernel(const float* __restrict__ A,
                                                    float* __restrict__ part) {
    int b = blockIdx.x, tid = threadIdx.x;
    const float* Ab = A + (size_t)b * HEADS * T;
    float p[10];
    #pragma unroll
    for (int i = 0; i < 10; i++) p[i] = 0.f;
    for (int t = tid; t < T; t += 256) {
        float a0 = Ab[t], a1 = Ab[T + t], a2 = Ab[2 * T + t], a3 = Ab[3 * T + t], a4 = Ab[4 * T + t];
        p[0] += a0 * a1; p[1] += a0 * a2; p[2] += a0 * a3; p[3] += a0 * a4;
        p[4] += a1 * a2; p[5] += a1 * a3; p[6] += a1 * a4;
        p[7] += a2 * a3; p[8] += a2 * a4; p[9] += a3 * a4;
    }
    __shared__ float red[10][4];
    int lane = tid & 63, wave = tid >> 6;
    #pragma unroll
    for (int i = 0; i < 10; i++) {
        float v = p[i];
        for (int off = 32; off; off >>= 1) v += __shfl_xor(v, off, 64);
        if (lane == 0) red[i][wave] = v;
    }
    __syncthreads();
    if (tid == 0) {
        float s = 0.f;
        #pragma unroll
        for (int i = 0; i < 10; i++) {
            float P = red[i][0] + red[i][1] + red[i][2] + red[i][3];
            s += 2.f * P * P;
        }
        part[b] = s;
    }
}

__global__ __launch_bounds__(128) void final_kernel(const float* __restrict__ part,
                                                    float* __restrict__ out) {
    int tid = threadIdx.x;
    float v = part[tid];
    for (int off = 32; off; off >>= 1) v += __shfl_xor(v, off, 64);
    __shared__ float r2[2];
    if ((tid & 63) == 0) r2[tid >> 6] = v;
    __syncthreads();
    if (tid == 0) out[(size_t)B * HEADS * 2 * H] = (r2[0] + r2[1]) * (1.f / (float)B);
}

// ---------------- host launcher ----------------
extern "C" void kernel_launch(void* const* d_in, const int* in_sizes, int n_in,
                              void* d_out, int out_size, void* d_ws, size_t ws_size,
                              hipStream_t stream) {
    const int*   word_ids = (const int*)d_in[0];
    const int*   lengths  = (const int*)d_in[1];
    const float* emb      = (const float*)d_in[2];
    const float* W_ih_f   = (const float*)d_in[3];
    const float* W_hh_f   = (const float*)d_in[4];
    const float* b_f      = (const float*)d_in[5];
    const float* W_ih_b   = (const float*)d_in[6];
    const float* W_hh_b   = (const float*)d_in[7];
    const float* b_b      = (const float*)d_in[8];
    const float* W_s1     = (const float*)d_in[9];
    const float* W_s2     = (const float*)d_in[10];
    float* out = (float*)d_out;

    char* ws = (char*)d_ws;
    unsigned short* wbt = (unsigned short*)(ws + WBT_OFF);
    float* ws1t   = (float*)(ws + WS1T_OFF);
    float* pxc    = (float*)(ws + PX_OFF);
    float* hc     = (float*)(ws + HC_OFF);
    float* hbuf   = (float*)(ws + HBUF_OFF);
    float* cstate = (float*)(ws + CST_OFF);
    float* Abuf   = (float*)(ws + A_OFF);
    float* part   = (float*)(ws + PART_OFF);

    prep_kernel<<<2048, 256, 0, stream>>>(W_hh_f, W_hh_b, W_s1, wbt, ws1t);

    for (int c = 0; c < 8; c++) {
        proj_kernel<<<dim3(16, 128, 2), 256, 0, stream>>>(
            word_ids, lengths, emb, W_ih_f, W_ih_b, b_f, b_b, pxc, c);
        lstm4_kernel<<<dim3(64, 2), 1024, 0, stream>>>(
            lengths, wbt, pxc, hc, hbuf, cstate, c);
    }

    logits_kernel<<<dim3(8, 128), 256, 0, stream>>>(lengths, hc, ws1t, W_s2, Abuf);
    softmax_kernel<<<B * HEADS, 256, 0, stream>>>(Abuf);
    attnM_kernel<<<B, 256, 0, stream>>>(lengths, Abuf, hc, out);
    penal_kernel<<<B, 256, 0, stream>>>(Abuf, part);
    final_kernel<<<1, 128, 0, stream>>>(part, out);
}

// Round 11
// 3663.869 us; speedup vs baseline: 3.8156x; 3.8156x over previous
//
#include <hip/hip_runtime.h>
#include <math.h>

#define T 512
#define B 128
#define E 256
#define H 256
#define G 1024   // 4H
#define DA 25
#define HEADS 5
#define NEGINF (-1e30f)

// ---------------- workspace layout (bytes) ----------------
static constexpr size_t WBT_OFF  = 0;           // [2][128 k2][256 j][8] ushort (bf16 W_hh^T) 1,048,576
static constexpr size_t WS1T_OFF = 2097152;     // [512][25] f32                  51,200
static constexpr size_t PX_OFF   = 2148352;     // [2][64][128][1024] f32     67,108,864
static constexpr size_t HC_OFF   = 69257216;    // [128][512][512] f32       134,217,728
static constexpr size_t HBUF_OFF = 203474944;   // [2][128 b][256 j] f32         262,144
static constexpr size_t CST_OFF  = 203737088;   // [2][128][256] f32 c-state     262,144
static constexpr size_t A_OFF    = 203999232;   // [128][5][512] f32           1,310,720
static constexpr size_t PART_OFF = 205309952;   // [128] f32                         512

__device__ __forceinline__ float sigmoidf_(float x) { return 1.f / (1.f + expf(-x)); }
__device__ __forceinline__ float blo_(unsigned u) { return __uint_as_float(u << 16); }
__device__ __forceinline__ float bhi_(unsigned u) { return __uint_as_float(u & 0xffff0000u); }

__device__ __forceinline__ unsigned short f2bf_(float f) {   // RNE bf16
    unsigned u = __float_as_uint(f);
    unsigned r = (u + 0x7fffu + ((u >> 16) & 1u)) >> 16;
    return (unsigned short)r;
}

// 8 FMAs for one k-pair: 4 gates x 1 sample x 2 k
__device__ __forceinline__ void fma4_(uint4 wv, float2 h2,
                                      float& a0, float& a1, float& a2, float& a3) {
    float w0e = blo_(wv.x), w1e = bhi_(wv.x);
    float w2e = blo_(wv.y), w3e = bhi_(wv.y);
    float w0o = blo_(wv.z), w1o = bhi_(wv.z);
    float w2o = blo_(wv.w), w3o = bhi_(wv.w);
    a0 = fmaf(w0e, h2.x, a0); a1 = fmaf(w1e, h2.x, a1);
    a2 = fmaf(w2e, h2.x, a2); a3 = fmaf(w3e, h2.x, a3);
    a0 = fmaf(w0o, h2.y, a0); a1 = fmaf(w1o, h2.y, a1);
    a2 = fmaf(w2o, h2.y, a2); a3 = fmaf(w3o, h2.y, a3);
}

// ---------------- prep: pack W_hh (bf16, k-pair/gate interleaved) + W_s1^T --
// wbt layout: [(d*128 + k2)*256 + j]*8 + ke*4 + gate  (ushort)
__global__ __launch_bounds__(256) void prep_kernel(const float* __restrict__ Whf,
                                                   const float* __restrict__ Whb,
                                                   const float* __restrict__ Ws1,
                                                   unsigned short* __restrict__ wbt,
                                                   float* __restrict__ ws1t) {
    int idx = blockIdx.x * 256 + threadIdx.x;
    if (idx < 2 * G * H) {
        int d = idx >> 18;
        int rem = idx & 262143;
        int r = rem >> 8;                        // gate row 0..1023
        int k = rem & 255;                       // h index
        const float* W = d ? Whb : Whf;
        int gate = r >> 8, j = r & 255;
        int k2 = k >> 1, ke = k & 1;
        wbt[(((size_t)d * 128 + k2) * 256 + j) * 8 + ke * 4 + gate] = f2bf_(W[(size_t)r * H + k]);
    }
    if (idx < DA * 512) {
        int r = idx / 512, k = idx % 512;
        ws1t[k * DA + r] = Ws1[idx];
    }
}

// ---------------- input projection for one 64-step chunk ----------------
// grid (16 gtiles, 128 b, 2 dir), block 256
__global__ __launch_bounds__(256) void proj_kernel(const int* __restrict__ word_ids,
                                                   const int* __restrict__ lengths,
                                                   const float* __restrict__ emb,
                                                   const float* __restrict__ Wf,
                                                   const float* __restrict__ Wb,
                                                   const float* __restrict__ bf,
                                                   const float* __restrict__ bb,
                                                   float* __restrict__ pxc, int chunk) {
    int g0 = blockIdx.x * 64;
    int b  = blockIdx.y;
    int d  = blockIdx.z;
    int len = lengths[b];
    int t0 = chunk * 64;
    if (t0 >= len) return;
    const float* Wih  = d ? Wb : Wf;
    const float* bias = d ? bb : bf;

    __shared__ int   wid[64];
    __shared__ float As[64][17];   // [m][kk], k-minor, padded
    __shared__ float Bs[64][17];

    int tid = threadIdx.x;
    if (tid < 64) {
        int t = t0 + tid;
        int src;
        if (d == 0) src = t;
        else { src = len - 1 - t; if (src < 0) src = 0; }
        wid[tid] = word_ids[b * T + src];
    }
    __syncthreads();

    int tx = tid & 15, ty = tid >> 4;   // compute mapping
    int kk = tid & 15, r0 = tid >> 4;   // load mapping
    float acc[4][4];
    #pragma unroll
    for (int i = 0; i < 4; i++)
        #pragma unroll
        for (int j = 0; j < 4; j++) acc[i][j] = 0.f;

    for (int k0 = 0; k0 < E; k0 += 16) {
        #pragma unroll
        for (int i = 0; i < 4; i++) {
            int m = r0 + 16 * i;
            As[m][kk] = emb[(size_t)wid[m] * E + k0 + kk];
            Bs[m][kk] = Wih[(size_t)(g0 + m) * E + k0 + kk];
        }
        __syncthreads();
        #pragma unroll
        for (int kq = 0; kq < 16; kq++) {
            float a[4], bv[4];
            #pragma unroll
            for (int i = 0; i < 4; i++) a[i] = As[ty * 4 + i][kq];
            #pragma unroll
            for (int j = 0; j < 4; j++) bv[j] = Bs[tx * 4 + j][kq];
            #pragma unroll
            for (int i = 0; i < 4; i++)
                #pragma unroll
                for (int j = 0; j < 4; j++) acc[i][j] += a[i] * bv[j];
        }
        __syncthreads();
    }
    #pragma unroll
    for (int i = 0; i < 4; i++) {
        int m = ty * 4 + i;
        #pragma unroll
        for (int j = 0; j < 4; j++) {
            int n = tx * 4 + j;
            pxc[((size_t)(d * 64 + m) * B + b) * G + g0 + n] = acc[i][j] + bias[g0 + n];
        }
    }
}

// ---------------- LSTM recurrence: 1 sample/block, all 256 CUs ----------
// grid (128 b, 2 dir); block 1024 = 16 waves (round-7 skeleton, VGPR ~48,
// no resident W, no allocator games). Thread (j = tid&255, kq = tid>>8):
// k-slice [kq*64, kq*64+64) = 32 k-pairs for hidden col j, 4 gates, 1 sample.
// W_hh^T bf16 streamed from L2 (512 KB/step/CU). Cross-kq reduce via LDS.
__global__ __launch_bounds__(1024) void lstm5_kernel(const int* __restrict__ lengths,
                                                     const unsigned short* __restrict__ wbt,
                                                     const float* __restrict__ pxc,
                                                     float* __restrict__ hc_out,
                                                     float* __restrict__ hbuf,
                                                     float* __restrict__ cstate,
                                                     int chunk) {
    int b   = blockIdx.x;
    int d   = blockIdx.y;
    int tid = threadIdx.x;
    int j  = tid & 255;
    int kq = tid >> 8;                 // 0..3 (wave-uniform)

    int len = lengths[b];
    int t0 = chunk * 64;
    if (t0 >= len) return;
    int tend = min(t0 + 64, len);      // every t in [t0,tend) is < len

    __shared__ float  hping[2][256];   // [buf][k] = h[k]
    __shared__ float4 part[3][257];    // kq=1..3 partials (4 gates), padded

    float* hbufg = hbuf + ((size_t)d * B + b) * 256;

    float c = 0.f;
    int cur = 0;
    if (chunk == 0) {
        if (tid < 256) hping[0][tid] = 0.f;
    } else if (kq == 0) {
        c = cstate[((size_t)d * B + b) * H + j];
        hping[0][j] = hbufg[j];
    }
    __syncthreads();

    // thread's W rows: k2 in [kq*32, kq*32+32), column j
    const uint4* wp  = (const uint4*)wbt + (size_t)d * 128 * 256 + (size_t)(kq * 32) * 256 + j;
    const float* pxd = pxc + (size_t)d * 64 * B * G;

    for (int t = t0; t < tend; t++) {
        int s = t - t0;
        // px loads (kq0 waves only), consumed after the barrier — pipelined
        float p0, p1, p2, p3;
        if (kq == 0) {
            const float* pxs = pxd + ((size_t)s * B + b) * G;
            p0 = pxs[j];
            p1 = pxs[256 + j];
            p2 = pxs[512 + j];
            p3 = pxs[768 + j];
        }
        float a0 = 0.f, a1 = 0.f, a2 = 0.f, a3 = 0.f;

        const float2* hcur = (const float2*)hping[cur] + kq * 32;
        #pragma unroll 4
        for (int k2 = 0; k2 < 32; k2++) {
            uint4 wv = wp[(size_t)k2 * 256];
            float2 h2 = hcur[k2];          // wave-uniform address -> broadcast
            fma4_(wv, h2, a0, a1, a2, a3);
        }

        if (kq > 0) part[kq - 1][j] = make_float4(a0, a1, a2, a3);
        __syncthreads();

        if (kq == 0) {
            #pragma unroll
            for (int q = 0; q < 3; q++) {
                float4 qv = part[q][j];
                a0 += qv.x; a1 += qv.y; a2 += qv.z; a3 += qv.w;
            }
            a0 += p0; a1 += p1; a2 += p2; a3 += p3;

            float ig = sigmoidf_(a0), fg = sigmoidf_(a1), og = sigmoidf_(a3);
            c = fg * c + ig * tanhf(a2);
            float h = og * tanhf(c);

            hping[cur ^ 1][j] = h;
            int pos = d ? (len - 1 - t) : t;
            hc_out[((size_t)b * T + pos) * (2 * H) + d * H + j] = h;
        }
        __syncthreads();
        cur ^= 1;
    }

    if (kq == 0) {
        cstate[((size_t)d * B + b) * H + j] = c;
        hbufg[j] = hping[cur][j];
    }
}

// ---------------- attention logits (masked) ----------------
__global__ __launch_bounds__(256) void logits_kernel(const int* __restrict__ lengths,
                                                     const float* __restrict__ hc,
                                                     const float* __restrict__ ws1t,
                                                     const float* __restrict__ Ws2,
                                                     float* __restrict__ S) {
    __shared__ float s_w1[512 * DA];
    __shared__ float s_w2[HEADS * DA];
    int b = blockIdx.y, tt = blockIdx.x;
    int tid = threadIdx.x;
    for (int i = tid; i < 512 * DA; i += 256) s_w1[i] = ws1t[i];
    for (int i = tid; i < HEADS * DA; i += 256) s_w2[i] = Ws2[i];
    __syncthreads();

    int len = lengths[b];
    int lane = tid & 63, wave = tid >> 6;
    for (int ti = 0; ti < 16; ti++) {
        int t = tt * 64 + wave * 16 + ti;
        if (t < len) {
            float y[DA];
            #pragma unroll
            for (int r = 0; r < DA; r++) y[r] = 0.f;
            const float* hcp = hc + ((size_t)b * T + t) * (2 * H);
            #pragma unroll
            for (int kk = 0; kk < 8; kk++) {
                int k = lane + kk * 64;
                float v = hcp[k];
                const float* w = s_w1 + k * DA;
                #pragma unroll
                for (int r = 0; r < DA; r++) y[r] += v * w[r];
            }
            #pragma unroll
            for (int r = 0; r < DA; r++) {
                float v = y[r];
                for (int off = 32; off; off >>= 1) v += __shfl_xor(v, off, 64);
                y[r] = tanhf(v);
            }
            if (lane < HEADS) {
                float s = 0.f;
                #pragma unroll
                for (int r = 0; r < DA; r++) s += y[r] * s_w2[lane * DA + r];
                S[((size_t)b * HEADS + lane) * T + t] = s;
            }
        } else {
            if (lane < HEADS) S[((size_t)b * HEADS + lane) * T + t] = NEGINF;
        }
    }
}

// ---------------- masked softmax over T, in place ----------------
__global__ __launch_bounds__(256) void softmax_kernel(float* __restrict__ S) {
    int row = blockIdx.x;
    float* p = S + (size_t)row * T;
    int tid = threadIdx.x;
    int lane = tid & 63, wave = tid >> 6;
    __shared__ float rr[4], ss[4];

    float mx = NEGINF;
    #pragma unroll
    for (int i = 0; i < 2; i++) mx = fmaxf(mx, p[tid + i * 256]);
    for (int off = 32; off; off >>= 1) mx = fmaxf(mx, __shfl_xor(mx, off, 64));
    if (lane == 0) rr[wave] = mx;
    __syncthreads();
    mx = fmaxf(fmaxf(rr[0], rr[1]), fmaxf(rr[2], rr[3]));

    float e[2], sum = 0.f;
    #pragma unroll
    for (int i = 0; i < 2; i++) { e[i] = expf(p[tid + i * 256] - mx); sum += e[i]; }
    for (int off = 32; off; off >>= 1) sum += __shfl_xor(sum, off, 64);
    if (lane == 0) ss[wave] = sum;
    __syncthreads();
    sum = ss[0] + ss[1] + ss[2] + ss[3];
    float inv = 1.f / sum;
    #pragma unroll
    for (int i = 0; i < 2; i++) p[tid + i * 256] = e[i] * inv;
}

// ---------------- M = A @ Hc -> sentence embeddings (d_out) ----------------
__global__ __launch_bounds__(256) void attnM_kernel(const int* __restrict__ lengths,
                                                    const float* __restrict__ A,
                                                    const float* __restrict__ hc,
                                                    float* __restrict__ out) {
    int b = blockIdx.x, tid = threadIdx.x;
    int len = lengths[b];
    const float* Ab  = A + (size_t)b * HEADS * T;
    const float* hcb = hc + (size_t)b * T * (2 * H);
    float acc[HEADS][2];
    #pragma unroll
    for (int h = 0; h < HEADS; h++) { acc[h][0] = 0.f; acc[h][1] = 0.f; }
    for (int t = 0; t < len; t++) {
        float v0 = hcb[(size_t)t * (2 * H) + tid];
        float v1 = hcb[(size_t)t * (2 * H) + H + tid];
        #pragma unroll
        for (int h = 0; h < HEADS; h++) {
            float a = Ab[h * T + t];
            acc[h][0] += a * v0;
            acc[h][1] += a * v1;
        }
    }
    #pragma unroll
    for (int h = 0; h < HEADS; h++) {
        out[(size_t)b * (HEADS * 2 * H) + h * (2 * H) + tid]     = acc[h][0];
        out[(size_t)b * (HEADS * 2 * H) + h * (2 * H) + H + tid] = acc[h][1];
    }
}

// ---------------- penalization ----------------
__global__ __launch_bounds__(256) void penal_kernel(const float* __restrict__ A,
                                                    float* __restrict__ part) {
    int b = blockIdx.x, tid = threadIdx.x;
    const float* Ab = A + (size_t)b * HEADS * T;
    float p[10];
    #pragma unroll
    for (int i = 0; i < 10; i++) p[i] = 0.f;
    for (int t = tid; t < T; t += 256) {
        float a0 = Ab[t], a1 = Ab[T + t], a2 = Ab[2 * T + t], a3 = Ab[3 * T + t], a4 = Ab[4 * T + t];
        p[0] += a0 * a1; p[1] += a0 * a2; p[2] += a0 * a3; p[3] += a0 * a4;
        p[4] += a1 * a2; p[5] += a1 * a3; p[6] += a1 * a4;
        p[7] += a2 * a3; p[8] += a2 * a4; p[9] += a3 * a4;
    }
    __shared__ float red[10][4];
    int lane = tid & 63, wave = tid >> 6;
    #pragma unroll
    for (int i = 0; i < 10; i++) {
        float v = p[i];
        for (int off = 32; off; off >>= 1) v += __shfl_xor(v, off, 64);
        if (lane == 0) red[i][wave] = v;
    }
    __syncthreads();
    if (tid == 0) {
        float s = 0.f;
        #pragma unroll
        for (int i = 0; i < 10; i++) {
            float P = red[i][0] + red[i][1] + red[i][2] + red[i][3];
            s += 2.f * P * P;
        }
        part[b] = s;
    }
}

__global__ __launch_bounds__(128) void final_kernel(const float* __restrict__ part,
                                                    float* __restrict__ out) {
    int tid = threadIdx.x;
    float v = part[tid];
    for (int off = 32; off; off >>= 1) v += __shfl_xor(v, off, 64);
    __shared__ float r2[2];
    if ((tid & 63) == 0) r2[tid >> 6] = v;
    __syncthreads();
    if (tid == 0) out[(size_t)B * HEADS * 2 * H] = (r2[0] + r2[1]) * (1.f / (float)B);
}

// ---------------- host launcher ----------------
extern "C" void kernel_launch(void* const* d_in, const int* in_sizes, int n_in,
                              void* d_out, int out_size, void* d_ws, size_t ws_size,
                              hipStream_t stream) {
    const int*   word_ids = (const int*)d_in[0];
    const int*   lengths  = (const int*)d_in[1];
    const float* emb      = (const float*)d_in[2];
    const float* W_ih_f   = (const float*)d_in[3];
    const float* W_hh_f   = (const float*)d_in[4];
    const float* b_f      = (const float*)d_in[5];
    const float* W_ih_b   = (const float*)d_in[6];
    const float* W_hh_b   = (const float*)d_in[7];
    const float* b_b      = (const float*)d_in[8];
    const float* W_s1     = (const float*)d_in[9];
    const float* W_s2     = (const float*)d_in[10];
    float* out = (float*)d_out;

    char* ws = (char*)d_ws;
    unsigned short* wbt = (unsigned short*)(ws + WBT_OFF);
    float* ws1t   = (float*)(ws + WS1T_OFF);
    float* pxc    = (float*)(ws + PX_OFF);
    float* hc     = (float*)(ws + HC_OFF);
    float* hbuf   = (float*)(ws + HBUF_OFF);
    float* cstate = (float*)(ws + CST_OFF);
    float* Abuf   = (float*)(ws + A_OFF);
    float* part   = (float*)(ws + PART_OFF);

    prep_kernel<<<2048, 256, 0, stream>>>(W_hh_f, W_hh_b, W_s1, wbt, ws1t);

    for (int c = 0; c < 8; c++) {
        proj_kernel<<<dim3(16, 128, 2), 256, 0, stream>>>(
            word_ids, lengths, emb, W_ih_f, W_ih_b, b_f, b_b, pxc, c);
        lstm5_kernel<<<dim3(128, 2), 1024, 0, stream>>>(
            lengths, wbt, pxc, hc, hbuf, cstate, c);
    }

    logits_kernel<<<dim3(8, 128), 256, 0, stream>>>(lengths, hc, ws1t, W_s2, Abuf);
    softmax_kernel<<<B * HEADS, 256, 0, stream>>>(Abuf);
    attnM_kernel<<<B, 256, 0, stream>>>(lengths, Abuf, hc, out);
    penal_kernel<<<B, 256, 0, stream>>>(Abuf, part);
    final_kernel<<<1, 128, 0, stream>>>(part, out);
}

// Round 12
// 3650.985 us; speedup vs baseline: 3.8290x; 1.0035x over previous
//
#include <hip/hip_runtime.h>
#include <math.h>

#define T 512
#define B 128
#define E 256
#define H 256
#define G 1024   // 4H
#define DA 25
#define HEADS 5
#define NEGINF (-1e30f)

// ---------------- workspace layout (bytes) ----------------
static constexpr size_t WBT_OFF  = 0;           // [2][128 k2][256 j][4 gate] uint (f16 pair) 1,048,576
static constexpr size_t WS1T_OFF = 2097152;     // [512][25] f32                  51,200
static constexpr size_t PX_OFF   = 2148352;     // [2][64][128][1024] f32     67,108,864
static constexpr size_t HC_OFF   = 69257216;    // [128][512][512] f32       134,217,728
static constexpr size_t HBUF_OFF = 203474944;   // [2][128 b][256 j] f32         262,144
static constexpr size_t CST_OFF  = 203737088;   // [2][128][256] f32 c-state     262,144
static constexpr size_t A_OFF    = 203999232;   // [128][5][512] f32           1,310,720
static constexpr size_t PART_OFF = 205309952;   // [128] f32                         512

typedef _Float16 half2v __attribute__((ext_vector_type(2)));

__device__ __forceinline__ float sigmoidf_(float x) { return 1.f / (1.f + expf(-x)); }

__device__ __forceinline__ unsigned short f2h_(float f) {   // f32 -> f16 bits
    _Float16 h = (_Float16)f;
    unsigned short u;
    __builtin_memcpy(&u, &h, 2);
    return u;
}

// dot2: acc += w.lo*h.lo + w.hi*h.hi  (f32 accumulate)
__device__ __forceinline__ float fdot2_(unsigned w, half2v h, float acc) {
#if __has_builtin(__builtin_amdgcn_fdot2)
    half2v wv;
    __builtin_memcpy(&wv, &w, 4);
    return __builtin_amdgcn_fdot2(wv, h, acc, false);
#else
    unsigned short lo = (unsigned short)(w & 0xffffu), hi = (unsigned short)(w >> 16);
    _Float16 w0, w1;
    __builtin_memcpy(&w0, &lo, 2);
    __builtin_memcpy(&w1, &hi, 2);
    return fmaf((float)w0, (float)h[0], fmaf((float)w1, (float)h[1], acc));
#endif
}

// ---------------- prep: pack W_hh (f16, gate-major dwords) + W_s1^T --------
// wbt ushort layout: [((d*128 + k2)*256 + j)*8 + gate*2 + ke]
// -> dword g of the (k2,j) uint4 = (w[2k2][g*256+j], w[2k2+1][g*256+j]) f16x2
__global__ __launch_bounds__(256) void prep_kernel(const float* __restrict__ Whf,
                                                   const float* __restrict__ Whb,
                                                   const float* __restrict__ Ws1,
                                                   unsigned short* __restrict__ wbt,
                                                   float* __restrict__ ws1t) {
    int idx = blockIdx.x * 256 + threadIdx.x;
    if (idx < 2 * G * H) {
        int d = idx >> 18;
        int rem = idx & 262143;
        int r = rem >> 8;                        // gate row 0..1023
        int k = rem & 255;                       // h index
        const float* W = d ? Whb : Whf;
        int gate = r >> 8, j = r & 255;
        int k2 = k >> 1, ke = k & 1;
        wbt[(((size_t)d * 128 + k2) * 256 + j) * 8 + gate * 2 + ke] = f2h_(W[(size_t)r * H + k]);
    }
    if (idx < DA * 512) {
        int r = idx / 512, k = idx % 512;
        ws1t[k * DA + r] = Ws1[idx];
    }
}

// ---------------- input projection for one 64-step chunk ----------------
// grid (16 gtiles, 128 b, 2 dir), block 256
__global__ __launch_bounds__(256) void proj_kernel(const int* __restrict__ word_ids,
                                                   const int* __restrict__ lengths,
                                                   const float* __restrict__ emb,
                                                   const float* __restrict__ Wf,
                                                   const float* __restrict__ Wb,
                                                   const float* __restrict__ bf,
                                                   const float* __restrict__ bb,
                                                   float* __restrict__ pxc, int chunk) {
    int g0 = blockIdx.x * 64;
    int b  = blockIdx.y;
    int d  = blockIdx.z;
    int len = lengths[b];
    int t0 = chunk * 64;
    if (t0 >= len) return;
    const float* Wih  = d ? Wb : Wf;
    const float* bias = d ? bb : bf;

    __shared__ int   wid[64];
    __shared__ float As[64][17];   // [m][kk], k-minor, padded
    __shared__ float Bs[64][17];

    int tid = threadIdx.x;
    if (tid < 64) {
        int t = t0 + tid;
        int src;
        if (d == 0) src = t;
        else { src = len - 1 - t; if (src < 0) src = 0; }
        wid[tid] = word_ids[b * T + src];
    }
    __syncthreads();

    int tx = tid & 15, ty = tid >> 4;   // compute mapping
    int kk = tid & 15, r0 = tid >> 4;   // load mapping
    float acc[4][4];
    #pragma unroll
    for (int i = 0; i < 4; i++)
        #pragma unroll
        for (int j = 0; j < 4; j++) acc[i][j] = 0.f;

    for (int k0 = 0; k0 < E; k0 += 16) {
        #pragma unroll
        for (int i = 0; i < 4; i++) {
            int m = r0 + 16 * i;
            As[m][kk] = emb[(size_t)wid[m] * E + k0 + kk];
            Bs[m][kk] = Wih[(size_t)(g0 + m) * E + k0 + kk];
        }
        __syncthreads();
        #pragma unroll
        for (int kq = 0; kq < 16; kq++) {
            float a[4], bv[4];
            #pragma unroll
            for (int i = 0; i < 4; i++) a[i] = As[ty * 4 + i][kq];
            #pragma unroll
            for (int j = 0; j < 4; j++) bv[j] = Bs[tx * 4 + j][kq];
            #pragma unroll
            for (int i = 0; i < 4; i++)
                #pragma unroll
                for (int j = 0; j < 4; j++) acc[i][j] += a[i] * bv[j];
        }
        __syncthreads();
    }
    #pragma unroll
    for (int i = 0; i < 4; i++) {
        int m = ty * 4 + i;
        #pragma unroll
        for (int j = 0; j < 4; j++) {
            int n = tx * 4 + j;
            pxc[((size_t)(d * 64 + m) * B + b) * G + g0 + n] = acc[i][j] + bias[g0 + n];
        }
    }
}

// ---------------- LSTM recurrence: 1 sample/block, all 256 CUs ----------
// grid (128 b, 2 dir); block 1024 = 16 waves (round-11 skeleton, VGPR ~36,
// no spill). Thread (j = tid&255, kq = tid>>8): k-slice [kq*64, kq*64+64) =
// 32 k-pairs for hidden col j, 4 gates, 1 sample.
// W_hh^T as f16 pairs streamed from L2 (512 KB/step/CU); per k-pair the dot
// is 1 pack-cvt + 4 v_dot2_f32_f16 (was 8 unpack + 8 fma with bf16) —
// cuts per-step VALU from ~512 to ~200 ops/thread. Cross-kq reduce via LDS.
__global__ __launch_bounds__(1024) void lstm5_kernel(const int* __restrict__ lengths,
                                                     const unsigned* __restrict__ wbt,
                                                     const float* __restrict__ pxc,
                                                     float* __restrict__ hc_out,
                                                     float* __restrict__ hbuf,
                                                     float* __restrict__ cstate,
                                                     int chunk) {
    int b   = blockIdx.x;
    int d   = blockIdx.y;
    int tid = threadIdx.x;
    int j  = tid & 255;
    int kq = tid >> 8;                 // 0..3 (wave-uniform)

    int len = lengths[b];
    int t0 = chunk * 64;
    if (t0 >= len) return;
    int tend = min(t0 + 64, len);      // every t in [t0,tend) is < len

    __shared__ float  hping[2][256];   // [buf][k] = h[k]
    __shared__ float4 part[3][257];    // kq=1..3 partials (4 gates), padded

    float* hbufg = hbuf + ((size_t)d * B + b) * 256;

    float c = 0.f;
    int cur = 0;
    if (chunk == 0) {
        if (tid < 256) hping[0][tid] = 0.f;
    } else if (kq == 0) {
        c = cstate[((size_t)d * B + b) * H + j];
        hping[0][j] = hbufg[j];
    }
    __syncthreads();

    // thread's W rows: k2 in [kq*32, kq*32+32), column j
    const uint4* wp  = (const uint4*)wbt + ((size_t)d * 128 + kq * 32) * 256 + j;
    const float* pxd = pxc + (size_t)d * 64 * B * G;

    for (int t = t0; t < tend; t++) {
        int s = t - t0;
        // px loads (kq0 waves only), consumed after the barrier — pipelined
        float p0, p1, p2, p3;
        if (kq == 0) {
            const float* pxs = pxd + ((size_t)s * B + b) * G;
            p0 = pxs[j];
            p1 = pxs[256 + j];
            p2 = pxs[512 + j];
            p3 = pxs[768 + j];
        }
        float a0 = 0.f, a1 = 0.f, a2 = 0.f, a3 = 0.f;

        const float2* hcur = (const float2*)hping[cur] + kq * 32;
        #pragma unroll 4
        for (int k2 = 0; k2 < 32; k2++) {
            uint4 wv = wp[(size_t)k2 * 256];
            float2 h2 = hcur[k2];          // wave-uniform address -> broadcast
            half2v hh;
            hh[0] = (_Float16)h2.x;
            hh[1] = (_Float16)h2.y;
            a0 = fdot2_(wv.x, hh, a0);
            a1 = fdot2_(wv.y, hh, a1);
            a2 = fdot2_(wv.z, hh, a2);
            a3 = fdot2_(wv.w, hh, a3);
        }

        if (kq > 0) part[kq - 1][j] = make_float4(a0, a1, a2, a3);
        __syncthreads();

        if (kq == 0) {
            #pragma unroll
            for (int q = 0; q < 3; q++) {
                float4 qv = part[q][j];
                a0 += qv.x; a1 += qv.y; a2 += qv.z; a3 += qv.w;
            }
            a0 += p0; a1 += p1; a2 += p2; a3 += p3;

            float ig = sigmoidf_(a0), fg = sigmoidf_(a1), og = sigmoidf_(a3);
            c = fg * c + ig * tanhf(a2);
            float h = og * tanhf(c);

            hping[cur ^ 1][j] = h;
            int pos = d ? (len - 1 - t) : t;
            hc_out[((size_t)b * T + pos) * (2 * H) + d * H + j] = h;
        }
        __syncthreads();
        cur ^= 1;
    }

    if (kq == 0) {
        cstate[((size_t)d * B + b) * H + j] = c;
        hbufg[j] = hping[cur][j];
    }
}

// ---------------- attention logits (masked) ----------------
__global__ __launch_bounds__(256) void logits_kernel(const int* __restrict__ lengths,
                                                     const float* __restrict__ hc,
                                                     const float* __restrict__ ws1t,
                                                     const float* __restrict__ Ws2,
                                                     float* __restrict__ S) {
    __shared__ float s_w1[512 * DA];
    __shared__ float s_w2[HEADS * DA];
    int b = blockIdx.y, tt = blockIdx.x;
    int tid = threadIdx.x;
    for (int i = tid; i < 512 * DA; i += 256) s_w1[i] = ws1t[i];
    for (int i = tid; i < HEADS * DA; i += 256) s_w2[i] = Ws2[i];
    __syncthreads();

    int len = lengths[b];
    int lane = tid & 63, wave = tid >> 6;
    for (int ti = 0; ti < 16; ti++) {
        int t = tt * 64 + wave * 16 + ti;
        if (t < len) {
            float y[DA];
            #pragma unroll
            for (int r = 0; r < DA; r++) y[r] = 0.f;
            const float* hcp = hc + ((size_t)b * T + t) * (2 * H);
            #pragma unroll
            for (int kk = 0; kk < 8; kk++) {
                int k = lane + kk * 64;
                float v = hcp[k];
                const float* w = s_w1 + k * DA;
                #pragma unroll
                for (int r = 0; r < DA; r++) y[r] += v * w[r];
            }
            #pragma unroll
            for (int r = 0; r < DA; r++) {
                float v = y[r];
                for (int off = 32; off; off >>= 1) v += __shfl_xor(v, off, 64);
                y[r] = tanhf(v);
            }
            if (lane < HEADS) {
                float s = 0.f;
                #pragma unroll
                for (int r = 0; r < DA; r++) s += y[r] * s_w2[lane * DA + r];
                S[((size_t)b * HEADS + lane) * T + t] = s;
            }
        } else {
            if (lane < HEADS) S[((size_t)b * HEADS + lane) * T + t] = NEGINF;
        }
    }
}

// ---------------- masked softmax over T, in place ----------------
__global__ __launch_bounds__(256) void softmax_kernel(float* __restrict__ S) {
    int row = blockIdx.x;
    float* p = S + (size_t)row * T;
    int tid = threadIdx.x;
    int lane = tid & 63, wave = tid >> 6;
    __shared__ float rr[4], ss[4];

    float mx = NEGINF;
    #pragma unroll
    for (int i = 0; i < 2; i++) mx = fmaxf(mx, p[tid + i * 256]);
    for (int off = 32; off; off >>= 1) mx = fmaxf(mx, __shfl_xor(mx, off, 64));
    if (lane == 0) rr[wave] = mx;
    __syncthreads();
    mx = fmaxf(fmaxf(rr[0], rr[1]), fmaxf(rr[2], rr[3]));

    float e[2], sum = 0.f;
    #pragma unroll
    for (int i = 0; i < 2; i++) { e[i] = expf(p[tid + i * 256] - mx); sum += e[i]; }
    for (int off = 32; off; off >>= 1) sum += __shfl_xor(sum, off, 64);
    if (lane == 0) ss[wave] = sum;
    __syncthreads();
    sum = ss[0] + ss[1] + ss[2] + ss[3];
    float inv = 1.f / sum;
    #pragma unroll
    for (int i = 0; i < 2; i++) p[tid + i * 256] = e[i] * inv;
}

// ---------------- M = A @ Hc -> sentence embeddings (d_out) ----------------
__global__ __launch_bounds__(256) void attnM_kernel(const int* __restrict__ lengths,
                                                    const float* __restrict__ A,
                                                    const float* __restrict__ hc,
                                                    float* __restrict__ out) {
    int b = blockIdx.x, tid = threadIdx.x;
    int len = lengths[b];
    const float* Ab  = A + (size_t)b * HEADS * T;
    const float* hcb = hc + (size_t)b * T * (2 * H);
    float acc[HEADS][2];
    #pragma unroll
    for (int h = 0; h < HEADS; h++) { acc[h][0] = 0.f; acc[h][1] = 0.f; }
    for (int t = 0; t < len; t++) {
        float v0 = hcb[(size_t)t * (2 * H) + tid];
        float v1 = hcb[(size_t)t * (2 * H) + H + tid];
        #pragma unroll
        for (int h = 0; h < HEADS; h++) {
            float a = Ab[h * T + t];
            acc[h][0] += a * v0;
            acc[h][1] += a * v1;
        }
    }
    #pragma unroll
    for (int h = 0; h < HEADS; h++) {
        out[(size_t)b * (HEADS * 2 * H) + h * (2 * H) + tid]     = acc[h][0];
        out[(size_t)b * (HEADS * 2 * H) + h * (2 * H) + H + tid] = acc[h][1];
    }
}

// ---------------- penalization ----------------
__global__ __launch_bounds__(256) void penal_kernel(const float* __restrict__ A,
                                                    float* __restrict__ part) {
    int b = blockIdx.x, tid = threadIdx.x;
    const float* Ab = A + (size_t)b * HEADS * T;
    float p[10];
    #pragma unroll
    for (int i = 0; i < 10; i++) p[i] = 0.f;
    for (int t = tid; t < T; t += 256) {
        float a0 = Ab[t], a1 = Ab[T + t], a2 = Ab[2 * T + t], a3 = Ab[3 * T + t], a4 = Ab[4 * T + t];
        p[0] += a0 * a1; p[1] += a0 * a2; p[2] += a0 * a3; p[3] += a0 * a4;
        p[4] += a1 * a2; p[5] += a1 * a3; p[6] += a1 * a4;
        p[7] += a2 * a3; p[8] += a2 * a4; p[9] += a3 * a4;
    }
    __shared__ float red[10][4];
    int lane = tid & 63, wave = tid >> 6;
    #pragma unroll
    for (int i = 0; i < 10; i++) {
        float v = p[i];
        for (int off = 32; off; off >>= 1) v += __shfl_xor(v, off, 64);
        if (lane == 0) red[i][wave] = v;
    }
    __syncthreads();
    if (tid == 0) {
        float s = 0.f;
        #pragma unroll
        for (int i = 0; i < 10; i++) {
            float P = red[i][0] + red[i][1] + red[i][2] + red[i][3];
            s += 2.f * P * P;
        }
        part[b] = s;
    }
}

__global__ __launch_bounds__(128) void final_kernel(const float* __restrict__ part,
                                                    float* __restrict__ out) {
    int tid = threadIdx.x;
    float v = part[tid];
    for (int off = 32; off; off >>= 1) v += __shfl_xor(v, off, 64);
    __shared__ float r2[2];
    if ((tid & 63) == 0) r2[tid >> 6] = v;
    __syncthreads();
    if (tid == 0) out[(size_t)B * HEADS * 2 * H] = (r2[0] + r2[1]) * (1.f / (float)B);
}

// ---------------- host launcher ----------------
extern "C" void kernel_launch(void* const* d_in, const int* in_sizes, int n_in,
                              void* d_out, int out_size, void* d_ws, size_t ws_size,
                              hipStream_t stream) {
    const int*   word_ids = (const int*)d_in[0];
    const int*   lengths  = (const int*)d_in[1];
    const float* emb      = (const float*)d_in[2];
    const float* W_ih_f   = (const float*)d_in[3];
    const float* W_hh_f   = (const float*)d_in[4];
    const float* b_f      = (const float*)d_in[5];
    const float* W_ih_b   = (const float*)d_in[6];
    const float* W_hh_b   = (const float*)d_in[7];
    const float* b_b      = (const float*)d_in[8];
    const float* W_s1     = (const float*)d_in[9];
    const float* W_s2     = (const float*)d_in[10];
    float* out = (float*)d_out;

    char* ws = (char*)d_ws;
    unsigned short* wbt16 = (unsigned short*)(ws + WBT_OFF);
    unsigned*       wbt   = (unsigned*)(ws + WBT_OFF);
    float* ws1t   = (float*)(ws + WS1T_OFF);
    float* pxc    = (float*)(ws + PX_OFF);
    float* hc     = (float*)(ws + HC_OFF);
    float* hbuf   = (float*)(ws + HBUF_OFF);
    float* cstate = (float*)(ws + CST_OFF);
    float* Abuf   = (float*)(ws + A_OFF);
    float* part   = (float*)(ws + PART_OFF);

    prep_kernel<<<2048, 256, 0, stream>>>(W_hh_f, W_hh_b, W_s1, wbt16, ws1t);

    for (int c = 0; c < 8; c++) {
        proj_kernel<<<dim3(16, 128, 2), 256, 0, stream>>>(
            word_ids, lengths, emb, W_ih_f, W_ih_b, b_f, b_b, pxc, c);
        lstm5_kernel<<<dim3(128, 2), 1024, 0, stream>>>(
            lengths, wbt, pxc, hc, hbuf, cstate, c);
    }

    logits_kernel<<<dim3(8, 128), 256, 0, stream>>>(lengths, hc, ws1t, W_s2, Abuf);
    softmax_kernel<<<B * HEADS, 256, 0, stream>>>(Abuf);
    attnM_kernel<<<B, 256, 0, stream>>>(lengths, Abuf, hc, out);
    penal_kernel<<<B, 256, 0, stream>>>(Abuf, part);
    final_kernel<<<1, 128, 0, stream>>>(part, out);
}

// Round 13
// 3086.762 us; speedup vs baseline: 4.5289x; 1.1828x over previous
//
#include <hip/hip_runtime.h>
#include <math.h>

#define T 512
#define B 128
#define E 256
#define H 256
#define G 1024   // 4H
#define DA 25
#define HEADS 5
#define NEGINF (-1e30f)

// ---------------- workspace layout (bytes) ----------------
static constexpr size_t WBT_OFF  = 0;           // [2][128 k2][256 j][4 gate] uint (f16 pair) 1,048,576
static constexpr size_t WS1T_OFF = 2097152;     // [512][25] f32                  51,200
static constexpr size_t PX_OFF   = 2148352;     // [2][64][128][1024] f32     67,108,864
static constexpr size_t HC_OFF   = 69257216;    // [128][512][512] f32       134,217,728
static constexpr size_t HBUF_OFF = 203474944;   // [2][128 b][256 j] f32         262,144
static constexpr size_t CST_OFF  = 203737088;   // [2][128][256] f32 c-state     262,144
static constexpr size_t A_OFF    = 203999232;   // [128][5][512] f32           1,310,720
static constexpr size_t PART_OFF = 205309952;   // [128] f32                         512

// ---- lstm6 dynamic LDS layout (bytes) ----
// hping  : [2][256] f32     @ 0      (2048)
// hh     : [2][128] u32     @ 2048   (1024)   packed half2 copy of h
// part   : [3][257] f32x4   @ 3072   (12336)
// wstage : [32][256] uint4  @ 15408  (131072) 8 k2/kq thread-private W cache
static constexpr unsigned LSTM_LDS_BYTES = 146480;

typedef _Float16 half2v __attribute__((ext_vector_type(2)));

__device__ __forceinline__ float sigmoidf_(float x) { return 1.f / (1.f + expf(-x)); }

__device__ __forceinline__ unsigned short f2h_(float f) {   // f32 -> f16 bits
    _Float16 h = (_Float16)f;
    unsigned short u;
    __builtin_memcpy(&u, &h, 2);
    return u;
}

// dot2: acc += w.lo*h.lo + w.hi*h.hi  (f32 accumulate)
__device__ __forceinline__ float fdot2_(unsigned w, half2v h, float acc) {
#if __has_builtin(__builtin_amdgcn_fdot2)
    half2v wv;
    __builtin_memcpy(&wv, &w, 4);
    return __builtin_amdgcn_fdot2(wv, h, acc, false);
#else
    unsigned short lo = (unsigned short)(w & 0xffffu), hi = (unsigned short)(w >> 16);
    _Float16 w0, w1;
    __builtin_memcpy(&w0, &lo, 2);
    __builtin_memcpy(&w1, &hi, 2);
    return fmaf((float)w0, (float)h[0], fmaf((float)w1, (float)h[1], acc));
#endif
}

// ---------------- prep: pack W_hh (f16, gate-major dwords) + W_s1^T --------
// wbt ushort layout: [((d*128 + k2)*256 + j)*8 + gate*2 + ke]
__global__ __launch_bounds__(256) void prep_kernel(const float* __restrict__ Whf,
                                                   const float* __restrict__ Whb,
                                                   const float* __restrict__ Ws1,
                                                   unsigned short* __restrict__ wbt,
                                                   float* __restrict__ ws1t) {
    int idx = blockIdx.x * 256 + threadIdx.x;
    if (idx < 2 * G * H) {
        int d = idx >> 18;
        int rem = idx & 262143;
        int r = rem >> 8;                        // gate row 0..1023
        int k = rem & 255;                       // h index
        const float* W = d ? Whb : Whf;
        int gate = r >> 8, j = r & 255;
        int k2 = k >> 1, ke = k & 1;
        wbt[(((size_t)d * 128 + k2) * 256 + j) * 8 + gate * 2 + ke] = f2h_(W[(size_t)r * H + k]);
    }
    if (idx < DA * 512) {
        int r = idx / 512, k = idx % 512;
        ws1t[k * DA + r] = Ws1[idx];
    }
}

// ---------------- input projection for one 64-step chunk ----------------
// grid (16 gtiles, 128 b, 2 dir), block 256
__global__ __launch_bounds__(256) void proj_kernel(const int* __restrict__ word_ids,
                                                   const int* __restrict__ lengths,
                                                   const float* __restrict__ emb,
                                                   const float* __restrict__ Wf,
                                                   const float* __restrict__ Wb,
                                                   const float* __restrict__ bf,
                                                   const float* __restrict__ bb,
                                                   float* __restrict__ pxc, int chunk) {
    int g0 = blockIdx.x * 64;
    int b  = blockIdx.y;
    int d  = blockIdx.z;
    int len = lengths[b];
    int t0 = chunk * 64;
    if (t0 >= len) return;
    const float* Wih  = d ? Wb : Wf;
    const float* bias = d ? bb : bf;

    __shared__ int   wid[64];
    __shared__ float As[64][17];   // [m][kk], k-minor, padded
    __shared__ float Bs[64][17];

    int tid = threadIdx.x;
    if (tid < 64) {
        int t = t0 + tid;
        int src;
        if (d == 0) src = t;
        else { src = len - 1 - t; if (src < 0) src = 0; }
        wid[tid] = word_ids[b * T + src];
    }
    __syncthreads();

    int tx = tid & 15, ty = tid >> 4;   // compute mapping
    int kk = tid & 15, r0 = tid >> 4;   // load mapping
    float acc[4][4];
    #pragma unroll
    for (int i = 0; i < 4; i++)
        #pragma unroll
        for (int j = 0; j < 4; j++) acc[i][j] = 0.f;

    for (int k0 = 0; k0 < E; k0 += 16) {
        #pragma unroll
        for (int i = 0; i < 4; i++) {
            int m = r0 + 16 * i;
            As[m][kk] = emb[(size_t)wid[m] * E + k0 + kk];
            Bs[m][kk] = Wih[(size_t)(g0 + m) * E + k0 + kk];
        }
        __syncthreads();
        #pragma unroll
        for (int kq = 0; kq < 16; kq++) {
            float a[4], bv[4];
            #pragma unroll
            for (int i = 0; i < 4; i++) a[i] = As[ty * 4 + i][kq];
            #pragma unroll
            for (int j = 0; j < 4; j++) bv[j] = Bs[tx * 4 + j][kq];
            #pragma unroll
            for (int i = 0; i < 4; i++)
                #pragma unroll
                for (int j = 0; j < 4; j++) acc[i][j] += a[i] * bv[j];
        }
        __syncthreads();
    }
    #pragma unroll
    for (int i = 0; i < 4; i++) {
        int m = ty * 4 + i;
        #pragma unroll
        for (int j = 0; j < 4; j++) {
            int n = tx * 4 + j;
            pxc[((size_t)(d * 64 + m) * B + b) * G + g0 + n] = acc[i][j] + bias[g0 + n];
        }
    }
}

// ---------------- LSTM recurrence: residency-split W ----------------
// grid (128 b, 2 dir); block 1024 = 16 waves (r12 skeleton).
// Thread (j = tid&255, kq = tid>>8) owns 32 k2 of hidden col j:
//   k2 0..7  : staged in LDS once per chunk (thread-private cache, 128 KB/block)
//   k2 8..11 : 4 NAMED uint4 registers (16 VGPR; stay under the 64-VGPR cap)
//   k2 12..31: streamed from L2 -> 320 KB/step (was 512)
// h kept twice: f32 (state) + packed half2 (dot2 operand), both ping-pong.
__global__ __launch_bounds__(1024) void lstm6_kernel(const int* __restrict__ lengths,
                                                     const unsigned* __restrict__ wbt,
                                                     const float* __restrict__ pxc,
                                                     float* __restrict__ hc_out,
                                                     float* __restrict__ hbuf,
                                                     float* __restrict__ cstate,
                                                     int chunk) {
    int b   = blockIdx.x;
    int d   = blockIdx.y;
    int tid = threadIdx.x;
    int j  = tid & 255;
    int kq = tid >> 8;                 // 0..3 (wave-uniform)

    int len = lengths[b];
    int t0 = chunk * 64;
    if (t0 >= len) return;
    int tend = min(t0 + 64, len);

    extern __shared__ char smem[];
    float*    hping = (float*)smem;                  // [2][256]
    unsigned* hh    = (unsigned*)(smem + 2048);      // [2][128]
    float4*   part  = (float4*)(smem + 3072);        // [3][257]
    uint4*    wst   = (uint4*)(smem + 15408);        // [32][256]

    float* hbufg = hbuf + ((size_t)d * B + b) * 256;

    float c = 0.f;
    int cur = 0;
    if (chunk == 0) {
        if (tid < 256) hping[tid] = 0.f;
        if (tid < 128) hh[tid] = 0u;
    } else {
        if (kq == 0) {
            c = cstate[((size_t)d * B + b) * H + j];
            hping[j] = hbufg[j];
        }
        if (tid < 128) {
            half2v hv2;
            hv2[0] = (_Float16)hbufg[2 * tid];
            hv2[1] = (_Float16)hbufg[2 * tid + 1];
            unsigned hu;
            __builtin_memcpy(&hu, &hv2, 4);
            hh[tid] = hu;
        }
    }

    // thread's W rows: k2 in [kq*32, kq*32+32), column j
    const uint4* wp  = (const uint4*)wbt + ((size_t)d * 128 + kq * 32) * 256 + j;
    const float* pxd = pxc + (size_t)d * 64 * B * G;

    // stage k2 0..7 into LDS (thread-private; written+read by same thread)
    #pragma unroll
    for (int r = 0; r < 8; r++)
        wst[(kq * 8 + r) * 256 + j] = wp[(size_t)r * 256];
    // resident k2 8..11 in named registers
    uint4 wr0 = wp[8 * 256], wr1 = wp[9 * 256], wr2 = wp[10 * 256], wr3 = wp[11 * 256];
    __syncthreads();

    for (int t = t0; t < tend; t++) {
        int s = t - t0;
        float p0, p1, p2, p3;
        if (kq == 0) {
            const float* pxs = pxd + ((size_t)s * B + b) * G;
            p0 = pxs[j];
            p1 = pxs[256 + j];
            p2 = pxs[512 + j];
            p3 = pxs[768 + j];
        }
        float a0 = 0.f, a1 = 0.f, a2 = 0.f, a3 = 0.f;

        const unsigned* hhc = hh + cur * 128 + kq * 32;

        // streamed k2 12..31 first (loads issue early)
        #pragma unroll 4
        for (int r = 12; r < 32; r++) {
            uint4 wv = wp[(size_t)r * 256];
            unsigned hu = hhc[r];              // wave-uniform -> broadcast
            half2v hhv;
            __builtin_memcpy(&hhv, &hu, 4);
            a0 = fdot2_(wv.x, hhv, a0);
            a1 = fdot2_(wv.y, hhv, a1);
            a2 = fdot2_(wv.z, hhv, a2);
            a3 = fdot2_(wv.w, hhv, a3);
        }
        // LDS-cached k2 0..7
        #pragma unroll
        for (int r = 0; r < 8; r++) {
            uint4 wv = wst[(kq * 8 + r) * 256 + j];
            unsigned hu = hhc[r];
            half2v hhv;
            __builtin_memcpy(&hhv, &hu, 4);
            a0 = fdot2_(wv.x, hhv, a0);
            a1 = fdot2_(wv.y, hhv, a1);
            a2 = fdot2_(wv.z, hhv, a2);
            a3 = fdot2_(wv.w, hhv, a3);
        }
        // register-resident k2 8..11
        {
            unsigned hu8 = hhc[8], hu9 = hhc[9], hu10 = hhc[10], hu11 = hhc[11];
            half2v h8, h9, h10, h11;
            __builtin_memcpy(&h8, &hu8, 4);
            __builtin_memcpy(&h9, &hu9, 4);
            __builtin_memcpy(&h10, &hu10, 4);
            __builtin_memcpy(&h11, &hu11, 4);
            a0 = fdot2_(wr0.x, h8, a0);  a1 = fdot2_(wr0.y, h8, a1);
            a2 = fdot2_(wr0.z, h8, a2);  a3 = fdot2_(wr0.w, h8, a3);
            a0 = fdot2_(wr1.x, h9, a0);  a1 = fdot2_(wr1.y, h9, a1);
            a2 = fdot2_(wr1.z, h9, a2);  a3 = fdot2_(wr1.w, h9, a3);
            a0 = fdot2_(wr2.x, h10, a0); a1 = fdot2_(wr2.y, h10, a1);
            a2 = fdot2_(wr2.z, h10, a2); a3 = fdot2_(wr2.w, h10, a3);
            a0 = fdot2_(wr3.x, h11, a0); a1 = fdot2_(wr3.y, h11, a1);
            a2 = fdot2_(wr3.z, h11, a2); a3 = fdot2_(wr3.w, h11, a3);
        }

        if (kq > 0) part[(kq - 1) * 257 + j] = make_float4(a0, a1, a2, a3);
        __syncthreads();

        if (kq == 0) {
            #pragma unroll
            for (int q = 0; q < 3; q++) {
                float4 qv = part[q * 257 + j];
                a0 += qv.x; a1 += qv.y; a2 += qv.z; a3 += qv.w;
            }
            a0 += p0; a1 += p1; a2 += p2; a3 += p3;

            float ig = sigmoidf_(a0), fg = sigmoidf_(a1), og = sigmoidf_(a3);
            c = fg * c + ig * tanhf(a2);
            float h = og * tanhf(c);

            hping[(cur ^ 1) * 256 + j] = h;
            float hn = __shfl_down(h, 1);
            if (!(j & 1)) {
                half2v hv2;
                hv2[0] = (_Float16)h;
                hv2[1] = (_Float16)hn;
                unsigned hu;
                __builtin_memcpy(&hu, &hv2, 4);
                hh[(cur ^ 1) * 128 + (j >> 1)] = hu;
            }
            int pos = d ? (len - 1 - t) : t;
            hc_out[((size_t)b * T + pos) * (2 * H) + d * H + j] = h;
        }
        __syncthreads();
        cur ^= 1;
    }

    if (kq == 0) {
        cstate[((size_t)d * B + b) * H + j] = c;
        hbufg[j] = hping[cur * 256 + j];
    }
}

// ---------------- attention logits (masked) ----------------
__global__ __launch_bounds__(256) void logits_kernel(const int* __restrict__ lengths,
                                                     const float* __restrict__ hc,
                                                     const float* __restrict__ ws1t,
                                                     const float* __restrict__ Ws2,
                                                     float* __restrict__ S) {
    __shared__ float s_w1[512 * DA];
    __shared__ float s_w2[HEADS * DA];
    int b = blockIdx.y, tt = blockIdx.x;
    int tid = threadIdx.x;
    for (int i = tid; i < 512 * DA; i += 256) s_w1[i] = ws1t[i];
    for (int i = tid; i < HEADS * DA; i += 256) s_w2[i] = Ws2[i];
    __syncthreads();

    int len = lengths[b];
    int lane = tid & 63, wave = tid >> 6;
    for (int ti = 0; ti < 16; ti++) {
        int t = tt * 64 + wave * 16 + ti;
        if (t < len) {
            float y[DA];
            #pragma unroll
            for (int r = 0; r < DA; r++) y[r] = 0.f;
            const float* hcp = hc + ((size_t)b * T + t) * (2 * H);
            #pragma unroll
            for (int kk = 0; kk < 8; kk++) {
                int k = lane + kk * 64;
                float v = hcp[k];
                const float* w = s_w1 + k * DA;
                #pragma unroll
                for (int r = 0; r < DA; r++) y[r] += v * w[r];
            }
            #pragma unroll
            for (int r = 0; r < DA; r++) {
                float v = y[r];
                for (int off = 32; off; off >>= 1) v += __shfl_xor(v, off, 64);
                y[r] = tanhf(v);
            }
            if (lane < HEADS) {
                float s = 0.f;
                #pragma unroll
                for (int r = 0; r < DA; r++) s += y[r] * s_w2[lane * DA + r];
                S[((size_t)b * HEADS + lane) * T + t] = s;
            }
        } else {
            if (lane < HEADS) S[((size_t)b * HEADS + lane) * T + t] = NEGINF;
        }
    }
}

// ---------------- masked softmax over T, in place ----------------
__global__ __launch_bounds__(256) void softmax_kernel(float* __restrict__ S) {
    int row = blockIdx.x;
    float* p = S + (size_t)row * T;
    int tid = threadIdx.x;
    int lane = tid & 63, wave = tid >> 6;
    __shared__ float rr[4], ss[4];

    float mx = NEGINF;
    #pragma unroll
    for (int i = 0; i < 2; i++) mx = fmaxf(mx, p[tid + i * 256]);
    for (int off = 32; off; off >>= 1) mx = fmaxf(mx, __shfl_xor(mx, off, 64));
    if (lane == 0) rr[wave] = mx;
    __syncthreads();
    mx = fmaxf(fmaxf(rr[0], rr[1]), fmaxf(rr[2], rr[3]));

    float e[2], sum = 0.f;
    #pragma unroll
    for (int i = 0; i < 2; i++) { e[i] = expf(p[tid + i * 256] - mx); sum += e[i]; }
    for (int off = 32; off; off >>= 1) sum += __shfl_xor(sum, off, 64);
    if (lane == 0) ss[wave] = sum;
    __syncthreads();
    sum = ss[0] + ss[1] + ss[2] + ss[3];
    float inv = 1.f / sum;
    #pragma unroll
    for (int i = 0; i < 2; i++) p[tid + i * 256] = e[i] * inv;
}

// ---------------- M = A @ Hc -> sentence embeddings (d_out) ----------------
__global__ __launch_bounds__(256) void attnM_kernel(const int* __restrict__ lengths,
                                                    const float* __restrict__ A,
                                                    const float* __restrict__ hc,
                                                    float* __restrict__ out) {
    int b = blockIdx.x, tid = threadIdx.x;
    int len = lengths[b];
    const float* Ab  = A + (size_t)b * HEADS * T;
    const float* hcb = hc + (size_t)b * T * (2 * H);
    float acc[HEADS][2];
    #pragma unroll
    for (int h = 0; h < HEADS; h++) { acc[h][0] = 0.f; acc[h][1] = 0.f; }
    for (int t = 0; t < len; t++) {
        float v0 = hcb[(size_t)t * (2 * H) + tid];
        float v1 = hcb[(size_t)t * (2 * H) + H + tid];
        #pragma unroll
        for (int h = 0; h < HEADS; h++) {
            float a = Ab[h * T + t];
            acc[h][0] += a * v0;
            acc[h][1] += a * v1;
        }
    }
    #pragma unroll
    for (int h = 0; h < HEADS; h++) {
        out[(size_t)b * (HEADS * 2 * H) + h * (2 * H) + tid]     = acc[h][0];
        out[(size_t)b * (HEADS * 2 * H) + h * (2 * H) + H + tid] = acc[h][1];
    }
}

// ---------------- penalization ----------------
__global__ __launch_bounds__(256) void penal_kernel(const float* __restrict__ A,
                                                    float* __restrict__ part) {
    int b = blockIdx.x, tid = threadIdx.x;
    const float* Ab = A + (size_t)b * HEADS * T;
    float p[10];
    #pragma unroll
    for (int i = 0; i < 10; i++) p[i] = 0.f;
    for (int t = tid; t < T; t += 256) {
        float a0 = Ab[t], a1 = Ab[T + t], a2 = Ab[2 * T + t], a3 = Ab[3 * T + t], a4 = Ab[4 * T + t];
        p[0] += a0 * a1; p[1] += a0 * a2; p[2] += a0 * a3; p[3] += a0 * a4;
        p[4] += a1 * a2; p[5] += a1 * a3; p[6] += a1 * a4;
        p[7] += a2 * a3; p[8] += a2 * a4; p[9] += a3 * a4;
    }
    __shared__ float red[10][4];
    int lane = tid & 63, wave = tid >> 6;
    #pragma unroll
    for (int i = 0; i < 10; i++) {
        float v = p[i];
        for (int off = 32; off; off >>= 1) v += __shfl_xor(v, off, 64);
        if (lane == 0) red[i][wave] = v;
    }
    __syncthreads();
    if (tid == 0) {
        float s = 0.f;
        #pragma unroll
        for (int i = 0; i < 10; i++) {
            float P = red[i][0] + red[i][1] + red[i][2] + red[i][3];
            s += 2.f * P * P;
        }
        part[b] = s;
    }
}

__global__ __launch_bounds__(128) void final_kernel(const float* __restrict__ part,
                                                    float* __restrict__ out) {
    int tid = threadIdx.x;
    float v = part[tid];
    for (int off = 32; off; off >>= 1) v += __shfl_xor(v, off, 64);
    __shared__ float r2[2];
    if ((tid & 63) == 0) r2[tid >> 6] = v;
    __syncthreads();
    if (tid == 0) out[(size_t)B * HEADS * 2 * H] = (r2[0] + r2[1]) * (1.f / (float)B);
}

// ---------------- host launcher ----------------
extern "C" void kernel_launch(void* const* d_in, const int* in_sizes, int n_in,
                              void* d_out, int out_size, void* d_ws, size_t ws_size,
                              hipStream_t stream) {
    const int*   word_ids = (const int*)d_in[0];
    const int*   lengths  = (const int*)d_in[1];
    const float* emb      = (const float*)d_in[2];
    const float* W_ih_f   = (const float*)d_in[3];
    const float* W_hh_f   = (const float*)d_in[4];
    const float* b_f      = (const float*)d_in[5];
    const float* W_ih_b   = (const float*)d_in[6];
    const float* W_hh_b   = (const float*)d_in[7];
    const float* b_b      = (const float*)d_in[8];
    const float* W_s1     = (const float*)d_in[9];
    const float* W_s2     = (const float*)d_in[10];
    float* out = (float*)d_out;

    char* ws = (char*)d_ws;
    unsigned short* wbt16 = (unsigned short*)(ws + WBT_OFF);
    unsigned*       wbt   = (unsigned*)(ws + WBT_OFF);
    float* ws1t   = (float*)(ws + WS1T_OFF);
    float* pxc    = (float*)(ws + PX_OFF);
    float* hc     = (float*)(ws + HC_OFF);
    float* hbuf   = (float*)(ws + HBUF_OFF);
    float* cstate = (float*)(ws + CST_OFF);
    float* Abuf   = (float*)(ws + A_OFF);
    float* part   = (float*)(ws + PART_OFF);

    prep_kernel<<<2048, 256, 0, stream>>>(W_hh_f, W_hh_b, W_s1, wbt16, ws1t);

    for (int c = 0; c < 8; c++) {
        proj_kernel<<<dim3(16, 128, 2), 256, 0, stream>>>(
            word_ids, lengths, emb, W_ih_f, W_ih_b, b_f, b_b, pxc, c);
        lstm6_kernel<<<dim3(128, 2), 1024, LSTM_LDS_BYTES, stream>>>(
            lengths, wbt, pxc, hc, hbuf, cstate, c);
    }

    logits_kernel<<<dim3(8, 128), 256, 0, stream>>>(lengths, hc, ws1t, W_s2, Abuf);
    softmax_kernel<<<B * HEADS, 256, 0, stream>>>(Abuf);
    attnM_kernel<<<B, 256, 0, stream>>>(lengths, Abuf, hc, out);
    penal_kernel<<<B, 256, 0, stream>>>(Abuf, part);
    final_kernel<<<1, 128, 0, stream>>>(part, out);
}

// Round 14
// 2570.838 us; speedup vs baseline: 5.4378x; 1.2007x over previous
//
#include <hip/hip_runtime.h>
#include <math.h>

#define T 512
#define B 128
#define E 256
#define H 256
#define G 1024   // 4H
#define DA 25
#define HEADS 5
#define NEGINF (-1e30f)

// ---------------- workspace layout (bytes) ----------------
static constexpr size_t WBT_OFF  = 0;           // [2][128 k2][256 j][4 gate] uint (f16 pair W_hh) 1,048,576
static constexpr size_t WIH_OFF  = 1048576;     // [2][1024 g][256 e] ushort (f16 W_ih)            1,048,576
static constexpr size_t WS1T_OFF = 2097152;     // [512][25] f32                  51,200
static constexpr size_t PX_OFF   = 2148352;     // [2][64][128][1024] f32     67,108,864
static constexpr size_t HC_OFF   = 69257216;    // [128][512][512] f32       134,217,728
static constexpr size_t HBUF_OFF = 203474944;   // [2][128 b][256 j] f32         262,144
static constexpr size_t CST_OFF  = 203737088;   // [2][128][256] f32 c-state     262,144
static constexpr size_t A_OFF    = 203999232;   // [128][5][512] f32           1,310,720
static constexpr size_t PART_OFF = 205309952;   // [128] f32                         512

// ---- lstm6 dynamic LDS layout (bytes) ----
// hping  : [2][256] f32     @ 0      (2048)
// hh     : [2][128] u32     @ 2048   (1024)   packed half2 copy of h
// part   : [3][257] f32x4   @ 3072   (12336)
// wstage : [32][256] uint4  @ 15408  (131072) 8 k2/kq thread-private W cache
static constexpr unsigned LSTM_LDS_BYTES = 146480;

typedef _Float16 half2v __attribute__((ext_vector_type(2)));

__device__ __forceinline__ float sigmoidf_(float x) { return 1.f / (1.f + expf(-x)); }

__device__ __forceinline__ unsigned short f2h_(float f) {   // f32 -> f16 bits
    _Float16 h = (_Float16)f;
    unsigned short u;
    __builtin_memcpy(&u, &h, 2);
    return u;
}

// dot2: acc += w.lo*h.lo + w.hi*h.hi  (f32 accumulate)
__device__ __forceinline__ float fdot2_(unsigned w, half2v h, float acc) {
#if __has_builtin(__builtin_amdgcn_fdot2)
    half2v wv;
    __builtin_memcpy(&wv, &w, 4);
    return __builtin_amdgcn_fdot2(wv, h, acc, false);
#else
    unsigned short lo = (unsigned short)(w & 0xffffu), hi = (unsigned short)(w >> 16);
    _Float16 w0, w1;
    __builtin_memcpy(&w0, &lo, 2);
    __builtin_memcpy(&w1, &hi, 2);
    return fmaf((float)w0, (float)h[0], fmaf((float)w1, (float)h[1], acc));
#endif
}

// ---------------- prep: pack W_hh + W_ih to f16, W_s1^T --------------------
// wbt ushort layout: [((d*128 + k2)*256 + j)*8 + gate*2 + ke]
// wih ushort layout: [(d*1024 + g)*256 + e]  (pairs adjacent in e)
__global__ __launch_bounds__(256) void prep_kernel(const float* __restrict__ Whf,
                                                   const float* __restrict__ Whb,
                                                   const float* __restrict__ Wif,
                                                   const float* __restrict__ Wib,
                                                   const float* __restrict__ Ws1,
                                                   unsigned short* __restrict__ wbt,
                                                   unsigned short* __restrict__ wih,
                                                   float* __restrict__ ws1t) {
    int idx = blockIdx.x * 256 + threadIdx.x;
    if (idx < 2 * G * H) {
        int d = idx >> 18;
        int rem = idx & 262143;
        int r = rem >> 8;                        // gate row 0..1023
        int k = rem & 255;                       // h index
        const float* W = d ? Whb : Whf;
        int gate = r >> 8, j = r & 255;
        int k2 = k >> 1, ke = k & 1;
        wbt[(((size_t)d * 128 + k2) * 256 + j) * 8 + gate * 2 + ke] = f2h_(W[(size_t)r * H + k]);
        const float* Wi = d ? Wib : Wif;
        wih[((size_t)d * G + r) * 256 + k] = f2h_(Wi[(size_t)r * E + k]);
    }
    if (idx < DA * 512) {
        int r = idx / 512, k = idx % 512;
        ws1t[k * DA + r] = Ws1[idx];
    }
}

// ---------------- input projection, f16 dot2, one 64-step chunk ----------
// grid (16 gtiles, 128 b, 2 dir), block 256. k-block = 32 e (16 pairs).
__global__ __launch_bounds__(256) void proj_kernel(const int* __restrict__ word_ids,
                                                   const int* __restrict__ lengths,
                                                   const float* __restrict__ emb,
                                                   const unsigned* __restrict__ wih,
                                                   const float* __restrict__ bf,
                                                   const float* __restrict__ bb,
                                                   float* __restrict__ pxc, int chunk) {
    int g0 = blockIdx.x * 64;
    int b  = blockIdx.y;
    int d  = blockIdx.z;
    int len = lengths[b];
    int t0 = chunk * 64;
    if (t0 >= len) return;
    const float* bias = d ? bb : bf;

    __shared__ int      wid[64];
    __shared__ unsigned As2[64][17];   // [m][kp] emb as f16 pairs
    __shared__ unsigned Bs2[64][17];   // [m][kp] W_ih as f16 pairs

    int tid = threadIdx.x;
    if (tid < 64) {
        int t = t0 + tid;
        int src;
        if (d == 0) src = t;
        else { src = len - 1 - t; if (src < 0) src = 0; }
        wid[tid] = word_ids[b * T + src];
    }
    __syncthreads();

    int tx = tid & 15, ty = tid >> 4;   // compute mapping
    int lk = tid & 15, lm = tid >> 4;   // load mapping (kp 0..15, m base)
    const unsigned* wihd = wih + ((size_t)d * G + g0) * 128;

    float acc[4][4];
    #pragma unroll
    for (int i = 0; i < 4; i++)
        #pragma unroll
        for (int j = 0; j < 4; j++) acc[i][j] = 0.f;

    for (int k0 = 0; k0 < E; k0 += 32) {
        int e2 = k0 >> 1;
        #pragma unroll
        for (int i = 0; i < 4; i++) {
            int m = lm + 16 * i;
            const float* ep = emb + (size_t)wid[m] * E + k0 + 2 * lk;
            half2v av;
            av[0] = (_Float16)ep[0];
            av[1] = (_Float16)ep[1];
            unsigned au;
            __builtin_memcpy(&au, &av, 4);
            As2[m][lk] = au;
            Bs2[m][lk] = wihd[(size_t)m * 128 + e2 + lk];
        }
        __syncthreads();
        #pragma unroll
        for (int kp = 0; kp < 16; kp++) {
            unsigned a2[4], b2[4];
            #pragma unroll
            for (int i = 0; i < 4; i++) a2[i] = As2[ty * 4 + i][kp];
            #pragma unroll
            for (int j = 0; j < 4; j++) b2[j] = Bs2[tx * 4 + j][kp];
            #pragma unroll
            for (int i = 0; i < 4; i++) {
                half2v ah;
                __builtin_memcpy(&ah, &a2[i], 4);
                #pragma unroll
                for (int j = 0; j < 4; j++)
                    acc[i][j] = fdot2_(b2[j], ah, acc[i][j]);
            }
        }
        __syncthreads();
    }
    #pragma unroll
    for (int i = 0; i < 4; i++) {
        int m = ty * 4 + i;
        #pragma unroll
        for (int j = 0; j < 4; j++) {
            int n = tx * 4 + j;
            pxc[((size_t)(d * 64 + m) * B + b) * G + g0 + n] = acc[i][j] + bias[g0 + n];
        }
    }
}

// ---------------- LSTM recurrence: residency-split W ----------------
// grid (128 b, 2 dir); block 1024 = 16 waves.
// Thread (j = tid&255, kq = tid>>8) owns 32 k2 of hidden col j:
//   k2 0..7  : staged in LDS once per chunk (thread-private cache, 128 KB/block)
//   k2 8..15 : 8 NAMED uint4 registers (32 VGPR; ~52 total, under the 64 cap)
//   k2 16..31: streamed from L2 -> 256 KB/step (was 320)
__global__ __launch_bounds__(1024) void lstm6_kernel(const int* __restrict__ lengths,
                                                     const unsigned* __restrict__ wbt,
                                                     const float* __restrict__ pxc,
                                                     float* __restrict__ hc_out,
                                                     float* __restrict__ hbuf,
                                                     float* __restrict__ cstate,
                                                     int chunk) {
    int b   = blockIdx.x;
    int d   = blockIdx.y;
    int tid = threadIdx.x;
    int j  = tid & 255;
    int kq = tid >> 8;                 // 0..3 (wave-uniform)

    int len = lengths[b];
    int t0 = chunk * 64;
    if (t0 >= len) return;
    int tend = min(t0 + 64, len);

    extern __shared__ char smem[];
    float*    hping = (float*)smem;                  // [2][256]
    unsigned* hh    = (unsigned*)(smem + 2048);      // [2][128]
    float4*   part  = (float4*)(smem + 3072);        // [3][257]
    uint4*    wst   = (uint4*)(smem + 15408);        // [32][256]

    float* hbufg = hbuf + ((size_t)d * B + b) * 256;

    float c = 0.f;
    int cur = 0;
    if (chunk == 0) {
        if (tid < 256) hping[tid] = 0.f;
        if (tid < 128) hh[tid] = 0u;
    } else {
        if (kq == 0) {
            c = cstate[((size_t)d * B + b) * H + j];
            hping[j] = hbufg[j];
        }
        if (tid < 128) {
            half2v hv2;
            hv2[0] = (_Float16)hbufg[2 * tid];
            hv2[1] = (_Float16)hbufg[2 * tid + 1];
            unsigned hu;
            __builtin_memcpy(&hu, &hv2, 4);
            hh[tid] = hu;
        }
    }

    // thread's W rows: k2 in [kq*32, kq*32+32), column j
    const uint4* wp  = (const uint4*)wbt + ((size_t)d * 128 + kq * 32) * 256 + j;
    const float* pxd = pxc + (size_t)d * 64 * B * G;

    // stage k2 0..7 into LDS (thread-private; written+read by same thread)
    #pragma unroll
    for (int r = 0; r < 8; r++)
        wst[(kq * 8 + r) * 256 + j] = wp[(size_t)r * 256];
    // resident k2 8..15 in named registers (8 x uint4 = 32 VGPR)
    uint4 wr0 = wp[8 * 256],  wr1 = wp[9 * 256],  wr2 = wp[10 * 256], wr3 = wp[11 * 256];
    uint4 wr4 = wp[12 * 256], wr5 = wp[13 * 256], wr6 = wp[14 * 256], wr7 = wp[15 * 256];
    __syncthreads();

    for (int t = t0; t < tend; t++) {
        int s = t - t0;
        float p0, p1, p2, p3;
        if (kq == 0) {
            const float* pxs = pxd + ((size_t)s * B + b) * G;
            p0 = pxs[j];
            p1 = pxs[256 + j];
            p2 = pxs[512 + j];
            p3 = pxs[768 + j];
        }
        float a0 = 0.f, a1 = 0.f, a2 = 0.f, a3 = 0.f;

        const unsigned* hhc = hh + cur * 128 + kq * 32;

        // streamed k2 16..31 first (loads issue early)
        #pragma unroll 4
        for (int r = 16; r < 32; r++) {
            uint4 wv = wp[(size_t)r * 256];
            unsigned hu = hhc[r];              // wave-uniform -> broadcast
            half2v hhv;
            __builtin_memcpy(&hhv, &hu, 4);
            a0 = fdot2_(wv.x, hhv, a0);
            a1 = fdot2_(wv.y, hhv, a1);
            a2 = fdot2_(wv.z, hhv, a2);
            a3 = fdot2_(wv.w, hhv, a3);
        }
        // LDS-cached k2 0..7
        #pragma unroll
        for (int r = 0; r < 8; r++) {
            uint4 wv = wst[(kq * 8 + r) * 256 + j];
            unsigned hu = hhc[r];
            half2v hhv;
            __builtin_memcpy(&hhv, &hu, 4);
            a0 = fdot2_(wv.x, hhv, a0);
            a1 = fdot2_(wv.y, hhv, a1);
            a2 = fdot2_(wv.z, hhv, a2);
            a3 = fdot2_(wv.w, hhv, a3);
        }
        // register-resident k2 8..15
        {
            unsigned hu;
            half2v hv;
            #define RES_DOT(WR, IDX)                                   \
                hu = hhc[IDX];                                         \
                __builtin_memcpy(&hv, &hu, 4);                         \
                a0 = fdot2_(WR.x, hv, a0); a1 = fdot2_(WR.y, hv, a1);  \
                a2 = fdot2_(WR.z, hv, a2); a3 = fdot2_(WR.w, hv, a3);
            RES_DOT(wr0, 8)
            RES_DOT(wr1, 9)
            RES_DOT(wr2, 10)
            RES_DOT(wr3, 11)
            RES_DOT(wr4, 12)
            RES_DOT(wr5, 13)
            RES_DOT(wr6, 14)
            RES_DOT(wr7, 15)
            #undef RES_DOT
        }

        if (kq > 0) part[(kq - 1) * 257 + j] = make_float4(a0, a1, a2, a3);
        __syncthreads();

        if (kq == 0) {
            #pragma unroll
            for (int q = 0; q < 3; q++) {
                float4 qv = part[q * 257 + j];
                a0 += qv.x; a1 += qv.y; a2 += qv.z; a3 += qv.w;
            }
            a0 += p0; a1 += p1; a2 += p2; a3 += p3;

            float ig = sigmoidf_(a0), fg = sigmoidf_(a1), og = sigmoidf_(a3);
            c = fg * c + ig * tanhf(a2);
            float h = og * tanhf(c);

            hping[(cur ^ 1) * 256 + j] = h;
            float hn = __shfl_down(h, 1);
            if (!(j & 1)) {
                half2v hv2;
                hv2[0] = (_Float16)h;
                hv2[1] = (_Float16)hn;
                unsigned hu;
                __builtin_memcpy(&hu, &hv2, 4);
                hh[(cur ^ 1) * 128 + (j >> 1)] = hu;
            }
            int pos = d ? (len - 1 - t) : t;
            hc_out[((size_t)b * T + pos) * (2 * H) + d * H + j] = h;
        }
        __syncthreads();
        cur ^= 1;
    }

    if (kq == 0) {
        cstate[((size_t)d * B + b) * H + j] = c;
        hbufg[j] = hping[cur * 256 + j];
    }
}

// ---------------- attention logits (masked) ----------------
__global__ __launch_bounds__(256) void logits_kernel(const int* __restrict__ lengths,
                                                     const float* __restrict__ hc,
                                                     const float* __restrict__ ws1t,
                                                     const float* __restrict__ Ws2,
                                                     float* __restrict__ S) {
    __shared__ float s_w1[512 * DA];
    __shared__ float s_w2[HEADS * DA];
    int b = blockIdx.y, tt = blockIdx.x;
    int tid = threadIdx.x;
    for (int i = tid; i < 512 * DA; i += 256) s_w1[i] = ws1t[i];
    for (int i = tid; i < HEADS * DA; i += 256) s_w2[i] = Ws2[i];
    __syncthreads();

    int len = lengths[b];
    int lane = tid & 63, wave = tid >> 6;
    for (int ti = 0; ti < 16; ti++) {
        int t = tt * 64 + wave * 16 + ti;
        if (t < len) {
            float y[DA];
            #pragma unroll
            for (int r = 0; r < DA; r++) y[r] = 0.f;
            const float* hcp = hc + ((size_t)b * T + t) * (2 * H);
            #pragma unroll
            for (int kk = 0; kk < 8; kk++) {
                int k = lane + kk * 64;
                float v = hcp[k];
                const float* w = s_w1 + k * DA;
                #pragma unroll
                for (int r = 0; r < DA; r++) y[r] += v * w[r];
            }
            #pragma unroll
            for (int r = 0; r < DA; r++) {
                float v = y[r];
                for (int off = 32; off; off >>= 1) v += __shfl_xor(v, off, 64);
                y[r] = tanhf(v);
            }
            if (lane < HEADS) {
                float s = 0.f;
                #pragma unroll
                for (int r = 0; r < DA; r++) s += y[r] * s_w2[lane * DA + r];
                S[((size_t)b * HEADS + lane) * T + t] = s;
            }
        } else {
            if (lane < HEADS) S[((size_t)b * HEADS + lane) * T + t] = NEGINF;
        }
    }
}

// ---------------- masked softmax over T, in place ----------------
__global__ __launch_bounds__(256) void softmax_kernel(float* __restrict__ S) {
    int row = blockIdx.x;
    float* p = S + (size_t)row * T;
    int tid = threadIdx.x;
    int lane = tid & 63, wave = tid >> 6;
    __shared__ float rr[4], ss[4];

    float mx = NEGINF;
    #pragma unroll
    for (int i = 0; i < 2; i++) mx = fmaxf(mx, p[tid + i * 256]);
    for (int off = 32; off; off >>= 1) mx = fmaxf(mx, __shfl_xor(mx, off, 64));
    if (lane == 0) rr[wave] = mx;
    __syncthreads();
    mx = fmaxf(fmaxf(rr[0], rr[1]), fmaxf(rr[2], rr[3]));

    float e[2], sum = 0.f;
    #pragma unroll
    for (int i = 0; i < 2; i++) { e[i] = expf(p[tid + i * 256] - mx); sum += e[i]; }
    for (int off = 32; off; off >>= 1) sum += __shfl_xor(sum, off, 64);
    if (lane == 0) ss[wave] = sum;
    __syncthreads();
    sum = ss[0] + ss[1] + ss[2] + ss[3];
    float inv = 1.f / sum;
    #pragma unroll
    for (int i = 0; i < 2; i++) p[tid + i * 256] = e[i] * inv;
}

// ---------------- M = A @ Hc -> sentence embeddings (d_out) ----------------
__global__ __launch_bounds__(256) void attnM_kernel(const int* __restrict__ lengths,
                                                    const float* __restrict__ A,
                                                    const float* __restrict__ hc,
                                                    float* __restrict__ out) {
    int b = blockIdx.x, tid = threadIdx.x;
    int len = lengths[b];
    const float* Ab  = A + (size_t)b * HEADS * T;
    const float* hcb = hc + (size_t)b * T * (2 * H);
    float acc[HEADS][2];
    #pragma unroll
    for (int h = 0; h < HEADS; h++) { acc[h][0] = 0.f; acc[h][1] = 0.f; }
    for (int t = 0; t < len; t++) {
        float v0 = hcb[(size_t)t * (2 * H) + tid];
        float v1 = hcb[(size_t)t * (2 * H) + H + tid];
        #pragma unroll
        for (int h = 0; h < HEADS; h++) {
            float a = Ab[h * T + t];
            acc[h][0] += a * v0;
            acc[h][1] += a * v1;
        }
    }
    #pragma unroll
    for (int h = 0; h < HEADS; h++) {
        out[(size_t)b * (HEADS * 2 * H) + h * (2 * H) + tid]     = acc[h][0];
        out[(size_t)b * (HEADS * 2 * H) + h * (2 * H) + H + tid] = acc[h][1];
    }
}

// ---------------- penalization ----------------
__global__ __launch_bounds__(256) void penal_kernel(const float* __restrict__ A,
                                                    float* __restrict__ part) {
    int b = blockIdx.x, tid = threadIdx.x;
    const float* Ab = A + (size_t)b * HEADS * T;
    float p[10];
    #pragma unroll
    for (int i = 0; i < 10; i++) p[i] = 0.f;
    for (int t = tid; t < T; t += 256) {
        float a0 = Ab[t], a1 = Ab[T + t], a2 = Ab[2 * T + t], a3 = Ab[3 * T + t], a4 = Ab[4 * T + t];
        p[0] += a0 * a1; p[1] += a0 * a2; p[2] += a0 * a3; p[3] += a0 * a4;
        p[4] += a1 * a2; p[5] += a1 * a3; p[6] += a1 * a4;
        p[7] += a2 * a3; p[8] += a2 * a4; p[9] += a3 * a4;
    }
    __shared__ float red[10][4];
    int lane = tid & 63, wave = tid >> 6;
    #pragma unroll
    for (int i = 0; i < 10; i++) {
        float v = p[i];
        for (int off = 32; off; off >>= 1) v += __shfl_xor(v, off, 64);
        if (lane == 0) red[i][wave] = v;
    }
    __syncthreads();
    if (tid == 0) {
        float s = 0.f;
        #pragma unroll
        for (int i = 0; i < 10; i++) {
            float P = red[i][0] + red[i][1] + red[i][2] + red[i][3];
            s += 2.f * P * P;
        }
        part[b] = s;
    }
}

__global__ __launch_bounds__(128) void final_kernel(const float* __restrict__ part,
                                                    float* __restrict__ out) {
    int tid = threadIdx.x;
    float v = part[tid];
    for (int off = 32; off; off >>= 1) v += __shfl_xor(v, off, 64);
    __shared__ float r2[2];
    if ((tid & 63) == 0) r2[tid >> 6] = v;
    __syncthreads();
    if (tid == 0) out[(size_t)B * HEADS * 2 * H] = (r2[0] + r2[1]) * (1.f / (float)B);
}

// ---------------- host launcher ----------------
extern "C" void kernel_launch(void* const* d_in, const int* in_sizes, int n_in,
                              void* d_out, int out_size, void* d_ws, size_t ws_size,
                              hipStream_t stream) {
    const int*   word_ids = (const int*)d_in[0];
    const int*   lengths  = (const int*)d_in[1];
    const float* emb      = (const float*)d_in[2];
    const float* W_ih_f   = (const float*)d_in[3];
    const float* W_hh_f   = (const float*)d_in[4];
    const float* b_f      = (const float*)d_in[5];
    const float* W_ih_b   = (const float*)d_in[6];
    const float* W_hh_b   = (const float*)d_in[7];
    const float* b_b      = (const float*)d_in[8];
    const float* W_s1     = (const float*)d_in[9];
    const float* W_s2     = (const float*)d_in[10];
    float* out = (float*)d_out;

    char* ws = (char*)d_ws;
    unsigned short* wbt16 = (unsigned short*)(ws + WBT_OFF);
    unsigned*       wbt   = (unsigned*)(ws + WBT_OFF);
    unsigned short* wih16 = (unsigned short*)(ws + WIH_OFF);
    unsigned*       wihu  = (unsigned*)(ws + WIH_OFF);
    float* ws1t   = (float*)(ws + WS1T_OFF);
    float* pxc    = (float*)(ws + PX_OFF);
    float* hc     = (float*)(ws + HC_OFF);
    float* hbuf   = (float*)(ws + HBUF_OFF);
    float* cstate = (float*)(ws + CST_OFF);
    float* Abuf   = (float*)(ws + A_OFF);
    float* part   = (float*)(ws + PART_OFF);

    prep_kernel<<<2048, 256, 0, stream>>>(W_hh_f, W_hh_b, W_ih_f, W_ih_b, W_s1,
                                          wbt16, wih16, ws1t);

    for (int c = 0; c < 8; c++) {
        proj_kernel<<<dim3(16, 128, 2), 256, 0, stream>>>(
            word_ids, lengths, emb, wihu, b_f, b_b, pxc, c);
        lstm6_kernel<<<dim3(128, 2), 1024, LSTM_LDS_BYTES, stream>>>(
            lengths, wbt, pxc, hc, hbuf, cstate, c);
    }

    logits_kernel<<<dim3(8, 128), 256, 0, stream>>>(lengths, hc, ws1t, W_s2, Abuf);
    softmax_kernel<<<B * HEADS, 256, 0, stream>>>(Abuf);
    attnM_kernel<<<B, 256, 0, stream>>>(lengths, Abuf, hc, out);
    penal_kernel<<<B, 256, 0, stream>>>(Abuf, part);
    final_kernel<<<1, 128, 0, stream>>>(part, out);
}

// Round 15
// 2528.432 us; speedup vs baseline: 5.5290x; 1.0168x over previous
//
#include <hip/hip_runtime.h>
#include <math.h>

#define T 512
#define B 128
#define E 256
#define H 256
#define G 1024   // 4H
#define DA 25
#define HEADS 5
#define NEGINF (-1e30f)

// ---------------- workspace layout (bytes) ----------------
static constexpr size_t WBT_OFF  = 0;           // [2][128 k2][256 j][4 gate] uint (f16 pair W_hh) 1,048,576
static constexpr size_t WIH_OFF  = 1048576;     // [2][1024 g][256 e] ushort (f16 W_ih)            1,048,576
static constexpr size_t WS1T_OFF = 2097152;     // [25 r][64 l] uint4 (f16 W_s1, lane-major)          25,600
static constexpr size_t PX_OFF   = 2148352;     // [2][64][128][1024] f32     67,108,864
static constexpr size_t HC_OFF   = 69257216;    // [128][512][512] f32       134,217,728
static constexpr size_t HBUF_OFF = 203474944;   // [2][128 b][256 j] f32         262,144
static constexpr size_t CST_OFF  = 203737088;   // [2][128][256] f32 c-state     262,144
static constexpr size_t A_OFF    = 203999232;   // [128][5][512] f32           1,310,720
static constexpr size_t PART_OFF = 205309952;   // [128] f32                         512

// ---- lstm6 dynamic LDS layout (bytes) ----
static constexpr unsigned LSTM_LDS_BYTES = 146480;

typedef _Float16 half2v __attribute__((ext_vector_type(2)));

__device__ __forceinline__ float sigmoidf_(float x) { return 1.f / (1.f + expf(-x)); }

__device__ __forceinline__ unsigned short f2h_(float f) {   // f32 -> f16 bits
    _Float16 h = (_Float16)f;
    unsigned short u;
    __builtin_memcpy(&u, &h, 2);
    return u;
}

// dot2: acc += w.lo*h.lo + w.hi*h.hi  (f32 accumulate)
__device__ __forceinline__ float fdot2_(unsigned w, half2v h, float acc) {
#if __has_builtin(__builtin_amdgcn_fdot2)
    half2v wv;
    __builtin_memcpy(&wv, &w, 4);
    return __builtin_amdgcn_fdot2(wv, h, acc, false);
#else
    unsigned short lo = (unsigned short)(w & 0xffffu), hi = (unsigned short)(w >> 16);
    _Float16 w0, w1;
    __builtin_memcpy(&w0, &lo, 2);
    __builtin_memcpy(&w1, &hi, 2);
    return fmaf((float)w0, (float)h[0], fmaf((float)w1, (float)h[1], acc));
#endif
}

__device__ __forceinline__ half2v packh2_(float a, float b) {
    half2v h;
    h[0] = (_Float16)a;
    h[1] = (_Float16)b;
    return h;
}

// ---------------- prep: pack W_hh + W_ih + W_s1 to f16 ---------------------
// wbt ushort layout: [((d*128 + k2)*256 + j)*8 + gate*2 + ke]
// wih ushort layout: [(d*1024 + g)*256 + e]
// ws1p ushort layout: [(r*64 + l)*8 + q*2 + ke]  (kp = l + 64q, k = 2kp+ke)
__global__ __launch_bounds__(256) void prep_kernel(const float* __restrict__ Whf,
                                                   const float* __restrict__ Whb,
                                                   const float* __restrict__ Wif,
                                                   const float* __restrict__ Wib,
                                                   const float* __restrict__ Ws1,
                                                   unsigned short* __restrict__ wbt,
                                                   unsigned short* __restrict__ wih,
                                                   unsigned short* __restrict__ ws1p) {
    int idx = blockIdx.x * 256 + threadIdx.x;
    if (idx < 2 * G * H) {
        int d = idx >> 18;
        int rem = idx & 262143;
        int r = rem >> 8;                        // gate row 0..1023
        int k = rem & 255;                       // h index
        const float* W = d ? Whb : Whf;
        int gate = r >> 8, j = r & 255;
        int k2 = k >> 1, ke = k & 1;
        wbt[(((size_t)d * 128 + k2) * 256 + j) * 8 + gate * 2 + ke] = f2h_(W[(size_t)r * H + k]);
        const float* Wi = d ? Wib : Wif;
        wih[((size_t)d * G + r) * 256 + k] = f2h_(Wi[(size_t)r * E + k]);
    }
    if (idx < DA * 512) {
        int r = idx / 512, k = idx % 512;
        int kp = k >> 1, ke = k & 1;
        int l = kp & 63, q = kp >> 6;
        ws1p[((r * 64 + l) * 4 + q) * 2 + ke] = f2h_(Ws1[idx]);
    }
}

// ---------------- input projection, f16 dot2, one 64-step chunk ----------
// grid (16 gtiles, 128 b, 2 dir), block 256. k-block = 32 e (16 pairs).
__global__ __launch_bounds__(256) void proj_kernel(const int* __restrict__ word_ids,
                                                   const int* __restrict__ lengths,
                                                   const float* __restrict__ emb,
                                                   const unsigned* __restrict__ wih,
                                                   const float* __restrict__ bf,
                                                   const float* __restrict__ bb,
                                                   float* __restrict__ pxc, int chunk) {
    int g0 = blockIdx.x * 64;
    int b  = blockIdx.y;
    int d  = blockIdx.z;
    int len = lengths[b];
    int t0 = chunk * 64;
    if (t0 >= len) return;
    const float* bias = d ? bb : bf;

    __shared__ int      wid[64];
    __shared__ unsigned As2[64][17];   // [m][kp] emb as f16 pairs
    __shared__ unsigned Bs2[64][17];   // [m][kp] W_ih as f16 pairs

    int tid = threadIdx.x;
    if (tid < 64) {
        int t = t0 + tid;
        int src;
        if (d == 0) src = t;
        else { src = len - 1 - t; if (src < 0) src = 0; }
        wid[tid] = word_ids[b * T + src];
    }
    __syncthreads();

    int tx = tid & 15, ty = tid >> 4;   // compute mapping
    int lk = tid & 15, lm = tid >> 4;   // load mapping (kp 0..15, m base)
    const unsigned* wihd = wih + ((size_t)d * G + g0) * 128;

    float acc[4][4];
    #pragma unroll
    for (int i = 0; i < 4; i++)
        #pragma unroll
        for (int j = 0; j < 4; j++) acc[i][j] = 0.f;

    for (int k0 = 0; k0 < E; k0 += 32) {
        int e2 = k0 >> 1;
        #pragma unroll
        for (int i = 0; i < 4; i++) {
            int m = lm + 16 * i;
            const float* ep = emb + (size_t)wid[m] * E + k0 + 2 * lk;
            half2v av = packh2_(ep[0], ep[1]);
            unsigned au;
            __builtin_memcpy(&au, &av, 4);
            As2[m][lk] = au;
            Bs2[m][lk] = wihd[(size_t)m * 128 + e2 + lk];
        }
        __syncthreads();
        #pragma unroll
        for (int kp = 0; kp < 16; kp++) {
            unsigned a2[4], b2[4];
            #pragma unroll
            for (int i = 0; i < 4; i++) a2[i] = As2[ty * 4 + i][kp];
            #pragma unroll
            for (int j = 0; j < 4; j++) b2[j] = Bs2[tx * 4 + j][kp];
            #pragma unroll
            for (int i = 0; i < 4; i++) {
                half2v ah;
                __builtin_memcpy(&ah, &a2[i], 4);
                #pragma unroll
                for (int j = 0; j < 4; j++)
                    acc[i][j] = fdot2_(b2[j], ah, acc[i][j]);
            }
        }
        __syncthreads();
    }
    #pragma unroll
    for (int i = 0; i < 4; i++) {
        int m = ty * 4 + i;
        #pragma unroll
        for (int j = 0; j < 4; j++) {
            int n = tx * 4 + j;
            pxc[((size_t)(d * 64 + m) * B + b) * G + g0 + n] = acc[i][j] + bias[g0 + n];
        }
    }
}

// ---------------- LSTM recurrence: residency-split W ----------------
// grid (128 b, 2 dir); block 1024 = 16 waves. (unchanged from round 14)
__global__ __launch_bounds__(1024) void lstm6_kernel(const int* __restrict__ lengths,
                                                     const unsigned* __restrict__ wbt,
                                                     const float* __restrict__ pxc,
                                                     float* __restrict__ hc_out,
                                                     float* __restrict__ hbuf,
                                                     float* __restrict__ cstate,
                                                     int chunk) {
    int b   = blockIdx.x;
    int d   = blockIdx.y;
    int tid = threadIdx.x;
    int j  = tid & 255;
    int kq = tid >> 8;                 // 0..3 (wave-uniform)

    int len = lengths[b];
    int t0 = chunk * 64;
    if (t0 >= len) return;
    int tend = min(t0 + 64, len);

    extern __shared__ char smem[];
    float*    hping = (float*)smem;                  // [2][256]
    unsigned* hh    = (unsigned*)(smem + 2048);      // [2][128]
    float4*   part  = (float4*)(smem + 3072);        // [3][257]
    uint4*    wst   = (uint4*)(smem + 15408);        // [32][256]

    float* hbufg = hbuf + ((size_t)d * B + b) * 256;

    float c = 0.f;
    int cur = 0;
    if (chunk == 0) {
        if (tid < 256) hping[tid] = 0.f;
        if (tid < 128) hh[tid] = 0u;
    } else {
        if (kq == 0) {
            c = cstate[((size_t)d * B + b) * H + j];
            hping[j] = hbufg[j];
        }
        if (tid < 128) {
            half2v hv2 = packh2_(hbufg[2 * tid], hbufg[2 * tid + 1]);
            unsigned hu;
            __builtin_memcpy(&hu, &hv2, 4);
            hh[tid] = hu;
        }
    }

    // thread's W rows: k2 in [kq*32, kq*32+32), column j
    const uint4* wp  = (const uint4*)wbt + ((size_t)d * 128 + kq * 32) * 256 + j;
    const float* pxd = pxc + (size_t)d * 64 * B * G;

    // stage k2 0..7 into LDS (thread-private; written+read by same thread)
    #pragma unroll
    for (int r = 0; r < 8; r++)
        wst[(kq * 8 + r) * 256 + j] = wp[(size_t)r * 256];
    // resident k2 8..15 in named registers (8 x uint4 = 32 VGPR)
    uint4 wr0 = wp[8 * 256],  wr1 = wp[9 * 256],  wr2 = wp[10 * 256], wr3 = wp[11 * 256];
    uint4 wr4 = wp[12 * 256], wr5 = wp[13 * 256], wr6 = wp[14 * 256], wr7 = wp[15 * 256];
    __syncthreads();

    for (int t = t0; t < tend; t++) {
        int s = t - t0;
        float p0, p1, p2, p3;
        if (kq == 0) {
            const float* pxs = pxd + ((size_t)s * B + b) * G;
            p0 = pxs[j];
            p1 = pxs[256 + j];
            p2 = pxs[512 + j];
            p3 = pxs[768 + j];
        }
        float a0 = 0.f, a1 = 0.f, a2 = 0.f, a3 = 0.f;

        const unsigned* hhc = hh + cur * 128 + kq * 32;

        // streamed k2 16..31 first (loads issue early)
        #pragma unroll 4
        for (int r = 16; r < 32; r++) {
            uint4 wv = wp[(size_t)r * 256];
            unsigned hu = hhc[r];              // wave-uniform -> broadcast
            half2v hhv;
            __builtin_memcpy(&hhv, &hu, 4);
            a0 = fdot2_(wv.x, hhv, a0);
            a1 = fdot2_(wv.y, hhv, a1);
            a2 = fdot2_(wv.z, hhv, a2);
            a3 = fdot2_(wv.w, hhv, a3);
        }
        // LDS-cached k2 0..7
        #pragma unroll
        for (int r = 0; r < 8; r++) {
            uint4 wv = wst[(kq * 8 + r) * 256 + j];
            unsigned hu = hhc[r];
            half2v hhv;
            __builtin_memcpy(&hhv, &hu, 4);
            a0 = fdot2_(wv.x, hhv, a0);
            a1 = fdot2_(wv.y, hhv, a1);
            a2 = fdot2_(wv.z, hhv, a2);
            a3 = fdot2_(wv.w, hhv, a3);
        }
        // register-resident k2 8..15
        {
            unsigned hu;
            half2v hv;
            #define RES_DOT(WR, IDX)                                   \
                hu = hhc[IDX];                                         \
                __builtin_memcpy(&hv, &hu, 4);                         \
                a0 = fdot2_(WR.x, hv, a0); a1 = fdot2_(WR.y, hv, a1);  \
                a2 = fdot2_(WR.z, hv, a2); a3 = fdot2_(WR.w, hv, a3);
            RES_DOT(wr0, 8)
            RES_DOT(wr1, 9)
            RES_DOT(wr2, 10)
            RES_DOT(wr3, 11)
            RES_DOT(wr4, 12)
            RES_DOT(wr5, 13)
            RES_DOT(wr6, 14)
            RES_DOT(wr7, 15)
            #undef RES_DOT
        }

        if (kq > 0) part[(kq - 1) * 257 + j] = make_float4(a0, a1, a2, a3);
        __syncthreads();

        if (kq == 0) {
            #pragma unroll
            for (int q = 0; q < 3; q++) {
                float4 qv = part[q * 257 + j];
                a0 += qv.x; a1 += qv.y; a2 += qv.z; a3 += qv.w;
            }
            a0 += p0; a1 += p1; a2 += p2; a3 += p3;

            float ig = sigmoidf_(a0), fg = sigmoidf_(a1), og = sigmoidf_(a3);
            c = fg * c + ig * tanhf(a2);
            float h = og * tanhf(c);

            hping[(cur ^ 1) * 256 + j] = h;
            float hn = __shfl_down(h, 1);
            if (!(j & 1)) {
                half2v hv2 = packh2_(h, hn);
                unsigned hu;
                __builtin_memcpy(&hu, &hv2, 4);
                hh[(cur ^ 1) * 128 + (j >> 1)] = hu;
            }
            int pos = d ? (len - 1 - t) : t;
            hc_out[((size_t)b * T + pos) * (2 * H) + d * H + j] = h;
        }
        __syncthreads();
        cur ^= 1;
    }

    if (kq == 0) {
        cstate[((size_t)d * B + b) * H + j] = c;
        hbufg[j] = hping[cur * 256 + j];
    }
}

// ---------------- attention logits (masked), f16 dot2, prefetched --------
// grid (8 tt, 128 b), block 256 = 4 waves; wave handles 16 t, lane owns
// k-pairs {l, l+64, l+128, l+192}. W_s1 in LDS as lane-major uint4
// (25.6 KB -> 6 blocks/CU capacity vs round-14's 51.7 KB / 3 blocks).
__global__ __launch_bounds__(256) void logits_kernel(const int* __restrict__ lengths,
                                                     const float* __restrict__ hc,
                                                     const uint4* __restrict__ ws1p,
                                                     const float* __restrict__ Ws2,
                                                     float* __restrict__ S) {
    __shared__ uint4 s_w1[DA * 64];    // 25600 B
    __shared__ float s_w2[HEADS * DA];
    int b = blockIdx.y, tt = blockIdx.x;
    int tid = threadIdx.x;
    for (int i = tid; i < DA * 64; i += 256) s_w1[i] = ws1p[i];
    for (int i = tid; i < HEADS * DA; i += 256) s_w2[i] = Ws2[i];
    __syncthreads();

    int len = lengths[b];
    int lane = tid & 63, wave = tid >> 6;
    int tbase = tt * 64 + wave * 16;

    if (tbase >= len) {
        if (lane < HEADS) {
            #pragma unroll
            for (int ti = 0; ti < 16; ti++)
                S[((size_t)b * HEADS + lane) * T + tbase + ti] = NEGINF;
        }
        return;
    }

    const float2* hc2 = (const float2*)hc;
    size_t rowbase = ((size_t)b * T + tbase) * 256 + lane;
    // prefetch ti = 0
    float2 f0 = hc2[rowbase];
    float2 f1 = hc2[rowbase + 64];
    float2 f2 = hc2[rowbase + 128];
    float2 f3 = hc2[rowbase + 192];

    for (int ti = 0; ti < 16; ti++) {
        int t = tbase + ti;
        // prefetch next t (clamped to valid row)
        int tn = tbase + ti + 1;
        if (tn >= len) tn = len - 1;
        size_t rn = ((size_t)b * T + tn) * 256 + lane;
        float2 n0 = hc2[rn];
        float2 n1 = hc2[rn + 64];
        float2 n2 = hc2[rn + 128];
        float2 n3 = hc2[rn + 192];

        if (t < len) {
            half2v h0 = packh2_(f0.x, f0.y);
            half2v h1 = packh2_(f1.x, f1.y);
            half2v h2 = packh2_(f2.x, f2.y);
            half2v h3 = packh2_(f3.x, f3.y);
            float y[DA];
            #pragma unroll
            for (int r = 0; r < DA; r++) {
                uint4 w = s_w1[r * 64 + lane];
                float v = fdot2_(w.x, h0, 0.f);
                v = fdot2_(w.y, h1, v);
                v = fdot2_(w.z, h2, v);
                v = fdot2_(w.w, h3, v);
                y[r] = v;
            }
            #pragma unroll
            for (int r = 0; r < DA; r++) {
                float v = y[r];
                for (int off = 32; off; off >>= 1) v += __shfl_xor(v, off, 64);
                y[r] = tanhf(v);
            }
            if (lane < HEADS) {
                float s = 0.f;
                #pragma unroll
                for (int r = 0; r < DA; r++) s += y[r] * s_w2[lane * DA + r];
                S[((size_t)b * HEADS + lane) * T + t] = s;
            }
        } else {
            if (lane < HEADS) S[((size_t)b * HEADS + lane) * T + t] = NEGINF;
        }
        f0 = n0; f1 = n1; f2 = n2; f3 = n3;
    }
}

// ---------------- masked softmax over T, in place ----------------
__global__ __launch_bounds__(256) void softmax_kernel(float* __restrict__ S) {
    int row = blockIdx.x;
    float* p = S + (size_t)row * T;
    int tid = threadIdx.x;
    int lane = tid & 63, wave = tid >> 6;
    __shared__ float rr[4], ss[4];

    float mx = NEGINF;
    #pragma unroll
    for (int i = 0; i < 2; i++) mx = fmaxf(mx, p[tid + i * 256]);
    for (int off = 32; off; off >>= 1) mx = fmaxf(mx, __shfl_xor(mx, off, 64));
    if (lane == 0) rr[wave] = mx;
    __syncthreads();
    mx = fmaxf(fmaxf(rr[0], rr[1]), fmaxf(rr[2], rr[3]));

    float e[2], sum = 0.f;
    #pragma unroll
    for (int i = 0; i < 2; i++) { e[i] = expf(p[tid + i * 256] - mx); sum += e[i]; }
    for (int off = 32; off; off >>= 1) sum += __shfl_xor(sum, off, 64);
    if (lane == 0) ss[wave] = sum;
    __syncthreads();
    sum = ss[0] + ss[1] + ss[2] + ss[3];
    float inv = 1.f / sum;
    #pragma unroll
    for (int i = 0; i < 2; i++) p[tid + i * 256] = e[i] * inv;
}

// ---------------- M = A @ Hc -> sentence embeddings (d_out) ----------------
__global__ __launch_bounds__(256) void attnM_kernel(const int* __restrict__ lengths,
                                                    const float* __restrict__ A,
                                                    const float* __restrict__ hc,
                                                    float* __restrict__ out) {
    int b = blockIdx.x, tid = threadIdx.x;
    int len = lengths[b];
    const float* Ab  = A + (size_t)b * HEADS * T;
    const float* hcb = hc + (size_t)b * T * (2 * H);
    float acc[HEADS][2];
    #pragma unroll
    for (int h = 0; h < HEADS; h++) { acc[h][0] = 0.f; acc[h][1] = 0.f; }
    for (int t = 0; t < len; t++) {
        float v0 = hcb[(size_t)t * (2 * H) + tid];
        float v1 = hcb[(size_t)t * (2 * H) + H + tid];
        #pragma unroll
        for (int h = 0; h < HEADS; h++) {
            float a = Ab[h * T + t];
            acc[h][0] += a * v0;
            acc[h][1] += a * v1;
        }
    }
    #pragma unroll
    for (int h = 0; h < HEADS; h++) {
        out[(size_t)b * (HEADS * 2 * H) + h * (2 * H) + tid]     = acc[h][0];
        out[(size_t)b * (HEADS * 2 * H) + h * (2 * H) + H + tid] = acc[h][1];
    }
}

// ---------------- penalization ----------------
__global__ __launch_bounds__(256) void penal_kernel(const float* __restrict__ A,
                                                    float* __restrict__ part) {
    int b = blockIdx.x, tid = threadIdx.x;
    const float* Ab = A + (size_t)b * HEADS * T;
    float p[10];
    #pragma unroll
    for (int i = 0; i < 10; i++) p[i] = 0.f;
    for (int t = tid; t < T; t += 256) {
        float a0 = Ab[t], a1 = Ab[T + t], a2 = Ab[2 * T + t], a3 = Ab[3 * T + t], a4 = Ab[4 * T + t];
        p[0] += a0 * a1; p[1] += a0 * a2; p[2] += a0 * a3; p[3] += a0 * a4;
        p[4] += a1 * a2; p[5] += a1 * a3; p[6] += a1 * a4;
        p[7] += a2 * a3; p[8] += a2 * a4; p[9] += a3 * a4;
    }
    __shared__ float red[10][4];
    int lane = tid & 63, wave = tid >> 6;
    #pragma unroll
    for (int i = 0; i < 10; i++) {
        float v = p[i];
        for (int off = 32; off; off >>= 1) v += __shfl_xor(v, off, 64);
        if (lane == 0) red[i][wave] = v;
    }
    __syncthreads();
    if (tid == 0) {
        float s = 0.f;
        #pragma unroll
        for (int i = 0; i < 10; i++) {
            float P = red[i][0] + red[i][1] + red[i][2] + red[i][3];
            s += 2.f * P * P;
        }
        part[b] = s;
    }
}

__global__ __launch_bounds__(128) void final_kernel(const float* __restrict__ part,
                                                    float* __restrict__ out) {
    int tid = threadIdx.x;
    float v = part[tid];
    for (int off = 32; off; off >>= 1) v += __shfl_xor(v, off, 64);
    __shared__ float r2[2];
    if ((tid & 63) == 0) r2[tid >> 6] = v;
    __syncthreads();
    if (tid == 0) out[(size_t)B * HEADS * 2 * H] = (r2[0] + r2[1]) * (1.f / (float)B);
}

// ---------------- host launcher ----------------
extern "C" void kernel_launch(void* const* d_in, const int* in_sizes, int n_in,
                              void* d_out, int out_size, void* d_ws, size_t ws_size,
                              hipStream_t stream) {
    const int*   word_ids = (const int*)d_in[0];
    const int*   lengths  = (const int*)d_in[1];
    const float* emb      = (const float*)d_in[2];
    const float* W_ih_f   = (const float*)d_in[3];
    const float* W_hh_f   = (const float*)d_in[4];
    const float* b_f      = (const float*)d_in[5];
    const float* W_ih_b   = (const float*)d_in[6];
    const float* W_hh_b   = (const float*)d_in[7];
    const float* b_b      = (const float*)d_in[8];
    const float* W_s1     = (const float*)d_in[9];
    const float* W_s2     = (const float*)d_in[10];
    float* out = (float*)d_out;

    char* ws = (char*)d_ws;
    unsigned short* wbt16 = (unsigned short*)(ws + WBT_OFF);
    unsigned*       wbt   = (unsigned*)(ws + WBT_OFF);
    unsigned short* wih16 = (unsigned short*)(ws + WIH_OFF);
    unsigned*       wihu  = (unsigned*)(ws + WIH_OFF);
    unsigned short* ws1p16 = (unsigned short*)(ws + WS1T_OFF);
    const uint4*    ws1p4  = (const uint4*)(ws + WS1T_OFF);
    float* pxc    = (float*)(ws + PX_OFF);
    float* hc     = (float*)(ws + HC_OFF);
    float* hbuf   = (float*)(ws + HBUF_OFF);
    float* cstate = (float*)(ws + CST_OFF);
    float* Abuf   = (float*)(ws + A_OFF);
    float* part   = (float*)(ws + PART_OFF);

    prep_kernel<<<2048, 256, 0, stream>>>(W_hh_f, W_hh_b, W_ih_f, W_ih_b, W_s1,
                                          wbt16, wih16, ws1p16);

    for (int c = 0; c < 8; c++) {
        proj_kernel<<<dim3(16, 128, 2), 256, 0, stream>>>(
            word_ids, lengths, emb, wihu, b_f, b_b, pxc, c);
        lstm6_kernel<<<dim3(128, 2), 1024, LSTM_LDS_BYTES, stream>>>(
            lengths, wbt, pxc, hc, hbuf, cstate, c);
    }

    logits_kernel<<<dim3(8, 128), 256, 0, stream>>>(lengths, hc, ws1p4, W_s2, Abuf);
    softmax_kernel<<<B * HEADS, 256, 0, stream>>>(Abuf);
    attnM_kernel<<<B, 256, 0, stream>>>(lengths, Abuf, hc, out);
    penal_kernel<<<B, 256, 0, stream>>>(Abuf, part);
    final_kernel<<<1, 128, 0, stream>>>(part, out);
}

// Round 16
// 2320.271 us; speedup vs baseline: 6.0250x; 1.0897x over previous
//
#include <hip/hip_runtime.h>
#include <math.h>

#define T 512
#define B 128
#define E 256
#define H 256
#define G 1024   // 4H
#define DA 25
#define HEADS 5
#define NEGINF (-1e30f)

// ---------------- workspace layout (bytes) ----------------
static constexpr size_t WBT_OFF  = 0;           // [2][128 k2][256 j][4 gate] uint (f16 pair W_hh) 1,048,576
static constexpr size_t WIH_OFF  = 1048576;     // [2][1024 g][256 e] ushort (f16 W_ih)            1,048,576
static constexpr size_t WS1T_OFF = 2097152;     // [25 r][64 l] uint4 (f16 W_s1, lane-major)          25,600
static constexpr size_t PX_OFF   = 2148352;     // [2][64][128][1024] f32     67,108,864
static constexpr size_t HC_OFF   = 69257216;    // [128][512][512] f32       134,217,728
static constexpr size_t HBUF_OFF = 203474944;   // [2][128 b][256 j] f32         262,144
static constexpr size_t CST_OFF  = 203737088;   // [2][128][256] f32 c-state     262,144
static constexpr size_t A_OFF    = 203999232;   // [128][5][512] f32           1,310,720
static constexpr size_t PART_OFF = 205309952;   // [128] f32                         512

// ---- lstm6 dynamic LDS layout (bytes) ----
// hh     : [128] u32        @ 0      (512)     packed half2 h (single buffer;
//                                              barrier1/2 separate rd/wr phases)
// part   : [3][257] f32x4   @ 512    (12336)
// wstage : [32][256] uint4  @ 12848  (131072)  8 k2/kq thread-private W cache
static constexpr unsigned LSTM_LDS_BYTES = 143920;

typedef _Float16 half2v __attribute__((ext_vector_type(2)));

__device__ __forceinline__ float sigmoidf_(float x) { return 1.f / (1.f + expf(-x)); }

__device__ __forceinline__ unsigned short f2h_(float f) {   // f32 -> f16 bits
    _Float16 h = (_Float16)f;
    unsigned short u;
    __builtin_memcpy(&u, &h, 2);
    return u;
}

// dot2: acc += w.lo*h.lo + w.hi*h.hi  (f32 accumulate)
__device__ __forceinline__ float fdot2_(unsigned w, half2v h, float acc) {
#if __has_builtin(__builtin_amdgcn_fdot2)
    half2v wv;
    __builtin_memcpy(&wv, &w, 4);
    return __builtin_amdgcn_fdot2(wv, h, acc, false);
#else
    unsigned short lo = (unsigned short)(w & 0xffffu), hi = (unsigned short)(w >> 16);
    _Float16 w0, w1;
    __builtin_memcpy(&w0, &lo, 2);
    __builtin_memcpy(&w1, &hi, 2);
    return fmaf((float)w0, (float)h[0], fmaf((float)w1, (float)h[1], acc));
#endif
}

__device__ __forceinline__ half2v packh2_(float a, float b) {
    half2v h;
    h[0] = (_Float16)a;
    h[1] = (_Float16)b;
    return h;
}

// ---------------- prep: pack W_hh + W_ih + W_s1 to f16 ---------------------
// wbt ushort layout: [((d*128 + k2)*256 + j)*8 + gate*2 + ke]
// wih ushort layout: [(d*1024 + g)*256 + e]
// ws1p ushort layout: [(r*64 + l)*8 + q*2 + ke]  (kp = l + 64q, k = 2kp+ke)
__global__ __launch_bounds__(256) void prep_kernel(const float* __restrict__ Whf,
                                                   const float* __restrict__ Whb,
                                                   const float* __restrict__ Wif,
                                                   const float* __restrict__ Wib,
                                                   const float* __restrict__ Ws1,
                                                   unsigned short* __restrict__ wbt,
                                                   unsigned short* __restrict__ wih,
                                                   unsigned short* __restrict__ ws1p) {
    int idx = blockIdx.x * 256 + threadIdx.x;
    if (idx < 2 * G * H) {
        int d = idx >> 18;
        int rem = idx & 262143;
        int r = rem >> 8;                        // gate row 0..1023
        int k = rem & 255;                       // h index
        const float* W = d ? Whb : Whf;
        int gate = r >> 8, j = r & 255;
        int k2 = k >> 1, ke = k & 1;
        wbt[(((size_t)d * 128 + k2) * 256 + j) * 8 + gate * 2 + ke] = f2h_(W[(size_t)r * H + k]);
        const float* Wi = d ? Wib : Wif;
        wih[((size_t)d * G + r) * 256 + k] = f2h_(Wi[(size_t)r * E + k]);
    }
    if (idx < DA * 512) {
        int r = idx / 512, k = idx % 512;
        int kp = k >> 1, ke = k & 1;
        int l = kp & 63, q = kp >> 6;
        ws1p[((r * 64 + l) * 4 + q) * 2 + ke] = f2h_(Ws1[idx]);
    }
}

// ---------------- input projection, f16 dot2, one 64-step chunk ----------
// grid (16 gtiles, 128 b, 2 dir), block 256. k-block = 32 e (16 pairs).
__global__ __launch_bounds__(256) void proj_kernel(const int* __restrict__ word_ids,
                                                   const int* __restrict__ lengths,
                                                   const float* __restrict__ emb,
                                                   const unsigned* __restrict__ wih,
                                                   const float* __restrict__ bf,
                                                   const float* __restrict__ bb,
                                                   float* __restrict__ pxc, int chunk) {
    int g0 = blockIdx.x * 64;
    int b  = blockIdx.y;
    int d  = blockIdx.z;
    int len = lengths[b];
    int t0 = chunk * 64;
    if (t0 >= len) return;
    const float* bias = d ? bb : bf;

    __shared__ int      wid[64];
    __shared__ unsigned As2[64][17];   // [m][kp] emb as f16 pairs
    __shared__ unsigned Bs2[64][17];   // [m][kp] W_ih as f16 pairs

    int tid = threadIdx.x;
    if (tid < 64) {
        int t = t0 + tid;
        int src;
        if (d == 0) src = t;
        else { src = len - 1 - t; if (src < 0) src = 0; }
        wid[tid] = word_ids[b * T + src];
    }
    __syncthreads();

    int tx = tid & 15, ty = tid >> 4;   // compute mapping
    int lk = tid & 15, lm = tid >> 4;   // load mapping (kp 0..15, m base)
    const unsigned* wihd = wih + ((size_t)d * G + g0) * 128;

    float acc[4][4];
    #pragma unroll
    for (int i = 0; i < 4; i++)
        #pragma unroll
        for (int j = 0; j < 4; j++) acc[i][j] = 0.f;

    for (int k0 = 0; k0 < E; k0 += 32) {
        int e2 = k0 >> 1;
        #pragma unroll
        for (int i = 0; i < 4; i++) {
            int m = lm + 16 * i;
            const float* ep = emb + (size_t)wid[m] * E + k0 + 2 * lk;
            half2v av = packh2_(ep[0], ep[1]);
            unsigned au;
            __builtin_memcpy(&au, &av, 4);
            As2[m][lk] = au;
            Bs2[m][lk] = wihd[(size_t)m * 128 + e2 + lk];
        }
        __syncthreads();
        #pragma unroll
        for (int kp = 0; kp < 16; kp++) {
            unsigned a2[4], b2[4];
            #pragma unroll
            for (int i = 0; i < 4; i++) a2[i] = As2[ty * 4 + i][kp];
            #pragma unroll
            for (int j = 0; j < 4; j++) b2[j] = Bs2[tx * 4 + j][kp];
            #pragma unroll
            for (int i = 0; i < 4; i++) {
                half2v ah;
                __builtin_memcpy(&ah, &a2[i], 4);
                #pragma unroll
                for (int j = 0; j < 4; j++)
                    acc[i][j] = fdot2_(b2[j], ah, acc[i][j]);
            }
        }
        __syncthreads();
    }
    #pragma unroll
    for (int i = 0; i < 4; i++) {
        int m = ty * 4 + i;
        #pragma unroll
        for (int j = 0; j < 4; j++) {
            int n = tx * 4 + j;
            pxc[((size_t)(d * 64 + m) * B + b) * G + g0 + n] = acc[i][j] + bias[g0 + n];
        }
    }
}

// ---------------- LSTM recurrence: residency-split W ----------------
// grid (128 b, 2 dir); block 1024 = 16 waves.
// Thread (j = tid&255, kq = tid>>8) owns 32 k2 of hidden col j:
//   k2 0..7  : staged in LDS once per chunk (thread-private cache, 128 KB/block)
//   k2 8..19 : 12 NAMED uint4 registers (48 VGPR raw; VGPR est ~56-60 < 64 cap)
//   k2 20..31: streamed from L2 -> 192 KB/step (was 256)
// h packed half2 in single-buffer LDS (barrier1/2 separate read/write phases);
// f32 h lives in kq0 registers only (hping removed).
__global__ __launch_bounds__(1024) void lstm6_kernel(const int* __restrict__ lengths,
                                                     const unsigned* __restrict__ wbt,
                                                     const float* __restrict__ pxc,
                                                     float* __restrict__ hc_out,
                                                     float* __restrict__ hbuf,
                                                     float* __restrict__ cstate,
                                                     int chunk) {
    int b   = blockIdx.x;
    int d   = blockIdx.y;
    int tid = threadIdx.x;
    int j  = tid & 255;
    int kq = tid >> 8;                 // 0..3 (wave-uniform)

    int len = lengths[b];
    int t0 = chunk * 64;
    if (t0 >= len) return;
    int tend = min(t0 + 64, len);

    extern __shared__ char smem[];
    unsigned* hh   = (unsigned*)smem;                // [128]
    float4*   part = (float4*)(smem + 512);          // [3][257]
    uint4*    wst  = (uint4*)(smem + 12848);         // [32][256]

    float* hbufg = hbuf + ((size_t)d * B + b) * 256;

    float c = 0.f, hreg = 0.f;
    if (chunk == 0) {
        if (tid < 128) hh[tid] = 0u;
    } else {
        if (kq == 0) c = cstate[((size_t)d * B + b) * H + j];
        if (tid < 128) {
            half2v hv2 = packh2_(hbufg[2 * tid], hbufg[2 * tid + 1]);
            unsigned hu;
            __builtin_memcpy(&hu, &hv2, 4);
            hh[tid] = hu;
        }
    }

    // thread's W rows: k2 in [kq*32, kq*32+32), column j
    const uint4* wp  = (const uint4*)wbt + ((size_t)d * 128 + kq * 32) * 256 + j;
    const float* pxd = pxc + (size_t)d * 64 * B * G;

    // stage k2 0..7 into LDS (thread-private; written+read by same thread)
    #pragma unroll
    for (int r = 0; r < 8; r++)
        wst[(kq * 8 + r) * 256 + j] = wp[(size_t)r * 256];
    // resident k2 8..19 in named registers (12 x uint4 = 48 VGPR raw)
    uint4 wr0 = wp[8 * 256],  wr1 = wp[9 * 256],  wr2  = wp[10 * 256], wr3  = wp[11 * 256];
    uint4 wr4 = wp[12 * 256], wr5 = wp[13 * 256], wr6  = wp[14 * 256], wr7  = wp[15 * 256];
    uint4 wr8 = wp[16 * 256], wr9 = wp[17 * 256], wr10 = wp[18 * 256], wr11 = wp[19 * 256];
    __syncthreads();

    for (int t = t0; t < tend; t++) {
        int s = t - t0;
        float p0, p1, p2, p3;
        if (kq == 0) {
            const float* pxs = pxd + ((size_t)s * B + b) * G;
            p0 = pxs[j];
            p1 = pxs[256 + j];
            p2 = pxs[512 + j];
            p3 = pxs[768 + j];
        }
        float a0 = 0.f, a1 = 0.f, a2 = 0.f, a3 = 0.f;

        const unsigned* hhc = hh + kq * 32;

        // streamed k2 20..31 first (loads issue early)
        #pragma unroll 4
        for (int r = 20; r < 32; r++) {
            uint4 wv = wp[(size_t)r * 256];
            unsigned hu = hhc[r];              // wave-uniform -> broadcast
            half2v hhv;
            __builtin_memcpy(&hhv, &hu, 4);
            a0 = fdot2_(wv.x, hhv, a0);
            a1 = fdot2_(wv.y, hhv, a1);
            a2 = fdot2_(wv.z, hhv, a2);
            a3 = fdot2_(wv.w, hhv, a3);
        }
        // LDS-cached k2 0..7
        #pragma unroll
        for (int r = 0; r < 8; r++) {
            uint4 wv = wst[(kq * 8 + r) * 256 + j];
            unsigned hu = hhc[r];
            half2v hhv;
            __builtin_memcpy(&hhv, &hu, 4);
            a0 = fdot2_(wv.x, hhv, a0);
            a1 = fdot2_(wv.y, hhv, a1);
            a2 = fdot2_(wv.z, hhv, a2);
            a3 = fdot2_(wv.w, hhv, a3);
        }
        // register-resident k2 8..19
        {
            unsigned hu;
            half2v hv;
            #define RES_DOT(WR, IDX)                                   \
                hu = hhc[IDX];                                         \
                __builtin_memcpy(&hv, &hu, 4);                         \
                a0 = fdot2_(WR.x, hv, a0); a1 = fdot2_(WR.y, hv, a1);  \
                a2 = fdot2_(WR.z, hv, a2); a3 = fdot2_(WR.w, hv, a3);
            RES_DOT(wr0, 8)
            RES_DOT(wr1, 9)
            RES_DOT(wr2, 10)
            RES_DOT(wr3, 11)
            RES_DOT(wr4, 12)
            RES_DOT(wr5, 13)
            RES_DOT(wr6, 14)
            RES_DOT(wr7, 15)
            RES_DOT(wr8, 16)
            RES_DOT(wr9, 17)
            RES_DOT(wr10, 18)
            RES_DOT(wr11, 19)
            #undef RES_DOT
        }

        if (kq > 0) part[(kq - 1) * 257 + j] = make_float4(a0, a1, a2, a3);
        __syncthreads();           // barrier 1: partials ready; hh reads done

        if (kq == 0) {
            #pragma unroll
            for (int q = 0; q < 3; q++) {
                float4 qv = part[q * 257 + j];
                a0 += qv.x; a1 += qv.y; a2 += qv.z; a3 += qv.w;
            }
            a0 += p0; a1 += p1; a2 += p2; a3 += p3;

            float ig = sigmoidf_(a0), fg = sigmoidf_(a1), og = sigmoidf_(a3);
            c = fg * c + ig * tanhf(a2);
            float h = og * tanhf(c);
            hreg = h;

            float hn = __shfl_down(h, 1);
            if (!(j & 1)) {
                half2v hv2 = packh2_(h, hn);
                unsigned hu;
                __builtin_memcpy(&hu, &hv2, 4);
                hh[j >> 1] = hu;
            }
            int pos = d ? (len - 1 - t) : t;
            hc_out[((size_t)b * T + pos) * (2 * H) + d * H + j] = h;
        }
        __syncthreads();           // barrier 2: hh updated before next reads
    }

    if (kq == 0) {
        cstate[((size_t)d * B + b) * H + j] = c;
        hbufg[j] = hreg;
    }
}

// ---------------- attention logits (masked), f16 dot2, prefetched --------
__global__ __launch_bounds__(256) void logits_kernel(const int* __restrict__ lengths,
                                                     const float* __restrict__ hc,
                                                     const uint4* __restrict__ ws1p,
                                                     const float* __restrict__ Ws2,
                                                     float* __restrict__ S) {
    __shared__ uint4 s_w1[DA * 64];    // 25600 B
    __shared__ float s_w2[HEADS * DA];
    int b = blockIdx.y, tt = blockIdx.x;
    int tid = threadIdx.x;
    for (int i = tid; i < DA * 64; i += 256) s_w1[i] = ws1p[i];
    for (int i = tid; i < HEADS * DA; i += 256) s_w2[i] = Ws2[i];
    __syncthreads();

    int len = lengths[b];
    int lane = tid & 63, wave = tid >> 6;
    int tbase = tt * 64 + wave * 16;

    if (tbase >= len) {
        if (lane < HEADS) {
            #pragma unroll
            for (int ti = 0; ti < 16; ti++)
                S[((size_t)b * HEADS + lane) * T + tbase + ti] = NEGINF;
        }
        return;
    }

    const float2* hc2 = (const float2*)hc;
    size_t rowbase = ((size_t)b * T + tbase) * 256 + lane;
    float2 f0 = hc2[rowbase];
    float2 f1 = hc2[rowbase + 64];
    float2 f2 = hc2[rowbase + 128];
    float2 f3 = hc2[rowbase + 192];

    for (int ti = 0; ti < 16; ti++) {
        int t = tbase + ti;
        int tn = tbase + ti + 1;
        if (tn >= len) tn = len - 1;
        size_t rn = ((size_t)b * T + tn) * 256 + lane;
        float2 n0 = hc2[rn];
        float2 n1 = hc2[rn + 64];
        float2 n2 = hc2[rn + 128];
        float2 n3 = hc2[rn + 192];

        if (t < len) {
            half2v h0 = packh2_(f0.x, f0.y);
            half2v h1 = packh2_(f1.x, f1.y);
            half2v h2 = packh2_(f2.x, f2.y);
            half2v h3 = packh2_(f3.x, f3.y);
            float y[DA];
            #pragma unroll
            for (int r = 0; r < DA; r++) {
                uint4 w = s_w1[r * 64 + lane];
                float v = fdot2_(w.x, h0, 0.f);
                v = fdot2_(w.y, h1, v);
                v = fdot2_(w.z, h2, v);
                v = fdot2_(w.w, h3, v);
                y[r] = v;
            }
            #pragma unroll
            for (int r = 0; r < DA; r++) {
                float v = y[r];
                for (int off = 32; off; off >>= 1) v += __shfl_xor(v, off, 64);
                y[r] = tanhf(v);
            }
            if (lane < HEADS) {
                float s = 0.f;
                #pragma unroll
                for (int r = 0; r < DA; r++) s += y[r] * s_w2[lane * DA + r];
                S[((size_t)b * HEADS + lane) * T + t] = s;
            }
        } else {
            if (lane < HEADS) S[((size_t)b * HEADS + lane) * T + t] = NEGINF;
        }
        f0 = n0; f1 = n1; f2 = n2; f3 = n3;
    }
}

// ---------------- masked softmax over T, in place ----------------
__global__ __launch_bounds__(256) void softmax_kernel(float* __restrict__ S) {
    int row = blockIdx.x;
    float* p = S + (size_t)row * T;
    int tid = threadIdx.x;
    int lane = tid & 63, wave = tid >> 6;
    __shared__ float rr[4], ss[4];

    float mx = NEGINF;
    #pragma unroll
    for (int i = 0; i < 2; i++) mx = fmaxf(mx, p[tid + i * 256]);
    for (int off = 32; off; off >>= 1) mx = fmaxf(mx, __shfl_xor(mx, off, 64));
    if (lane == 0) rr[wave] = mx;
    __syncthreads();
    mx = fmaxf(fmaxf(rr[0], rr[1]), fmaxf(rr[2], rr[3]));

    float e[2], sum = 0.f;
    #pragma unroll
    for (int i = 0; i < 2; i++) { e[i] = expf(p[tid + i * 256] - mx); sum += e[i]; }
    for (int off = 32; off; off >>= 1) sum += __shfl_xor(sum, off, 64);
    if (lane == 0) ss[wave] = sum;
    __syncthreads();
    sum = ss[0] + ss[1] + ss[2] + ss[3];
    float inv = 1.f / sum;
    #pragma unroll
    for (int i = 0; i < 2; i++) p[tid + i * 256] = e[i] * inv;
}

// ---------------- M = A @ Hc -> sentence embeddings (d_out) ----------------
__global__ __launch_bounds__(256) void attnM_kernel(const int* __restrict__ lengths,
                                                    const float* __restrict__ A,
                                                    const float* __restrict__ hc,
                                                    float* __restrict__ out) {
    int b = blockIdx.x, tid = threadIdx.x;
    int len = lengths[b];
    const float* Ab  = A + (size_t)b * HEADS * T;
    const float* hcb = hc + (size_t)b * T * (2 * H);
    float acc[HEADS][2];
    #pragma unroll
    for (int h = 0; h < HEADS; h++) { acc[h][0] = 0.f; acc[h][1] = 0.f; }
    for (int t = 0; t < len; t++) {
        float v0 = hcb[(size_t)t * (2 * H) + tid];
        float v1 = hcb[(size_t)t * (2 * H) + H + tid];
        #pragma unroll
        for (int h = 0; h < HEADS; h++) {
            float a = Ab[h * T + t];
            acc[h][0] += a * v0;
            acc[h][1] += a * v1;
        }
    }
    #pragma unroll
    for (int h = 0; h < HEADS; h++) {
        out[(size_t)b * (HEADS * 2 * H) + h * (2 * H) + tid]     = acc[h][0];
        out[(size_t)b * (HEADS * 2 * H) + h * (2 * H) + H + tid] = acc[h][1];
    }
}

// ---------------- penalization ----------------
__global__ __launch_bounds__(256) void penal_kernel(const float* __restrict__ A,
                                                    float* __restrict__ part) {
    int b = blockIdx.x, tid = threadIdx.x;
    const float* Ab = A + (size_t)b * HEADS * T;
    float p[10];
    #pragma unroll
    for (int i = 0; i < 10; i++) p[i] = 0.f;
    for (int t = tid; t < T; t += 256) {
        float a0 = Ab[t], a1 = Ab[T + t], a2 = Ab[2 * T + t], a3 = Ab[3 * T + t], a4 = Ab[4 * T + t];
        p[0] += a0 * a1; p[1] += a0 * a2; p[2] += a0 * a3; p[3] += a0 * a4;
        p[4] += a1 * a2; p[5] += a1 * a3; p[6] += a1 * a4;
        p[7] += a2 * a3; p[8] += a2 * a4; p[9] += a3 * a4;
    }
    __shared__ float red[10][4];
    int lane = tid & 63, wave = tid >> 6;
    #pragma unroll
    for (int i = 0; i < 10; i++) {
        float v = p[i];
        for (int off = 32; off; off >>= 1) v += __shfl_xor(v, off, 64);
        if (lane == 0) red[i][wave] = v;
    }
    __syncthreads();
    if (tid == 0) {
        float s = 0.f;
        #pragma unroll
        for (int i = 0; i < 10; i++) {
            float P = red[i][0] + red[i][1] + red[i][2] + red[i][3];
            s += 2.f * P * P;
        }
        part[b] = s;
    }
}

__global__ __launch_bounds__(128) void final_kernel(const float* __restrict__ part,
                                                    float* __restrict__ out) {
    int tid = threadIdx.x;
    float v = part[tid];
    for (int off = 32; off; off >>= 1) v += __shfl_xor(v, off, 64);
    __shared__ float r2[2];
    if ((tid & 63) == 0) r2[tid >> 6] = v;
    __syncthreads();
    if (tid == 0) out[(size_t)B * HEADS * 2 * H] = (r2[0] + r2[1]) * (1.f / (float)B);
}

// ---------------- host launcher ----------------
extern "C" void kernel_launch(void* const* d_in, const int* in_sizes, int n_in,
                              void* d_out, int out_size, void* d_ws, size_t ws_size,
                              hipStream_t stream) {
    const int*   word_ids = (const int*)d_in[0];
    const int*   lengths  = (const int*)d_in[1];
    const float* emb      = (const float*)d_in[2];
    const float* W_ih_f   = (const float*)d_in[3];
    const float* W_hh_f   = (const float*)d_in[4];
    const float* b_f      = (const float*)d_in[5];
    const float* W_ih_b   = (const float*)d_in[6];
    const float* W_hh_b   = (const float*)d_in[7];
    const float* b_b      = (const float*)d_in[8];
    const float* W_s1     = (const float*)d_in[9];
    const float* W_s2     = (const float*)d_in[10];
    float* out = (float*)d_out;

    char* ws = (char*)d_ws;
    unsigned short* wbt16 = (unsigned short*)(ws + WBT_OFF);
    unsigned*       wbt   = (unsigned*)(ws + WBT_OFF);
    unsigned short* wih16 = (unsigned short*)(ws + WIH_OFF);
    unsigned*       wihu  = (unsigned*)(ws + WIH_OFF);
    unsigned short* ws1p16 = (unsigned short*)(ws + WS1T_OFF);
    const uint4*    ws1p4  = (const uint4*)(ws + WS1T_OFF);
    float* pxc    = (float*)(ws + PX_OFF);
    float* hc     = (float*)(ws + HC_OFF);
    float* hbuf   = (float*)(ws + HBUF_OFF);
    float* cstate = (float*)(ws + CST_OFF);
    float* Abuf   = (float*)(ws + A_OFF);
    float* part   = (float*)(ws + PART_OFF);

    prep_kernel<<<2048, 256, 0, stream>>>(W_hh_f, W_hh_b, W_ih_f, W_ih_b, W_s1,
                                          wbt16, wih16, ws1p16);

    for (int c = 0; c < 8; c++) {
        proj_kernel<<<dim3(16, 128, 2), 256, 0, stream>>>(
            word_ids, lengths, emb, wihu, b_f, b_b, pxc, c);
        lstm6_kernel<<<dim3(128, 2), 1024, LSTM_LDS_BYTES, stream>>>(
            lengths, wbt, pxc, hc, hbuf, cstate, c);
    }

    logits_kernel<<<dim3(8, 128), 256, 0, stream>>>(lengths, hc, ws1p4, W_s2, Abuf);
    softmax_kernel<<<B * HEADS, 256, 0, stream>>>(Abuf);
    attnM_kernel<<<B, 256, 0, stream>>>(lengths, Abuf, hc, out);
    penal_kernel<<<B, 256, 0, stream>>>(Abuf, part);
    final_kernel<<<1, 128, 0, stream>>>(part, out);
}

// Round 17
// 2284.666 us; speedup vs baseline: 6.1189x; 1.0156x over previous
//
#include <hip/hip_runtime.h>
#include <math.h>

#define T 512
#define B 128
#define E 256
#define H 256
#define G 1024   // 4H
#define DA 25
#define HEADS 5
#define NEGINF (-1e30f)

// ---------------- workspace layout (bytes) ----------------
static constexpr size_t WBT_OFF  = 0;           // [2][128 k2][256 j][4 gate] uint (f16 pair W_hh) 1,048,576
static constexpr size_t WIH_OFF  = 1048576;     // [2][1024 g][256 e] ushort (f16 W_ih)            1,048,576
static constexpr size_t WS1T_OFF = 2097152;     // [25 r][64 l] uint4 (f16 W_s1, lane-major)          25,600
static constexpr size_t PX_OFF   = 2148352;     // [2][64][128][1024] f32     67,108,864
static constexpr size_t HC_OFF   = 69257216;    // [128][512][512] f32       134,217,728
static constexpr size_t HBUF_OFF = 203474944;   // [2][128 b][256 j] f32         262,144
static constexpr size_t CST_OFF  = 203737088;   // [2][128][256] f32 c-state     262,144
static constexpr size_t A_OFF    = 203999232;   // [128][5][512] f32           1,310,720
static constexpr size_t PART_OFF = 205309952;   // [128] f32                         512

// ---- lstm6 dynamic LDS layout (bytes) ----
// hh     : [128] u32        @ 0      (512)
// part   : [3][257] f32x4   @ 512    (12336)
// wstage : [36][256] uint4  @ 12848  (147456)  9 k2/kq thread-private W cache
// total 160304 <= 163840 (160 KiB pool)
static constexpr unsigned LSTM_LDS_BYTES = 160304;

typedef _Float16 half2v __attribute__((ext_vector_type(2)));

__device__ __forceinline__ float sigmoidf_(float x) { return 1.f / (1.f + expf(-x)); }

__device__ __forceinline__ unsigned short f2h_(float f) {   // f32 -> f16 bits
    _Float16 h = (_Float16)f;
    unsigned short u;
    __builtin_memcpy(&u, &h, 2);
    return u;
}

// dot2: acc += w.lo*h.lo + w.hi*h.hi  (f32 accumulate)
__device__ __forceinline__ float fdot2_(unsigned w, half2v h, float acc) {
#if __has_builtin(__builtin_amdgcn_fdot2)
    half2v wv;
    __builtin_memcpy(&wv, &w, 4);
    return __builtin_amdgcn_fdot2(wv, h, acc, false);
#else
    unsigned short lo = (unsigned short)(w & 0xffffu), hi = (unsigned short)(w >> 16);
    _Float16 w0, w1;
    __builtin_memcpy(&w0, &lo, 2);
    __builtin_memcpy(&w1, &hi, 2);
    return fmaf((float)w0, (float)h[0], fmaf((float)w1, (float)h[1], acc));
#endif
}

__device__ __forceinline__ half2v packh2_(float a, float b) {
    half2v h;
    h[0] = (_Float16)a;
    h[1] = (_Float16)b;
    return h;
}

// ---------------- prep: pack W_hh + W_ih + W_s1 to f16 ---------------------
__global__ __launch_bounds__(256) void prep_kernel(const float* __restrict__ Whf,
                                                   const float* __restrict__ Whb,
                                                   const float* __restrict__ Wif,
                                                   const float* __restrict__ Wib,
                                                   const float* __restrict__ Ws1,
                                                   unsigned short* __restrict__ wbt,
                                                   unsigned short* __restrict__ wih,
                                                   unsigned short* __restrict__ ws1p) {
    int idx = blockIdx.x * 256 + threadIdx.x;
    if (idx < 2 * G * H) {
        int d = idx >> 18;
        int rem = idx & 262143;
        int r = rem >> 8;                        // gate row 0..1023
        int k = rem & 255;                       // h index
        const float* W = d ? Whb : Whf;
        int gate = r >> 8, j = r & 255;
        int k2 = k >> 1, ke = k & 1;
        wbt[(((size_t)d * 128 + k2) * 256 + j) * 8 + gate * 2 + ke] = f2h_(W[(size_t)r * H + k]);
        const float* Wi = d ? Wib : Wif;
        wih[((size_t)d * G + r) * 256 + k] = f2h_(Wi[(size_t)r * E + k]);
    }
    if (idx < DA * 512) {
        int r = idx / 512, k = idx % 512;
        int kp = k >> 1, ke = k & 1;
        int l = kp & 63, q = kp >> 6;
        ws1p[((r * 64 + l) * 4 + q) * 2 + ke] = f2h_(Ws1[idx]);
    }
}

// ---------------- input projection, f16 dot2, one 64-step chunk ----------
__global__ __launch_bounds__(256) void proj_kernel(const int* __restrict__ word_ids,
                                                   const int* __restrict__ lengths,
                                                   const float* __restrict__ emb,
                                                   const unsigned* __restrict__ wih,
                                                   const float* __restrict__ bf,
                                                   const float* __restrict__ bb,
                                                   float* __restrict__ pxc, int chunk) {
    int g0 = blockIdx.x * 64;
    int b  = blockIdx.y;
    int d  = blockIdx.z;
    int len = lengths[b];
    int t0 = chunk * 64;
    if (t0 >= len) return;
    const float* bias = d ? bb : bf;

    __shared__ int      wid[64];
    __shared__ unsigned As2[64][17];   // [m][kp] emb as f16 pairs
    __shared__ unsigned Bs2[64][17];   // [m][kp] W_ih as f16 pairs

    int tid = threadIdx.x;
    if (tid < 64) {
        int t = t0 + tid;
        int src;
        if (d == 0) src = t;
        else { src = len - 1 - t; if (src < 0) src = 0; }
        wid[tid] = word_ids[b * T + src];
    }
    __syncthreads();

    int tx = tid & 15, ty = tid >> 4;
    int lk = tid & 15, lm = tid >> 4;
    const unsigned* wihd = wih + ((size_t)d * G + g0) * 128;

    float acc[4][4];
    #pragma unroll
    for (int i = 0; i < 4; i++)
        #pragma unroll
        for (int j = 0; j < 4; j++) acc[i][j] = 0.f;

    for (int k0 = 0; k0 < E; k0 += 32) {
        int e2 = k0 >> 1;
        #pragma unroll
        for (int i = 0; i < 4; i++) {
            int m = lm + 16 * i;
            const float* ep = emb + (size_t)wid[m] * E + k0 + 2 * lk;
            half2v av = packh2_(ep[0], ep[1]);
            unsigned au;
            __builtin_memcpy(&au, &av, 4);
            As2[m][lk] = au;
            Bs2[m][lk] = wihd[(size_t)m * 128 + e2 + lk];
        }
        __syncthreads();
        #pragma unroll
        for (int kp = 0; kp < 16; kp++) {
            unsigned a2[4], b2[4];
            #pragma unroll
            for (int i = 0; i < 4; i++) a2[i] = As2[ty * 4 + i][kp];
            #pragma unroll
            for (int j = 0; j < 4; j++) b2[j] = Bs2[tx * 4 + j][kp];
            #pragma unroll
            for (int i = 0; i < 4; i++) {
                half2v ah;
                __builtin_memcpy(&ah, &a2[i], 4);
                #pragma unroll
                for (int j = 0; j < 4; j++)
                    acc[i][j] = fdot2_(b2[j], ah, acc[i][j]);
            }
        }
        __syncthreads();
    }
    #pragma unroll
    for (int i = 0; i < 4; i++) {
        int m = ty * 4 + i;
        #pragma unroll
        for (int j = 0; j < 4; j++) {
            int n = tx * 4 + j;
            pxc[((size_t)(d * 64 + m) * B + b) * G + g0 + n] = acc[i][j] + bias[g0 + n];
        }
    }
}

// ---------------- LSTM recurrence: residency-split W ----------------
// grid (128 b, 2 dir); block 1024 = 16 waves.
// Thread (j = tid&255, kq = tid>>8) owns 32 k2 of hidden col j:
//   k2 0..8  : staged in LDS once per chunk (147 KB/block)
//   k2 9..20 : 12 NAMED uint4 registers (48 VGPR raw; stays under the 64 cap)
//   k2 21..31: streamed from L2 -> 176 KB/step (was 192)
__global__ __launch_bounds__(1024) void lstm6_kernel(const int* __restrict__ lengths,
                                                     const unsigned* __restrict__ wbt,
                                                     const float* __restrict__ pxc,
                                                     float* __restrict__ hc_out,
                                                     float* __restrict__ hbuf,
                                                     float* __restrict__ cstate,
                                                     int chunk) {
    int b   = blockIdx.x;
    int d   = blockIdx.y;
    int tid = threadIdx.x;
    int j  = tid & 255;
    int kq = tid >> 8;                 // 0..3 (wave-uniform)

    int len = lengths[b];
    int t0 = chunk * 64;
    if (t0 >= len) return;
    int tend = min(t0 + 64, len);

    extern __shared__ char smem[];
    unsigned* hh   = (unsigned*)smem;                // [128]
    float4*   part = (float4*)(smem + 512);          // [3][257]
    uint4*    wst  = (uint4*)(smem + 12848);         // [36][256]

    float* hbufg = hbuf + ((size_t)d * B + b) * 256;

    float c = 0.f, hreg = 0.f;
    if (chunk == 0) {
        if (tid < 128) hh[tid] = 0u;
    } else {
        if (kq == 0) c = cstate[((size_t)d * B + b) * H + j];
        if (tid < 128) {
            half2v hv2 = packh2_(hbufg[2 * tid], hbufg[2 * tid + 1]);
            unsigned hu;
            __builtin_memcpy(&hu, &hv2, 4);
            hh[tid] = hu;
        }
    }

    // thread's W rows: k2 in [kq*32, kq*32+32), column j
    const uint4* wp  = (const uint4*)wbt + ((size_t)d * 128 + kq * 32) * 256 + j;
    const float* pxd = pxc + (size_t)d * 64 * B * G;

    // stage k2 0..8 into LDS (thread-private; written+read by same thread)
    #pragma unroll
    for (int r = 0; r < 9; r++)
        wst[(kq * 9 + r) * 256 + j] = wp[(size_t)r * 256];
    // resident k2 9..20 in named registers (12 x uint4 = 48 VGPR raw)
    uint4 wr0 = wp[9 * 256],  wr1 = wp[10 * 256], wr2  = wp[11 * 256], wr3  = wp[12 * 256];
    uint4 wr4 = wp[13 * 256], wr5 = wp[14 * 256], wr6  = wp[15 * 256], wr7  = wp[16 * 256];
    uint4 wr8 = wp[17 * 256], wr9 = wp[18 * 256], wr10 = wp[19 * 256], wr11 = wp[20 * 256];
    __syncthreads();

    for (int t = t0; t < tend; t++) {
        int s = t - t0;
        float p0, p1, p2, p3;
        if (kq == 0) {
            const float* pxs = pxd + ((size_t)s * B + b) * G;
            p0 = pxs[j];
            p1 = pxs[256 + j];
            p2 = pxs[512 + j];
            p3 = pxs[768 + j];
        }
        float a0 = 0.f, a1 = 0.f, a2 = 0.f, a3 = 0.f;

        const unsigned* hhc = hh + kq * 32;

        // streamed k2 21..31 first (loads issue early)
        #pragma unroll 4
        for (int r = 21; r < 32; r++) {
            uint4 wv = wp[(size_t)r * 256];
            unsigned hu = hhc[r];              // wave-uniform -> broadcast
            half2v hhv;
            __builtin_memcpy(&hhv, &hu, 4);
            a0 = fdot2_(wv.x, hhv, a0);
            a1 = fdot2_(wv.y, hhv, a1);
            a2 = fdot2_(wv.z, hhv, a2);
            a3 = fdot2_(wv.w, hhv, a3);
        }
        // LDS-cached k2 0..8
        #pragma unroll
        for (int r = 0; r < 9; r++) {
            uint4 wv = wst[(kq * 9 + r) * 256 + j];
            unsigned hu = hhc[r];
            half2v hhv;
            __builtin_memcpy(&hhv, &hu, 4);
            a0 = fdot2_(wv.x, hhv, a0);
            a1 = fdot2_(wv.y, hhv, a1);
            a2 = fdot2_(wv.z, hhv, a2);
            a3 = fdot2_(wv.w, hhv, a3);
        }
        // register-resident k2 9..20
        {
            unsigned hu;
            half2v hv;
            #define RES_DOT(WR, IDX)                                   \
                hu = hhc[IDX];                                         \
                __builtin_memcpy(&hv, &hu, 4);                         \
                a0 = fdot2_(WR.x, hv, a0); a1 = fdot2_(WR.y, hv, a1);  \
                a2 = fdot2_(WR.z, hv, a2); a3 = fdot2_(WR.w, hv, a3);
            RES_DOT(wr0, 9)
            RES_DOT(wr1, 10)
            RES_DOT(wr2, 11)
            RES_DOT(wr3, 12)
            RES_DOT(wr4, 13)
            RES_DOT(wr5, 14)
            RES_DOT(wr6, 15)
            RES_DOT(wr7, 16)
            RES_DOT(wr8, 17)
            RES_DOT(wr9, 18)
            RES_DOT(wr10, 19)
            RES_DOT(wr11, 20)
            #undef RES_DOT
        }

        if (kq > 0) part[(kq - 1) * 257 + j] = make_float4(a0, a1, a2, a3);
        __syncthreads();           // barrier 1: partials ready; hh reads done

        if (kq == 0) {
            #pragma unroll
            for (int q = 0; q < 3; q++) {
                float4 qv = part[q * 257 + j];
                a0 += qv.x; a1 += qv.y; a2 += qv.z; a3 += qv.w;
            }
            a0 += p0; a1 += p1; a2 += p2; a3 += p3;

            float ig = sigmoidf_(a0), fg = sigmoidf_(a1), og = sigmoidf_(a3);
            c = fg * c + ig * tanhf(a2);
            float h = og * tanhf(c);
            hreg = h;

            float hn = __shfl_down(h, 1);
            if (!(j & 1)) {
                half2v hv2 = packh2_(h, hn);
                unsigned hu;
                __builtin_memcpy(&hu, &hv2, 4);
                hh[j >> 1] = hu;
            }
            int pos = d ? (len - 1 - t) : t;
            hc_out[((size_t)b * T + pos) * (2 * H) + d * H + j] = h;
        }
        __syncthreads();           // barrier 2: hh updated before next reads
    }

    if (kq == 0) {
        cstate[((size_t)d * B + b) * H + j] = c;
        hbufg[j] = hreg;
    }
}

// ---------------- attention logits (masked), f16 dot2, high-TLP ----------
// grid (32 tt, 128 b), block 256 = 4 waves; wave handles 4 t (was 16) ->
// 4x the active blocks, latency hidden by TLP instead of serial prefetch.
__global__ __launch_bounds__(256) void logits_kernel(const int* __restrict__ lengths,
                                                     const float* __restrict__ hc,
                                                     const uint4* __restrict__ ws1p,
                                                     const float* __restrict__ Ws2,
                                                     float* __restrict__ S) {
    __shared__ uint4 s_w1[DA * 64];    // 25600 B
    __shared__ float s_w2[HEADS * DA];
    int b = blockIdx.y, tt = blockIdx.x;
    int tid = threadIdx.x;
    for (int i = tid; i < DA * 64; i += 256) s_w1[i] = ws1p[i];
    for (int i = tid; i < HEADS * DA; i += 256) s_w2[i] = Ws2[i];
    __syncthreads();

    int len = lengths[b];
    int lane = tid & 63, wave = tid >> 6;
    int tbase = tt * 16 + wave * 4;

    if (tbase >= len) {
        if (lane < HEADS) {
            #pragma unroll
            for (int ti = 0; ti < 4; ti++)
                S[((size_t)b * HEADS + lane) * T + tbase + ti] = NEGINF;
        }
        return;
    }

    const float2* hc2 = (const float2*)hc;
    size_t rowbase = ((size_t)b * T + tbase) * 256 + lane;
    float2 f0 = hc2[rowbase];
    float2 f1 = hc2[rowbase + 64];
    float2 f2 = hc2[rowbase + 128];
    float2 f3 = hc2[rowbase + 192];

    for (int ti = 0; ti < 4; ti++) {
        int t = tbase + ti;
        int tn = tbase + ti + 1;
        if (tn >= len) tn = len - 1;
        size_t rn = ((size_t)b * T + tn) * 256 + lane;
        float2 n0 = hc2[rn];
        float2 n1 = hc2[rn + 64];
        float2 n2 = hc2[rn + 128];
        float2 n3 = hc2[rn + 192];

        if (t < len) {
            half2v h0 = packh2_(f0.x, f0.y);
            half2v h1 = packh2_(f1.x, f1.y);
            half2v h2 = packh2_(f2.x, f2.y);
            half2v h3 = packh2_(f3.x, f3.y);
            float y[DA];
            #pragma unroll
            for (int r = 0; r < DA; r++) {
                uint4 w = s_w1[r * 64 + lane];
                float v = fdot2_(w.x, h0, 0.f);
                v = fdot2_(w.y, h1, v);
                v = fdot2_(w.z, h2, v);
                v = fdot2_(w.w, h3, v);
                y[r] = v;
            }
            #pragma unroll
            for (int r = 0; r < DA; r++) {
                float v = y[r];
                for (int off = 32; off; off >>= 1) v += __shfl_xor(v, off, 64);
                y[r] = tanhf(v);
            }
            if (lane < HEADS) {
                float s = 0.f;
                #pragma unroll
                for (int r = 0; r < DA; r++) s += y[r] * s_w2[lane * DA + r];
                S[((size_t)b * HEADS + lane) * T + t] = s;
            }
        } else {
            if (lane < HEADS) S[((size_t)b * HEADS + lane) * T + t] = NEGINF;
        }
        f0 = n0; f1 = n1; f2 = n2; f3 = n3;
    }
}

// ---------------- masked softmax over T, in place ----------------
__global__ __launch_bounds__(256) void softmax_kernel(float* __restrict__ S) {
    int row = blockIdx.x;
    float* p = S + (size_t)row * T;
    int tid = threadIdx.x;
    int lane = tid & 63, wave = tid >> 6;
    __shared__ float rr[4], ss[4];

    float mx = NEGINF;
    #pragma unroll
    for (int i = 0; i < 2; i++) mx = fmaxf(mx, p[tid + i * 256]);
    for (int off = 32; off; off >>= 1) mx = fmaxf(mx, __shfl_xor(mx, off, 64));
    if (lane == 0) rr[wave] = mx;
    __syncthreads();
    mx = fmaxf(fmaxf(rr[0], rr[1]), fmaxf(rr[2], rr[3]));

    float e[2], sum = 0.f;
    #pragma unroll
    for (int i = 0; i < 2; i++) { e[i] = expf(p[tid + i * 256] - mx); sum += e[i]; }
    for (int off = 32; off; off >>= 1) sum += __shfl_xor(sum, off, 64);
    if (lane == 0) ss[wave] = sum;
    __syncthreads();
    sum = ss[0] + ss[1] + ss[2] + ss[3];
    float inv = 1.f / sum;
    #pragma unroll
    for (int i = 0; i < 2; i++) p[tid + i * 256] = e[i] * inv;
}

// ---------------- M = A @ Hc -> sentence embeddings (d_out) ----------------
__global__ __launch_bounds__(256) void attnM_kernel(const int* __restrict__ lengths,
                                                    const float* __restrict__ A,
                                                    const float* __restrict__ hc,
                                                    float* __restrict__ out) {
    int b = blockIdx.x, tid = threadIdx.x;
    int len = lengths[b];
    const float* Ab  = A + (size_t)b * HEADS * T;
    const float* hcb = hc + (size_t)b * T * (2 * H);
    float acc[HEADS][2];
    #pragma unroll
    for (int h = 0; h < HEADS; h++) { acc[h][0] = 0.f; acc[h][1] = 0.f; }
    for (int t = 0; t < len; t++) {
        float v0 = hcb[(size_t)t * (2 * H) + tid];
        float v1 = hcb[(size_t)t * (2 * H) + H + tid];
        #pragma unroll
        for (int h = 0; h < HEADS; h++) {
            float a = Ab[h * T + t];
            acc[h][0] += a * v0;
            acc[h][1] += a * v1;
        }
    }
    #pragma unroll
    for (int h = 0; h < HEADS; h++) {
        out[(size_t)b * (HEADS * 2 * H) + h * (2 * H) + tid]     = acc[h][0];
        out[(size_t)b * (HEADS * 2 * H) + h * (2 * H) + H + tid] = acc[h][1];
    }
}

// ---------------- penalization ----------------
__global__ __launch_bounds__(256) void penal_kernel(const float* __restrict__ A,
                                                    float* __restrict__ part) {
    int b = blockIdx.x, tid = threadIdx.x;
    const float* Ab = A + (size_t)b * HEADS * T;
    float p[10];
    #pragma unroll
    for (int i = 0; i < 10; i++) p[i] = 0.f;
    for (int t = tid; t < T; t += 256) {
        float a0 = Ab[t], a1 = Ab[T + t], a2 = Ab[2 * T + t], a3 = Ab[3 * T + t], a4 = Ab[4 * T + t];
        p[0] += a0 * a1; p[1] += a0 * a2; p[2] += a0 * a3; p[3] += a0 * a4;
        p[4] += a1 * a2; p[5] += a1 * a3; p[6] += a1 * a4;
        p[7] += a2 * a3; p[8] += a2 * a4; p[9] += a3 * a4;
    }
    __shared__ float red[10][4];
    int lane = tid & 63, wave = tid >> 6;
    #pragma unroll
    for (int i = 0; i < 10; i++) {
        float v = p[i];
        for (int off = 32; off; off >>= 1) v += __shfl_xor(v, off, 64);
        if (lane == 0) red[i][wave] = v;
    }
    __syncthreads();
    if (tid == 0) {
        float s = 0.f;
        #pragma unroll
        for (int i = 0; i < 10; i++) {
            float P = red[i][0] + red[i][1] + red[i][2] + red[i][3];
            s += 2.f * P * P;
        }
        part[b] = s;
    }
}

__global__ __launch_bounds__(128) void final_kernel(const float* __restrict__ part,
                                                    float* __restrict__ out) {
    int tid = threadIdx.x;
    float v = part[tid];
    for (int off = 32; off; off >>= 1) v += __shfl_xor(v, off, 64);
    __shared__ float r2[2];
    if ((tid & 63) == 0) r2[tid >> 6] = v;
    __syncthreads();
    if (tid == 0) out[(size_t)B * HEADS * 2 * H] = (r2[0] + r2[1]) * (1.f / (float)B);
}

// ---------------- host launcher ----------------
extern "C" void kernel_launch(void* const* d_in, const int* in_sizes, int n_in,
                              void* d_out, int out_size, void* d_ws, size_t ws_size,
                              hipStream_t stream) {
    const int*   word_ids = (const int*)d_in[0];
    const int*   lengths  = (const int*)d_in[1];
    const float* emb      = (const float*)d_in[2];
    const float* W_ih_f   = (const float*)d_in[3];
    const float* W_hh_f   = (const float*)d_in[4];
    const float* b_f      = (const float*)d_in[5];
    const float* W_ih_b   = (const float*)d_in[6];
    const float* W_hh_b   = (const float*)d_in[7];
    const float* b_b      = (const float*)d_in[8];
    const float* W_s1     = (const float*)d_in[9];
    const float* W_s2     = (const float*)d_in[10];
    float* out = (float*)d_out;

    char* ws = (char*)d_ws;
    unsigned short* wbt16 = (unsigned short*)(ws + WBT_OFF);
    unsigned*       wbt   = (unsigned*)(ws + WBT_OFF);
    unsigned short* wih16 = (unsigned short*)(ws + WIH_OFF);
    unsigned*       wihu  = (unsigned*)(ws + WIH_OFF);
    unsigned short* ws1p16 = (unsigned short*)(ws + WS1T_OFF);
    const uint4*    ws1p4  = (const uint4*)(ws + WS1T_OFF);
    float* pxc    = (float*)(ws + PX_OFF);
    float* hc     = (float*)(ws + HC_OFF);
    float* hbuf   = (float*)(ws + HBUF_OFF);
    float* cstate = (float*)(ws + CST_OFF);
    float* Abuf   = (float*)(ws + A_OFF);
    float* part   = (float*)(ws + PART_OFF);

    prep_kernel<<<2048, 256, 0, stream>>>(W_hh_f, W_hh_b, W_ih_f, W_ih_b, W_s1,
                                          wbt16, wih16, ws1p16);

    for (int c = 0; c < 8; c++) {
        proj_kernel<<<dim3(16, 128, 2), 256, 0, stream>>>(
            word_ids, lengths, emb, wihu, b_f, b_b, pxc, c);
        lstm6_kernel<<<dim3(128, 2), 1024, LSTM_LDS_BYTES, stream>>>(
            lengths, wbt, pxc, hc, hbuf, cstate, c);
    }

    logits_kernel<<<dim3(32, 128), 256, 0, stream>>>(lengths, hc, ws1p4, W_s2, Abuf);
    softmax_kernel<<<B * HEADS, 256, 0, stream>>>(Abuf);
    attnM_kernel<<<B, 256, 0, stream>>>(lengths, Abuf, hc, out);
    penal_kernel<<<B, 256, 0, stream>>>(Abuf, part);
    final_kernel<<<1, 128, 0, stream>>>(part, out);
}

// Round 18
// 1865.744 us; speedup vs baseline: 7.4928x; 1.2245x over previous
//
#include <hip/hip_runtime.h>
#include <math.h>

#define T 512
#define B 128
#define E 256
#define H 256
#define G 1024   // 4H
#define DA 25
#define HEADS 5
#define V 2080
#define NEGINF (-1e30f)

// ---------------- workspace layout (bytes) ----------------
static constexpr size_t WBT_OFF  = 0;           // [2][128 k2][256 j][4 gate] uint (f16 pair W_hh) 1,048,576
static constexpr size_t WIH_OFF  = 1048576;     // [2][1024 g][256 e] ushort (f16 W_ih)            1,048,576
static constexpr size_t WS1T_OFF = 2097152;     // [25 r][64 l] uint4 (f16 W_s1, lane-major)          25,600
static constexpr size_t PX_OFF   = 2148352;     // [2][64][128][1024] f32     67,108,864
static constexpr size_t HC_OFF   = 69257216;    // [128][512][512] f32       134,217,728
static constexpr size_t HBUF_OFF = 203474944;   // [2][128 b][256 j] f32         262,144
static constexpr size_t CST_OFF  = 203737088;   // [2][128][256] f32 c-state     262,144
static constexpr size_t A_OFF    = 203999232;   // [128][5][512] f32           1,310,720
static constexpr size_t PART_OFF = 205309952;   // [128] f32                         512
static constexpr size_t EMBH_OFF = 205310464;   // [2080][256] ushort (f16 emb) 1,064,960
static constexpr size_t EMBH_END = EMBH_OFF + (size_t)V * E * 2;

// ---- lstm6 dynamic LDS layout (bytes) ----
// hh     : [128] u32        @ 0      (512)
// part   : [3][257] f32x4   @ 512    (12336)
// wstage : [36][256] uint4  @ 12848  (147456)  9 k2/kq thread-private W cache
static constexpr unsigned LSTM_LDS_BYTES = 160304;

typedef _Float16 half2v __attribute__((ext_vector_type(2)));

__device__ __forceinline__ float sigmoidf_(float x) { return 1.f / (1.f + expf(-x)); }

__device__ __forceinline__ unsigned short f2h_(float f) {   // f32 -> f16 bits
    _Float16 h = (_Float16)f;
    unsigned short u;
    __builtin_memcpy(&u, &h, 2);
    return u;
}

// dot2: acc += w.lo*h.lo + w.hi*h.hi  (f32 accumulate)
__device__ __forceinline__ float fdot2_(unsigned w, half2v h, float acc) {
#if __has_builtin(__builtin_amdgcn_fdot2)
    half2v wv;
    __builtin_memcpy(&wv, &w, 4);
    return __builtin_amdgcn_fdot2(wv, h, acc, false);
#else
    unsigned short lo = (unsigned short)(w & 0xffffu), hi = (unsigned short)(w >> 16);
    _Float16 w0, w1;
    __builtin_memcpy(&w0, &lo, 2);
    __builtin_memcpy(&w1, &hi, 2);
    return fmaf((float)w0, (float)h[0], fmaf((float)w1, (float)h[1], acc));
#endif
}

__device__ __forceinline__ half2v packh2_(float a, float b) {
    half2v h;
    h[0] = (_Float16)a;
    h[1] = (_Float16)b;
    return h;
}

// ---------------- prep: pack W_hh + W_ih + W_s1 (+ emb) to f16 -------------
__global__ __launch_bounds__(256) void prep_kernel(const float* __restrict__ Whf,
                                                   const float* __restrict__ Whb,
                                                   const float* __restrict__ Wif,
                                                   const float* __restrict__ Wib,
                                                   const float* __restrict__ Ws1,
                                                   const float* __restrict__ emb,
                                                   unsigned short* __restrict__ wbt,
                                                   unsigned short* __restrict__ wih,
                                                   unsigned short* __restrict__ ws1p,
                                                   unsigned short* __restrict__ embh) {
    int idx = blockIdx.x * 256 + threadIdx.x;
    if (idx < 2 * G * H) {
        int d = idx >> 18;
        int rem = idx & 262143;
        int r = rem >> 8;                        // gate row 0..1023
        int k = rem & 255;                       // h index
        const float* W = d ? Whb : Whf;
        int gate = r >> 8, j = r & 255;
        int k2 = k >> 1, ke = k & 1;
        wbt[(((size_t)d * 128 + k2) * 256 + j) * 8 + gate * 2 + ke] = f2h_(W[(size_t)r * H + k]);
        const float* Wi = d ? Wib : Wif;
        wih[((size_t)d * G + r) * 256 + k] = f2h_(Wi[(size_t)r * E + k]);
    }
    if (idx < DA * 512) {
        int r = idx / 512, k = idx % 512;
        int kp = k >> 1, ke = k & 1;
        int l = kp & 63, q = kp >> 6;
        ws1p[((r * 64 + l) * 4 + q) * 2 + ke] = f2h_(Ws1[idx]);
    }
    if (embh && idx < V * E) embh[idx] = f2h_(emb[idx]);
}

// ---------------- input projection, f16 dot2, one 64-step chunk ----------
__global__ __launch_bounds__(256) void proj_kernel(const int* __restrict__ word_ids,
                                                   const int* __restrict__ lengths,
                                                   const float* __restrict__ emb,
                                                   const unsigned* __restrict__ embh,
                                                   const unsigned* __restrict__ wih,
                                                   const float* __restrict__ bf,
                                                   const float* __restrict__ bb,
                                                   float* __restrict__ pxc, int chunk) {
    int g0 = blockIdx.x * 64;
    int b  = blockIdx.y;
    int d  = blockIdx.z;
    int len = lengths[b];
    int t0 = chunk * 64;
    if (t0 >= len) return;
    const float* bias = d ? bb : bf;

    __shared__ int      wid[64];
    __shared__ unsigned As2[64][17];   // [m][kp] emb as f16 pairs
    __shared__ unsigned Bs2[64][17];   // [m][kp] W_ih as f16 pairs

    int tid = threadIdx.x;
    if (tid < 64) {
        int t = t0 + tid;
        int src;
        if (d == 0) src = t;
        else { src = len - 1 - t; if (src < 0) src = 0; }
        wid[tid] = word_ids[b * T + src];
    }
    __syncthreads();

    int tx = tid & 15, ty = tid >> 4;
    int lk = tid & 15, lm = tid >> 4;
    const unsigned* wihd = wih + ((size_t)d * G + g0) * 128;

    float acc[4][4];
    #pragma unroll
    for (int i = 0; i < 4; i++)
        #pragma unroll
        for (int j = 0; j < 4; j++) acc[i][j] = 0.f;

    for (int k0 = 0; k0 < E; k0 += 32) {
        int e2 = k0 >> 1;
        #pragma unroll
        for (int i = 0; i < 4; i++) {
            int m = lm + 16 * i;
            if (embh) {
                As2[m][lk] = embh[(size_t)wid[m] * 128 + e2 + lk];
            } else {
                const float* ep = emb + (size_t)wid[m] * E + k0 + 2 * lk;
                half2v av = packh2_(ep[0], ep[1]);
                unsigned au;
                __builtin_memcpy(&au, &av, 4);
                As2[m][lk] = au;
            }
            Bs2[m][lk] = wihd[(size_t)m * 128 + e2 + lk];
        }
        __syncthreads();
        #pragma unroll
        for (int kp = 0; kp < 16; kp++) {
            unsigned a2[4], b2[4];
            #pragma unroll
            for (int i = 0; i < 4; i++) a2[i] = As2[ty * 4 + i][kp];
            #pragma unroll
            for (int j = 0; j < 4; j++) b2[j] = Bs2[tx * 4 + j][kp];
            #pragma unroll
            for (int i = 0; i < 4; i++) {
                half2v ah;
                __builtin_memcpy(&ah, &a2[i], 4);
                #pragma unroll
                for (int j = 0; j < 4; j++)
                    acc[i][j] = fdot2_(b2[j], ah, acc[i][j]);
            }
        }
        __syncthreads();
    }
    #pragma unroll
    for (int i = 0; i < 4; i++) {
        int m = ty * 4 + i;
        #pragma unroll
        for (int j = 0; j < 4; j++) {
            int n = tx * 4 + j;
            pxc[((size_t)(d * 64 + m) * B + b) * G + g0 + n] = acc[i][j] + bias[g0 + n];
        }
    }
}

// ---------------- LSTM recurrence: residency-split W ----------------
// grid (128 b, 2 dir); block 1024 = 16 waves.
// Thread (j = tid&255, kq = tid>>8) owns 32 k2 of hidden col j:
//   k2 0..8  : staged in LDS once per chunk (147 KB/block)
//   k2 9..23 : 15 NAMED uint4 registers (60 VGPR raw; measured 12res=48 total,
//              so 15res est ~57-61 < 64 cap -- FETCH_SIZE is the spill tripwire)
//   k2 24..31: streamed from L2 -> 128 KB/step (was 176)
__global__ __launch_bounds__(1024) void lstm6_kernel(const int* __restrict__ lengths,
                                                     const unsigned* __restrict__ wbt,
                                                     const float* __restrict__ pxc,
                                                     float* __restrict__ hc_out,
                                                     float* __restrict__ hbuf,
                                                     float* __restrict__ cstate,
                                                     int chunk) {
    int b   = blockIdx.x;
    int d   = blockIdx.y;
    int tid = threadIdx.x;
    int j  = tid & 255;
    int kq = tid >> 8;                 // 0..3 (wave-uniform)

    int len = lengths[b];
    int t0 = chunk * 64;
    if (t0 >= len) return;
    int tend = min(t0 + 64, len);

    extern __shared__ char smem[];
    unsigned* hh   = (unsigned*)smem;                // [128]
    float4*   part = (float4*)(smem + 512);          // [3][257]
    uint4*    wst  = (uint4*)(smem + 12848);         // [36][256]

    float* hbufg = hbuf + ((size_t)d * B + b) * 256;

    float c = 0.f, hreg = 0.f;
    if (chunk == 0) {
        if (tid < 128) hh[tid] = 0u;
    } else {
        if (kq == 0) c = cstate[((size_t)d * B + b) * H + j];
        if (tid < 128) {
            half2v hv2 = packh2_(hbufg[2 * tid], hbufg[2 * tid + 1]);
            unsigned hu;
            __builtin_memcpy(&hu, &hv2, 4);
            hh[tid] = hu;
        }
    }

    // thread's W rows: k2 in [kq*32, kq*32+32), column j
    const uint4* wp  = (const uint4*)wbt + ((size_t)d * 128 + kq * 32) * 256 + j;
    const float* pxd = pxc + (size_t)d * 64 * B * G;

    // stage k2 0..8 into LDS (thread-private; written+read by same thread)
    #pragma unroll
    for (int r = 0; r < 9; r++)
        wst[(kq * 9 + r) * 256 + j] = wp[(size_t)r * 256];
    // resident k2 9..23 in named registers (15 x uint4 = 60 VGPR raw)
    uint4 wr0  = wp[9 * 256],  wr1  = wp[10 * 256], wr2  = wp[11 * 256];
    uint4 wr3  = wp[12 * 256], wr4  = wp[13 * 256], wr5  = wp[14 * 256];
    uint4 wr6  = wp[15 * 256], wr7  = wp[16 * 256], wr8  = wp[17 * 256];
    uint4 wr9  = wp[18 * 256], wr10 = wp[19 * 256], wr11 = wp[20 * 256];
    uint4 wr12 = wp[21 * 256], wr13 = wp[22 * 256], wr14 = wp[23 * 256];
    __syncthreads();

    for (int t = t0; t < tend; t++) {
        int s = t - t0;
        float p0, p1, p2, p3;
        if (kq == 0) {
            const float* pxs = pxd + ((size_t)s * B + b) * G;
            p0 = pxs[j];
            p1 = pxs[256 + j];
            p2 = pxs[512 + j];
            p3 = pxs[768 + j];
        }
        float a0 = 0.f, a1 = 0.f, a2 = 0.f, a3 = 0.f;

        const unsigned* hhc = hh + kq * 32;

        // streamed k2 24..31 first (loads issue early)
        #pragma unroll
        for (int r = 24; r < 32; r++) {
            uint4 wv = wp[(size_t)r * 256];
            unsigned hu = hhc[r];              // wave-uniform -> broadcast
            half2v hhv;
            __builtin_memcpy(&hhv, &hu, 4);
            a0 = fdot2_(wv.x, hhv, a0);
            a1 = fdot2_(wv.y, hhv, a1);
            a2 = fdot2_(wv.z, hhv, a2);
            a3 = fdot2_(wv.w, hhv, a3);
        }
        // LDS-cached k2 0..8
        #pragma unroll
        for (int r = 0; r < 9; r++) {
            uint4 wv = wst[(kq * 9 + r) * 256 + j];
            unsigned hu = hhc[r];
            half2v hhv;
            __builtin_memcpy(&hhv, &hu, 4);
            a0 = fdot2_(wv.x, hhv, a0);
            a1 = fdot2_(wv.y, hhv, a1);
            a2 = fdot2_(wv.z, hhv, a2);
            a3 = fdot2_(wv.w, hhv, a3);
        }
        // register-resident k2 9..23
        {
            unsigned hu;
            half2v hv;
            #define RES_DOT(WR, IDX)                                   \
                hu = hhc[IDX];                                         \
                __builtin_memcpy(&hv, &hu, 4);                         \
                a0 = fdot2_(WR.x, hv, a0); a1 = fdot2_(WR.y, hv, a1);  \
                a2 = fdot2_(WR.z, hv, a2); a3 = fdot2_(WR.w, hv, a3);
            RES_DOT(wr0, 9)
            RES_DOT(wr1, 10)
            RES_DOT(wr2, 11)
            RES_DOT(wr3, 12)
            RES_DOT(wr4, 13)
            RES_DOT(wr5, 14)
            RES_DOT(wr6, 15)
            RES_DOT(wr7, 16)
            RES_DOT(wr8, 17)
            RES_DOT(wr9, 18)
            RES_DOT(wr10, 19)
            RES_DOT(wr11, 20)
            RES_DOT(wr12, 21)
            RES_DOT(wr13, 22)
            RES_DOT(wr14, 23)
            #undef RES_DOT
        }

        if (kq > 0) part[(kq - 1) * 257 + j] = make_float4(a0, a1, a2, a3);
        __syncthreads();           // barrier 1: partials ready; hh reads done

        if (kq == 0) {
            #pragma unroll
            for (int q = 0; q < 3; q++) {
                float4 qv = part[q * 257 + j];
                a0 += qv.x; a1 += qv.y; a2 += qv.z; a3 += qv.w;
            }
            a0 += p0; a1 += p1; a2 += p2; a3 += p3;

            float ig = sigmoidf_(a0), fg = sigmoidf_(a1), og = sigmoidf_(a3);
            c = fg * c + ig * tanhf(a2);
            float h = og * tanhf(c);
            hreg = h;

            float hn = __shfl_down(h, 1);
            if (!(j & 1)) {
                half2v hv2 = packh2_(h, hn);
                unsigned hu;
                __builtin_memcpy(&hu, &hv2, 4);
                hh[j >> 1] = hu;
            }
            int pos = d ? (len - 1 - t) : t;
            hc_out[((size_t)b * T + pos) * (2 * H) + d * H + j] = h;
        }
        __syncthreads();           // barrier 2: hh updated before next reads
    }

    if (kq == 0) {
        cstate[((size_t)d * B + b) * H + j] = c;
        hbufg[j] = hreg;
    }
}

// ---------------- attention logits (masked), f16 dot2, high-TLP ----------
__global__ __launch_bounds__(256) void logits_kernel(const int* __restrict__ lengths,
                                                     const float* __restrict__ hc,
                                                     const uint4* __restrict__ ws1p,
                                                     const float* __restrict__ Ws2,
                                                     float* __restrict__ S) {
    __shared__ uint4 s_w1[DA * 64];    // 25600 B
    __shared__ float s_w2[HEADS * DA];
    int b = blockIdx.y, tt = blockIdx.x;
    int tid = threadIdx.x;
    for (int i = tid; i < DA * 64; i += 256) s_w1[i] = ws1p[i];
    for (int i = tid; i < HEADS * DA; i += 256) s_w2[i] = Ws2[i];
    __syncthreads();

    int len = lengths[b];
    int lane = tid & 63, wave = tid >> 6;
    int tbase = tt * 16 + wave * 4;

    if (tbase >= len) {
        if (lane < HEADS) {
            #pragma unroll
            for (int ti = 0; ti < 4; ti++)
                S[((size_t)b * HEADS + lane) * T + tbase + ti] = NEGINF;
        }
        return;
    }

    const float2* hc2 = (const float2*)hc;
    size_t rowbase = ((size_t)b * T + tbase) * 256 + lane;
    float2 f0 = hc2[rowbase];
    float2 f1 = hc2[rowbase + 64];
    float2 f2 = hc2[rowbase + 128];
    float2 f3 = hc2[rowbase + 192];

    for (int ti = 0; ti < 4; ti++) {
        int t = tbase + ti;
        int tn = tbase + ti + 1;
        if (tn >= len) tn = len - 1;
        size_t rn = ((size_t)b * T + tn) * 256 + lane;
        float2 n0 = hc2[rn];
        float2 n1 = hc2[rn + 64];
        float2 n2 = hc2[rn + 128];
        float2 n3 = hc2[rn + 192];

        if (t < len) {
            half2v h0 = packh2_(f0.x, f0.y);
            half2v h1 = packh2_(f1.x, f1.y);
            half2v h2 = packh2_(f2.x, f2.y);
            half2v h3 = packh2_(f3.x, f3.y);
            float y[DA];
            #pragma unroll
            for (int r = 0; r < DA; r++) {
                uint4 w = s_w1[r * 64 + lane];
                float v = fdot2_(w.x, h0, 0.f);
                v = fdot2_(w.y, h1, v);
                v = fdot2_(w.z, h2, v);
                v = fdot2_(w.w, h3, v);
                y[r] = v;
            }
            #pragma unroll
            for (int r = 0; r < DA; r++) {
                float v = y[r];
                for (int off = 32; off; off >>= 1) v += __shfl_xor(v, off, 64);
                y[r] = tanhf(v);
            }
            if (lane < HEADS) {
                float s = 0.f;
                #pragma unroll
                for (int r = 0; r < DA; r++) s += y[r] * s_w2[lane * DA + r];
                S[((size_t)b * HEADS + lane) * T + t] = s;
            }
        } else {
            if (lane < HEADS) S[((size_t)b * HEADS + lane) * T + t] = NEGINF;
        }
        f0 = n0; f1 = n1; f2 = n2; f3 = n3;
    }
}

// ---------------- masked softmax over T, in place ----------------
__global__ __launch_bounds__(256) void softmax_kernel(float* __restrict__ S) {
    int row = blockIdx.x;
    float* p = S + (size_t)row * T;
    int tid = threadIdx.x;
    int lane = tid & 63, wave = tid >> 6;
    __shared__ float rr[4], ss[4];

    float mx = NEGINF;
    #pragma unroll
    for (int i = 0; i < 2; i++) mx = fmaxf(mx, p[tid + i * 256]);
    for (int off = 32; off; off >>= 1) mx = fmaxf(mx, __shfl_xor(mx, off, 64));
    if (lane == 0) rr[wave] = mx;
    __syncthreads();
    mx = fmaxf(fmaxf(rr[0], rr[1]), fmaxf(rr[2], rr[3]));

    float e[2], sum = 0.f;
    #pragma unroll
    for (int i = 0; i < 2; i++) { e[i] = expf(p[tid + i * 256] - mx); sum += e[i]; }
    for (int off = 32; off; off >>= 1) sum += __shfl_xor(sum, off, 64);
    if (lane == 0) ss[wave] = sum;
    __syncthreads();
    sum = ss[0] + ss[1] + ss[2] + ss[3];
    float inv = 1.f / sum;
    #pragma unroll
    for (int i = 0; i < 2; i++) p[tid + i * 256] = e[i] * inv;
}

// ---------------- M = A @ Hc -> d_out, fused penal partials ----------------
__global__ __launch_bounds__(256) void attnM_kernel(const int* __restrict__ lengths,
                                                    const float* __restrict__ A,
                                                    const float* __restrict__ hc,
                                                    float* __restrict__ out,
                                                    float* __restrict__ part) {
    int b = blockIdx.x, tid = threadIdx.x;
    int len = lengths[b];
    const float* Ab  = A + (size_t)b * HEADS * T;
    const float* hcb = hc + (size_t)b * T * (2 * H);
    float acc[HEADS][2];
    #pragma unroll
    for (int h = 0; h < HEADS; h++) { acc[h][0] = 0.f; acc[h][1] = 0.f; }
    float p[10];
    #pragma unroll
    for (int i = 0; i < 10; i++) p[i] = 0.f;

    for (int t = 0; t < len; t++) {
        float v0 = hcb[(size_t)t * (2 * H) + tid];
        float v1 = hcb[(size_t)t * (2 * H) + H + tid];
        float a0 = Ab[t], a1 = Ab[T + t], a2 = Ab[2 * T + t], a3 = Ab[3 * T + t], a4 = Ab[4 * T + t];
        acc[0][0] += a0 * v0; acc[0][1] += a0 * v1;
        acc[1][0] += a1 * v0; acc[1][1] += a1 * v1;
        acc[2][0] += a2 * v0; acc[2][1] += a2 * v1;
        acc[3][0] += a3 * v0; acc[3][1] += a3 * v1;
        acc[4][0] += a4 * v0; acc[4][1] += a4 * v1;
        // penal partials on same 5 loads (A exact-zero outside len, t>=len adds 0)
        if ((tid & 255) < 64) {   // only wave 0 lanes would double-count: use strided split below instead
        }
        // strided ownership: thread tid accumulates t where (t % 256) == tid? No --
        // every thread loads every t here; to avoid 256x duplication, only
        // accumulate penal when this thread owns t:
        if ((t & 255) == tid) {
            p[0] += a0 * a1; p[1] += a0 * a2; p[2] += a0 * a3; p[3] += a0 * a4;
            p[4] += a1 * a2; p[5] += a1 * a3; p[6] += a1 * a4;
            p[7] += a2 * a3; p[8] += a2 * a4; p[9] += a3 * a4;
        }
    }
    #pragma unroll
    for (int h = 0; h < HEADS; h++) {
        out[(size_t)b * (HEADS * 2 * H) + h * (2 * H) + tid]     = acc[h][0];
        out[(size_t)b * (HEADS * 2 * H) + h * (2 * H) + H + tid] = acc[h][1];
    }

    __shared__ float red[10][4];
    int lane = tid & 63, wave = tid >> 6;
    #pragma unroll
    for (int i = 0; i < 10; i++) {
        float v = p[i];
        for (int off = 32; off; off >>= 1) v += __shfl_xor(v, off, 64);
        if (lane == 0) red[i][wave] = v;
    }
    __syncthreads();
    if (tid == 0) {
        float s = 0.f;
        #pragma unroll
        for (int i = 0; i < 10; i++) {
            float P = red[i][0] + red[i][1] + red[i][2] + red[i][3];
            s += 2.f * P * P;
        }
        part[b] = s;
    }
}

__global__ __launch_bounds__(128) void final_kernel(const float* __restrict__ part,
                                                    float* __restrict__ out) {
    int tid = threadIdx.x;
    float v = part[tid];
    for (int off = 32; off; off >>= 1) v += __shfl_xor(v, off, 64);
    __shared__ float r2[2];
    if ((tid & 63) == 0) r2[tid >> 6] = v;
    __syncthreads();
    if (tid == 0) out[(size_t)B * HEADS * 2 * H] = (r2[0] + r2[1]) * (1.f / (float)B);
}

// ---------------- host launcher ----------------
extern "C" void kernel_launch(void* const* d_in, const int* in_sizes, int n_in,
                              void* d_out, int out_size, void* d_ws, size_t ws_size,
                              hipStream_t stream) {
    const int*   word_ids = (const int*)d_in[0];
    const int*   lengths  = (const int*)d_in[1];
    const float* emb      = (const float*)d_in[2];
    const float* W_ih_f   = (const float*)d_in[3];
    const float* W_hh_f   = (const float*)d_in[4];
    const float* b_f      = (const float*)d_in[5];
    const float* W_ih_b   = (const float*)d_in[6];
    const float* W_hh_b   = (const float*)d_in[7];
    const float* b_b      = (const float*)d_in[8];
    const float* W_s1     = (const float*)d_in[9];
    const float* W_s2     = (const float*)d_in[10];
    float* out = (float*)d_out;

    char* ws = (char*)d_ws;
    unsigned short* wbt16 = (unsigned short*)(ws + WBT_OFF);
    unsigned*       wbt   = (unsigned*)(ws + WBT_OFF);
    unsigned short* wih16 = (unsigned short*)(ws + WIH_OFF);
    unsigned*       wihu  = (unsigned*)(ws + WIH_OFF);
    unsigned short* ws1p16 = (unsigned short*)(ws + WS1T_OFF);
    const uint4*    ws1p4  = (const uint4*)(ws + WS1T_OFF);
    float* pxc    = (float*)(ws + PX_OFF);
    float* hc     = (float*)(ws + HC_OFF);
    float* hbuf   = (float*)(ws + HBUF_OFF);
    float* cstate = (float*)(ws + CST_OFF);
    float* Abuf   = (float*)(ws + A_OFF);
    float* part   = (float*)(ws + PART_OFF);
    bool have_embh = (ws_size >= EMBH_END);
    unsigned short* embh16 = have_embh ? (unsigned short*)(ws + EMBH_OFF) : nullptr;
    const unsigned* embhu  = have_embh ? (const unsigned*)(ws + EMBH_OFF) : nullptr;

    prep_kernel<<<2080, 256, 0, stream>>>(W_hh_f, W_hh_b, W_ih_f, W_ih_b, W_s1, emb,
                                          wbt16, wih16, ws1p16, embh16);

    for (int c = 0; c < 8; c++) {
        proj_kernel<<<dim3(16, 128, 2), 256, 0, stream>>>(
            word_ids, lengths, emb, embhu, wihu, b_f, b_b, pxc, c);
        lstm6_kernel<<<dim3(128, 2), 1024, LSTM_LDS_BYTES, stream>>>(
            lengths, wbt, pxc, hc, hbuf, cstate, c);
    }

    logits_kernel<<<dim3(32, 128), 256, 0, stream>>>(lengths, hc, ws1p4, W_s2, Abuf);
    softmax_kernel<<<B * HEADS, 256, 0, stream>>>(Abuf);
    attnM_kernel<<<B, 256, 0, stream>>>(lengths, Abuf, hc, out, part);
    final_kernel<<<1, 128, 0, stream>>>(part, out);
}

// Round 19
// 1836.761 us; speedup vs baseline: 7.6110x; 1.0158x over previous
//
#include <hip/hip_runtime.h>
#include <math.h>

#define T 512
#define B 128
#define E 256
#define H 256
#define G 1024   // 4H
#define DA 25
#define HEADS 5
#define V 2080
#define NEGINF (-1e30f)

// ---------------- workspace layout (bytes) ----------------
static constexpr size_t WBT_OFF  = 0;           // [2][128 k2][256 j][4 gate] uint (f16 pair W_hh) 1,048,576
static constexpr size_t WIH_OFF  = 1048576;     // [2][1024 g][256 e] ushort (f16 W_ih)            1,048,576
static constexpr size_t WS1T_OFF = 2097152;     // [25 r][64 l] uint4 (f16 W_s1, lane-major)          25,600
static constexpr size_t PX_OFF   = 2148352;     // [2][64][128][1024] f32     67,108,864
static constexpr size_t HC_OFF   = 69257216;    // [128][512][512] f32       134,217,728
static constexpr size_t HBUF_OFF = 203474944;   // [2][128 b][256 j] f32         262,144
static constexpr size_t CST_OFF  = 203737088;   // [2][128][256] f32 c-state     262,144
static constexpr size_t A_OFF    = 203999232;   // [128][5][512] f32           1,310,720
static constexpr size_t PART_OFF = 205309952;   // [128] f32                         512
static constexpr size_t EMBH_OFF = 205310464;   // [2080][256] ushort (f16 emb) 1,064,960
static constexpr size_t EMBH_END = EMBH_OFF + (size_t)V * E * 2;

// ---- lstm6 dynamic LDS layout (bytes) ----
static constexpr unsigned LSTM_LDS_BYTES = 160304;

typedef _Float16 half2v __attribute__((ext_vector_type(2)));

__device__ __forceinline__ float sigmoidf_(float x) { return 1.f / (1.f + expf(-x)); }

__device__ __forceinline__ unsigned short f2h_(float f) {   // f32 -> f16 bits
    _Float16 h = (_Float16)f;
    unsigned short u;
    __builtin_memcpy(&u, &h, 2);
    return u;
}

// dot2: acc += w.lo*h.lo + w.hi*h.hi  (f32 accumulate)
__device__ __forceinline__ float fdot2_(unsigned w, half2v h, float acc) {
#if __has_builtin(__builtin_amdgcn_fdot2)
    half2v wv;
    __builtin_memcpy(&wv, &w, 4);
    return __builtin_amdgcn_fdot2(wv, h, acc, false);
#else
    unsigned short lo = (unsigned short)(w & 0xffffu), hi = (unsigned short)(w >> 16);
    _Float16 w0, w1;
    __builtin_memcpy(&w0, &lo, 2);
    __builtin_memcpy(&w1, &hi, 2);
    return fmaf((float)w0, (float)h[0], fmaf((float)w1, (float)h[1], acc));
#endif
}

__device__ __forceinline__ half2v packh2_(float a, float b) {
    half2v h;
    h[0] = (_Float16)a;
    h[1] = (_Float16)b;
    return h;
}

// ---------------- prep: pack W_hh + W_ih + W_s1 (+ emb) to f16 -------------
__global__ __launch_bounds__(256) void prep_kernel(const float* __restrict__ Whf,
                                                   const float* __restrict__ Whb,
                                                   const float* __restrict__ Wif,
                                                   const float* __restrict__ Wib,
                                                   const float* __restrict__ Ws1,
                                                   const float* __restrict__ emb,
                                                   unsigned short* __restrict__ wbt,
                                                   unsigned short* __restrict__ wih,
                                                   unsigned short* __restrict__ ws1p,
                                                   unsigned short* __restrict__ embh) {
    int idx = blockIdx.x * 256 + threadIdx.x;
    if (idx < 2 * G * H) {
        int d = idx >> 18;
        int rem = idx & 262143;
        int r = rem >> 8;                        // gate row 0..1023
        int k = rem & 255;                       // h index
        const float* W = d ? Whb : Whf;
        int gate = r >> 8, j = r & 255;
        int k2 = k >> 1, ke = k & 1;
        wbt[(((size_t)d * 128 + k2) * 256 + j) * 8 + gate * 2 + ke] = f2h_(W[(size_t)r * H + k]);
        const float* Wi = d ? Wib : Wif;
        wih[((size_t)d * G + r) * 256 + k] = f2h_(Wi[(size_t)r * E + k]);
    }
    if (idx < DA * 512) {
        int r = idx / 512, k = idx % 512;
        int kp = k >> 1, ke = k & 1;
        int l = kp & 63, q = kp >> 6;
        ws1p[((r * 64 + l) * 4 + q) * 2 + ke] = f2h_(Ws1[idx]);
    }
    if (embh && idx < V * E) embh[idx] = f2h_(emb[idx]);
}

// ---------------- input projection, f16 dot2, one 64-step chunk ----------
__global__ __launch_bounds__(256) void proj_kernel(const int* __restrict__ word_ids,
                                                   const int* __restrict__ lengths,
                                                   const float* __restrict__ emb,
                                                   const unsigned* __restrict__ embh,
                                                   const unsigned* __restrict__ wih,
                                                   const float* __restrict__ bf,
                                                   const float* __restrict__ bb,
                                                   float* __restrict__ pxc, int chunk) {
    int g0 = blockIdx.x * 64;
    int b  = blockIdx.y;
    int d  = blockIdx.z;
    int len = lengths[b];
    int t0 = chunk * 64;
    if (t0 >= len) return;
    const float* bias = d ? bb : bf;

    __shared__ int      wid[64];
    __shared__ unsigned As2[64][17];   // [m][kp] emb as f16 pairs
    __shared__ unsigned Bs2[64][17];   // [m][kp] W_ih as f16 pairs

    int tid = threadIdx.x;
    if (tid < 64) {
        int t = t0 + tid;
        int src;
        if (d == 0) src = t;
        else { src = len - 1 - t; if (src < 0) src = 0; }
        wid[tid] = word_ids[b * T + src];
    }
    __syncthreads();

    int tx = tid & 15, ty = tid >> 4;
    int lk = tid & 15, lm = tid >> 4;
    const unsigned* wihd = wih + ((size_t)d * G + g0) * 128;

    float acc[4][4];
    #pragma unroll
    for (int i = 0; i < 4; i++)
        #pragma unroll
        for (int j = 0; j < 4; j++) acc[i][j] = 0.f;

    for (int k0 = 0; k0 < E; k0 += 32) {
        int e2 = k0 >> 1;
        #pragma unroll
        for (int i = 0; i < 4; i++) {
            int m = lm + 16 * i;
            if (embh) {
                As2[m][lk] = embh[(size_t)wid[m] * 128 + e2 + lk];
            } else {
                const float* ep = emb + (size_t)wid[m] * E + k0 + 2 * lk;
                half2v av = packh2_(ep[0], ep[1]);
                unsigned au;
                __builtin_memcpy(&au, &av, 4);
                As2[m][lk] = au;
            }
            Bs2[m][lk] = wihd[(size_t)m * 128 + e2 + lk];
        }
        __syncthreads();
        #pragma unroll
        for (int kp = 0; kp < 16; kp++) {
            unsigned a2[4], b2[4];
            #pragma unroll
            for (int i = 0; i < 4; i++) a2[i] = As2[ty * 4 + i][kp];
            #pragma unroll
            for (int j = 0; j < 4; j++) b2[j] = Bs2[tx * 4 + j][kp];
            #pragma unroll
            for (int i = 0; i < 4; i++) {
                half2v ah;
                __builtin_memcpy(&ah, &a2[i], 4);
                #pragma unroll
                for (int j = 0; j < 4; j++)
                    acc[i][j] = fdot2_(b2[j], ah, acc[i][j]);
            }
        }
        __syncthreads();
    }
    #pragma unroll
    for (int i = 0; i < 4; i++) {
        int m = ty * 4 + i;
        #pragma unroll
        for (int j = 0; j < 4; j++) {
            int n = tx * 4 + j;
            pxc[((size_t)(d * 64 + m) * B + b) * G + g0 + n] = acc[i][j] + bias[g0 + n];
        }
    }
}

// ---------------- LSTM recurrence: residency-split W ----------------
// grid (128 b, 2 dir); block 1024 = 16 waves. (unchanged from round 18)
__global__ __launch_bounds__(1024) void lstm6_kernel(const int* __restrict__ lengths,
                                                     const unsigned* __restrict__ wbt,
                                                     const float* __restrict__ pxc,
                                                     float* __restrict__ hc_out,
                                                     float* __restrict__ hbuf,
                                                     float* __restrict__ cstate,
                                                     int chunk) {
    int b   = blockIdx.x;
    int d   = blockIdx.y;
    int tid = threadIdx.x;
    int j  = tid & 255;
    int kq = tid >> 8;                 // 0..3 (wave-uniform)

    int len = lengths[b];
    int t0 = chunk * 64;
    if (t0 >= len) return;
    int tend = min(t0 + 64, len);

    extern __shared__ char smem[];
    unsigned* hh   = (unsigned*)smem;                // [128]
    float4*   part = (float4*)(smem + 512);          // [3][257]
    uint4*    wst  = (uint4*)(smem + 12848);         // [36][256]

    float* hbufg = hbuf + ((size_t)d * B + b) * 256;

    float c = 0.f, hreg = 0.f;
    if (chunk == 0) {
        if (tid < 128) hh[tid] = 0u;
    } else {
        if (kq == 0) c = cstate[((size_t)d * B + b) * H + j];
        if (tid < 128) {
            half2v hv2 = packh2_(hbufg[2 * tid], hbufg[2 * tid + 1]);
            unsigned hu;
            __builtin_memcpy(&hu, &hv2, 4);
            hh[tid] = hu;
        }
    }

    // thread's W rows: k2 in [kq*32, kq*32+32), column j
    const uint4* wp  = (const uint4*)wbt + ((size_t)d * 128 + kq * 32) * 256 + j;
    const float* pxd = pxc + (size_t)d * 64 * B * G;

    // stage k2 0..8 into LDS (thread-private; written+read by same thread)
    #pragma unroll
    for (int r = 0; r < 9; r++)
        wst[(kq * 9 + r) * 256 + j] = wp[(size_t)r * 256];
    // resident k2 9..23 in named registers (15 x uint4 = 60 VGPR raw)
    uint4 wr0  = wp[9 * 256],  wr1  = wp[10 * 256], wr2  = wp[11 * 256];
    uint4 wr3  = wp[12 * 256], wr4  = wp[13 * 256], wr5  = wp[14 * 256];
    uint4 wr6  = wp[15 * 256], wr7  = wp[16 * 256], wr8  = wp[17 * 256];
    uint4 wr9  = wp[18 * 256], wr10 = wp[19 * 256], wr11 = wp[20 * 256];
    uint4 wr12 = wp[21 * 256], wr13 = wp[22 * 256], wr14 = wp[23 * 256];
    __syncthreads();

    for (int t = t0; t < tend; t++) {
        int s = t - t0;
        float p0, p1, p2, p3;
        if (kq == 0) {
            const float* pxs = pxd + ((size_t)s * B + b) * G;
            p0 = pxs[j];
            p1 = pxs[256 + j];
            p2 = pxs[512 + j];
            p3 = pxs[768 + j];
        }
        float a0 = 0.f, a1 = 0.f, a2 = 0.f, a3 = 0.f;

        const unsigned* hhc = hh + kq * 32;

        // streamed k2 24..31 first (loads issue early)
        #pragma unroll
        for (int r = 24; r < 32; r++) {
            uint4 wv = wp[(size_t)r * 256];
            unsigned hu = hhc[r];              // wave-uniform -> broadcast
            half2v hhv;
            __builtin_memcpy(&hhv, &hu, 4);
            a0 = fdot2_(wv.x, hhv, a0);
            a1 = fdot2_(wv.y, hhv, a1);
            a2 = fdot2_(wv.z, hhv, a2);
            a3 = fdot2_(wv.w, hhv, a3);
        }
        // LDS-cached k2 0..8
        #pragma unroll
        for (int r = 0; r < 9; r++) {
            uint4 wv = wst[(kq * 9 + r) * 256 + j];
            unsigned hu = hhc[r];
            half2v hhv;
            __builtin_memcpy(&hhv, &hu, 4);
            a0 = fdot2_(wv.x, hhv, a0);
            a1 = fdot2_(wv.y, hhv, a1);
            a2 = fdot2_(wv.z, hhv, a2);
            a3 = fdot2_(wv.w, hhv, a3);
        }
        // register-resident k2 9..23
        {
            unsigned hu;
            half2v hv;
            #define RES_DOT(WR, IDX)                                   \
                hu = hhc[IDX];                                         \
                __builtin_memcpy(&hv, &hu, 4);                         \
                a0 = fdot2_(WR.x, hv, a0); a1 = fdot2_(WR.y, hv, a1);  \
                a2 = fdot2_(WR.z, hv, a2); a3 = fdot2_(WR.w, hv, a3);
            RES_DOT(wr0, 9)
            RES_DOT(wr1, 10)
            RES_DOT(wr2, 11)
            RES_DOT(wr3, 12)
            RES_DOT(wr4, 13)
            RES_DOT(wr5, 14)
            RES_DOT(wr6, 15)
            RES_DOT(wr7, 16)
            RES_DOT(wr8, 17)
            RES_DOT(wr9, 18)
            RES_DOT(wr10, 19)
            RES_DOT(wr11, 20)
            RES_DOT(wr12, 21)
            RES_DOT(wr13, 22)
            RES_DOT(wr14, 23)
            #undef RES_DOT
        }

        if (kq > 0) part[(kq - 1) * 257 + j] = make_float4(a0, a1, a2, a3);
        __syncthreads();           // barrier 1: partials ready; hh reads done

        if (kq == 0) {
            #pragma unroll
            for (int q = 0; q < 3; q++) {
                float4 qv = part[q * 257 + j];
                a0 += qv.x; a1 += qv.y; a2 += qv.z; a3 += qv.w;
            }
            a0 += p0; a1 += p1; a2 += p2; a3 += p3;

            float ig = sigmoidf_(a0), fg = sigmoidf_(a1), og = sigmoidf_(a3);
            c = fg * c + ig * tanhf(a2);
            float h = og * tanhf(c);
            hreg = h;

            float hn = __shfl_down(h, 1);
            if (!(j & 1)) {
                half2v hv2 = packh2_(h, hn);
                unsigned hu;
                __builtin_memcpy(&hu, &hv2, 4);
                hh[j >> 1] = hu;
            }
            int pos = d ? (len - 1 - t) : t;
            hc_out[((size_t)b * T + pos) * (2 * H) + d * H + j] = h;
        }
        __syncthreads();           // barrier 2: hh updated before next reads
    }

    if (kq == 0) {
        cstate[((size_t)d * B + b) * H + j] = c;
        hbufg[j] = hreg;
    }
}

// ---------------- attention logits (masked), f16 dot2, 16-wave blocks ----
// grid (8 tt, 128 b), block 1024 = 16 waves; each block stages W_s1 ONCE for
// 64 t of work (r17's 4096x256 grid staged 25.6 KB per 16 t -> 105 MB traffic
// and ~5 waves/CU). 1024 blocks x 16 waves = 2 blocks/CU = 32 waves/CU (full).
// No software prefetch (launch_bounds(1024) caps VGPR at 64; TLP hides latency).
__global__ __launch_bounds__(1024) void logits_kernel(const int* __restrict__ lengths,
                                                      const float* __restrict__ hc,
                                                      const uint4* __restrict__ ws1p,
                                                      const float* __restrict__ Ws2,
                                                      float* __restrict__ S) {
    __shared__ uint4 s_w1[DA * 64];    // 25600 B
    __shared__ float s_w2[HEADS * DA];
    int b = blockIdx.y, tt = blockIdx.x;
    int tid = threadIdx.x;
    for (int i = tid; i < DA * 64; i += 1024) s_w1[i] = ws1p[i];
    for (int i = tid; i < HEADS * DA; i += 1024) s_w2[i] = Ws2[i];
    __syncthreads();

    int len = lengths[b];
    int lane = tid & 63, wave = tid >> 6;
    int tbase = tt * 64 + wave * 4;

    if (tbase >= len) {
        if (lane < HEADS) {
            #pragma unroll
            for (int ti = 0; ti < 4; ti++)
                S[((size_t)b * HEADS + lane) * T + tbase + ti] = NEGINF;
        }
        return;
    }

    const float2* hc2 = (const float2*)hc;
    for (int ti = 0; ti < 4; ti++) {
        int t = tbase + ti;
        if (t < len) {
            size_t row = ((size_t)b * T + t) * 256 + lane;
            float2 f0 = hc2[row];
            float2 f1 = hc2[row + 64];
            float2 f2 = hc2[row + 128];
            float2 f3 = hc2[row + 192];
            half2v h0 = packh2_(f0.x, f0.y);
            half2v h1 = packh2_(f1.x, f1.y);
            half2v h2 = packh2_(f2.x, f2.y);
            half2v h3 = packh2_(f3.x, f3.y);
            float y[DA];
            #pragma unroll
            for (int r = 0; r < DA; r++) {
                uint4 w = s_w1[r * 64 + lane];
                float v = fdot2_(w.x, h0, 0.f);
                v = fdot2_(w.y, h1, v);
                v = fdot2_(w.z, h2, v);
                v = fdot2_(w.w, h3, v);
                y[r] = v;
            }
            #pragma unroll
            for (int r = 0; r < DA; r++) {
                float v = y[r];
                for (int off = 32; off; off >>= 1) v += __shfl_xor(v, off, 64);
                y[r] = tanhf(v);
            }
            if (lane < HEADS) {
                float s = 0.f;
                #pragma unroll
                for (int r = 0; r < DA; r++) s += y[r] * s_w2[lane * DA + r];
                S[((size_t)b * HEADS + lane) * T + t] = s;
            }
        } else {
            if (lane < HEADS) S[((size_t)b * HEADS + lane) * T + t] = NEGINF;
        }
    }
}

// ---------------- masked softmax over T, in place ----------------
__global__ __launch_bounds__(256) void softmax_kernel(float* __restrict__ S) {
    int row = blockIdx.x;
    float* p = S + (size_t)row * T;
    int tid = threadIdx.x;
    int lane = tid & 63, wave = tid >> 6;
    __shared__ float rr[4], ss[4];

    float mx = NEGINF;
    #pragma unroll
    for (int i = 0; i < 2; i++) mx = fmaxf(mx, p[tid + i * 256]);
    for (int off = 32; off; off >>= 1) mx = fmaxf(mx, __shfl_xor(mx, off, 64));
    if (lane == 0) rr[wave] = mx;
    __syncthreads();
    mx = fmaxf(fmaxf(rr[0], rr[1]), fmaxf(rr[2], rr[3]));

    float e[2], sum = 0.f;
    #pragma unroll
    for (int i = 0; i < 2; i++) { e[i] = expf(p[tid + i * 256] - mx); sum += e[i]; }
    for (int off = 32; off; off >>= 1) sum += __shfl_xor(sum, off, 64);
    if (lane == 0) ss[wave] = sum;
    __syncthreads();
    sum = ss[0] + ss[1] + ss[2] + ss[3];
    float inv = 1.f / sum;
    #pragma unroll
    for (int i = 0; i < 2; i++) p[tid + i * 256] = e[i] * inv;
}

// ---------------- M = A @ Hc -> d_out, fused penal partials ----------------
__global__ __launch_bounds__(256) void attnM_kernel(const int* __restrict__ lengths,
                                                    const float* __restrict__ A,
                                                    const float* __restrict__ hc,
                                                    float* __restrict__ out,
                                                    float* __restrict__ part) {
    int b = blockIdx.x, tid = threadIdx.x;
    int len = lengths[b];
    const float* Ab  = A + (size_t)b * HEADS * T;
    const float* hcb = hc + (size_t)b * T * (2 * H);
    float acc[HEADS][2];
    #pragma unroll
    for (int h = 0; h < HEADS; h++) { acc[h][0] = 0.f; acc[h][1] = 0.f; }
    float p[10];
    #pragma unroll
    for (int i = 0; i < 10; i++) p[i] = 0.f;

    for (int t = 0; t < len; t++) {
        float v0 = hcb[(size_t)t * (2 * H) + tid];
        float v1 = hcb[(size_t)t * (2 * H) + H + tid];
        float a0 = Ab[t], a1 = Ab[T + t], a2 = Ab[2 * T + t], a3 = Ab[3 * T + t], a4 = Ab[4 * T + t];
        acc[0][0] += a0 * v0; acc[0][1] += a0 * v1;
        acc[1][0] += a1 * v0; acc[1][1] += a1 * v1;
        acc[2][0] += a2 * v0; acc[2][1] += a2 * v1;
        acc[3][0] += a3 * v0; acc[3][1] += a3 * v1;
        acc[4][0] += a4 * v0; acc[4][1] += a4 * v1;
        if ((t & 255) == tid) {
            p[0] += a0 * a1; p[1] += a0 * a2; p[2] += a0 * a3; p[3] += a0 * a4;
            p[4] += a1 * a2; p[5] += a1 * a3; p[6] += a1 * a4;
            p[7] += a2 * a3; p[8] += a2 * a4; p[9] += a3 * a4;
        }
    }
    #pragma unroll
    for (int h = 0; h < HEADS; h++) {
        out[(size_t)b * (HEADS * 2 * H) + h * (2 * H) + tid]     = acc[h][0];
        out[(size_t)b * (HEADS * 2 * H) + h * (2 * H) + H + tid] = acc[h][1];
    }

    __shared__ float red[10][4];
    int lane = tid & 63, wave = tid >> 6;
    #pragma unroll
    for (int i = 0; i < 10; i++) {
        float v = p[i];
        for (int off = 32; off; off >>= 1) v += __shfl_xor(v, off, 64);
        if (lane == 0) red[i][wave] = v;
    }
    __syncthreads();
    if (tid == 0) {
        float s = 0.f;
        #pragma unroll
        for (int i = 0; i < 10; i++) {
            float P = red[i][0] + red[i][1] + red[i][2] + red[i][3];
            s += 2.f * P * P;
        }
        part[b] = s;
    }
}

__global__ __launch_bounds__(128) void final_kernel(const float* __restrict__ part,
                                                    float* __restrict__ out) {
    int tid = threadIdx.x;
    float v = part[tid];
    for (int off = 32; off; off >>= 1) v += __shfl_xor(v, off, 64);
    __shared__ float r2[2];
    if ((tid & 63) == 0) r2[tid >> 6] = v;
    __syncthreads();
    if (tid == 0) out[(size_t)B * HEADS * 2 * H] = (r2[0] + r2[1]) * (1.f / (float)B);
}

// ---------------- host launcher ----------------
extern "C" void kernel_launch(void* const* d_in, const int* in_sizes, int n_in,
                              void* d_out, int out_size, void* d_ws, size_t ws_size,
                              hipStream_t stream) {
    const int*   word_ids = (const int*)d_in[0];
    const int*   lengths  = (const int*)d_in[1];
    const float* emb      = (const float*)d_in[2];
    const float* W_ih_f   = (const float*)d_in[3];
    const float* W_hh_f   = (const float*)d_in[4];
    const float* b_f      = (const float*)d_in[5];
    const float* W_ih_b   = (const float*)d_in[6];
    const float* W_hh_b   = (const float*)d_in[7];
    const float* b_b      = (const float*)d_in[8];
    const float* W_s1     = (const float*)d_in[9];
    const float* W_s2     = (const float*)d_in[10];
    float* out = (float*)d_out;

    char* ws = (char*)d_ws;
    unsigned short* wbt16 = (unsigned short*)(ws + WBT_OFF);
    unsigned*       wbt   = (unsigned*)(ws + WBT_OFF);
    unsigned short* wih16 = (unsigned short*)(ws + WIH_OFF);
    unsigned*       wihu  = (unsigned*)(ws + WIH_OFF);
    unsigned short* ws1p16 = (unsigned short*)(ws + WS1T_OFF);
    const uint4*    ws1p4  = (const uint4*)(ws + WS1T_OFF);
    float* pxc    = (float*)(ws + PX_OFF);
    float* hc     = (float*)(ws + HC_OFF);
    float* hbuf   = (float*)(ws + HBUF_OFF);
    float* cstate = (float*)(ws + CST_OFF);
    float* Abuf   = (float*)(ws + A_OFF);
    float* part   = (float*)(ws + PART_OFF);
    bool have_embh = (ws_size >= EMBH_END);
    unsigned short* embh16 = have_embh ? (unsigned short*)(ws + EMBH_OFF) : nullptr;
    const unsigned* embhu  = have_embh ? (const unsigned*)(ws + EMBH_OFF) : nullptr;

    prep_kernel<<<2080, 256, 0, stream>>>(W_hh_f, W_hh_b, W_ih_f, W_ih_b, W_s1, emb,
                                          wbt16, wih16, ws1p16, embh16);

    for (int c = 0; c < 8; c++) {
        proj_kernel<<<dim3(16, 128, 2), 256, 0, stream>>>(
            word_ids, lengths, emb, embhu, wihu, b_f, b_b, pxc, c);
        lstm6_kernel<<<dim3(128, 2), 1024, LSTM_LDS_BYTES, stream>>>(
            lengths, wbt, pxc, hc, hbuf, cstate, c);
    }

    logits_kernel<<<dim3(8, 128), 1024, 0, stream>>>(lengths, hc, ws1p4, W_s2, Abuf);
    softmax_kernel<<<B * HEADS, 256, 0, stream>>>(Abuf);
    attnM_kernel<<<B, 256, 0, stream>>>(lengths, Abuf, hc, out, part);
    final_kernel<<<1, 128, 0, stream>>>(part, out);
}